// Round 1
// baseline (2424.763 us; speedup 1.0000x reference)
//
#include <hip/hip_runtime.h>
#include <hip/hip_bf16.h>

#define B_ 2
#define S_ 1024
#define D_ 768
#define H_ 12
#define F_ 6
#define DH_ 64
#define BS_ (B_*S_)   // 2048
#define D2_ (2*D_)    // 1536
#define FD_ (F_*D_)   // 4608
#define FD4_ (FD_/4)  // 1152

__device__ __forceinline__ float gelu_exact(float x) {
    return 0.5f * x * (1.0f + erff(x * 0.70710678118654752f));
}

// ---------------------------------------------------------------------------
// Generic tiled fp32 GEMM: C[M,N] = epilogue(A[M,K] @ W[K,N] + bias)
// MODE 0: none; 1: gelu; 2: C = addend + (*scale_ptr)*v; 3: C = v + addend
// gridDim.z batches over W/bias/C with given strides (used for the 6 W_q).
// Requires M%64==0, N%64==0, K%16==0 (true for all shapes here).
// ---------------------------------------------------------------------------
template<int MODE>
__global__ __launch_bounds__(256) void gemm_kernel(
    const float* __restrict__ A, const float* __restrict__ W,
    const float* __restrict__ bias, float* __restrict__ C,
    int M, int N, int K,
    long wStrideZ, long bStrideZ, long cStrideZ,
    const float* __restrict__ addend, const float* __restrict__ scale_ptr)
{
    if (blockIdx.z) {
        W    += (long)blockIdx.z * wStrideZ;
        bias += (long)blockIdx.z * bStrideZ;
        C    += (long)blockIdx.z * cStrideZ;
    }
    // stride 68 pad: write/read patterns are <=2-way bank aliased (free on CDNA4)
    __shared__ float As[16][68];   // transposed A tile
    __shared__ float Bs[16][68];

    const int tid = threadIdx.x;
    const int tx = tid & 15;       // output col group
    const int ty = tid >> 4;       // output row group
    const int rowBase = blockIdx.y * 64;
    const int colBase = blockIdx.x * 64;

    const int la_k = tid & 15;     // A-load k within tile
    const int la_r = tid >> 4;     // A-load row base (0..15), +16*i
    const int lb_c = tid & 63;     // B-load col (coalesced 256B/wave)
    const int lb_k = tid >> 6;     // B-load k base (0..3), +4*i

    float acc[4][4] = {};

    for (int k0 = 0; k0 < K; k0 += 16) {
        #pragma unroll
        for (int i = 0; i < 4; i++)
            As[la_k][la_r + 16*i] = A[(long)(rowBase + la_r + 16*i)*K + (k0 + la_k)];
        #pragma unroll
        for (int i = 0; i < 4; i++)
            Bs[lb_k + 4*i][lb_c] = W[(long)(k0 + lb_k + 4*i)*N + (colBase + lb_c)];
        __syncthreads();
        #pragma unroll
        for (int kk = 0; kk < 16; kk++) {
            float4 av = *(const float4*)&As[kk][ty*4];
            float4 bv = *(const float4*)&Bs[kk][tx*4];
            float a0=av.x,a1=av.y,a2=av.z,a3=av.w;
            float b0=bv.x,b1=bv.y,b2=bv.z,b3=bv.w;
            acc[0][0]+=a0*b0; acc[0][1]+=a0*b1; acc[0][2]+=a0*b2; acc[0][3]+=a0*b3;
            acc[1][0]+=a1*b0; acc[1][1]+=a1*b1; acc[1][2]+=a1*b2; acc[1][3]+=a1*b3;
            acc[2][0]+=a2*b0; acc[2][1]+=a2*b1; acc[2][2]+=a2*b2; acc[2][3]+=a2*b3;
            acc[3][0]+=a3*b0; acc[3][1]+=a3*b1; acc[3][2]+=a3*b2; acc[3][3]+=a3*b3;
        }
        __syncthreads();
    }

    float scale = 0.0f;
    if (MODE == 2) scale = *scale_ptr;
    #pragma unroll
    for (int i = 0; i < 4; i++) {
        const int r = rowBase + ty*4 + i;
        #pragma unroll
        for (int j = 0; j < 4; j++) {
            const int c = colBase + tx*4 + j;
            float v = acc[i][j] + bias[c];
            if (MODE == 1) v = gelu_exact(v);
            if (MODE == 2) v = addend[(long)r*N + c] + scale * v;
            if (MODE == 3) v = v + addend[(long)r*N + c];
            C[(long)r*N + c] = v;
        }
    }
}

// ---------------------------------------------------------------------------
// Flash attention: one block = one (b,f,h) x 16 q-rows; K/V tiles of 64 keys.
// q layout [F,B,S,D]; kv layout [B,S,2D] (k cols 0..767, v cols 768..1535).
// Writes attention output directly into stacked [B,S,F*D] at f*D+h*64.
// thread (r=tid>>4, ci=tid&15): scores for keys c=ci+16j; O dims d=ci*4..+3.
// ---------------------------------------------------------------------------
__global__ __launch_bounds__(256) void attn_kernel(
    const float* __restrict__ q,
    const float* __restrict__ kv,
    float* __restrict__ stacked)
{
    __shared__ float Ks[64][68];
    __shared__ float Vs[64][68];
    __shared__ float Ps[16][68];

    const int gid = blockIdx.x;
    const int qt = gid & 63;            // q tile (S/16 = 64)
    const int rest = gid >> 6;          // 0..143
    const int h = rest % 12;
    const int rest2 = rest / 12;        // 0..11
    const int f = rest2 % 6;
    const int b = rest2 / 6;

    const int tid = threadIdx.x;
    const int r  = tid >> 4;            // q row within tile (0..15)
    const int ci = tid & 15;

    // q row (64 dims) into registers, pre-scaled by 1/sqrt(DH)=0.125
    float4 qreg[16];
    {
        const float* qrow = q + (((long)f*B_ + b)*S_ + qt*16 + r)*D_ + h*64;
        #pragma unroll
        for (int i = 0; i < 16; i++) {
            float4 v = *(const float4*)&qrow[i*4];
            v.x *= 0.125f; v.y *= 0.125f; v.z *= 0.125f; v.w *= 0.125f;
            qreg[i] = v;
        }
    }

    float m_i = -INFINITY, l_i = 0.0f;
    float o0 = 0.f, o1 = 0.f, o2 = 0.f, o3 = 0.f;

    for (int kt = 0; kt < 16; kt++) {
        // stage K,V tile (64 keys x 64 dims) -- 4 float4 per thread, coalesced
        #pragma unroll
        for (int i = 0; i < 4; i++) {
            int v = tid + 256*i;
            int c = v >> 4;
            int kk = (v & 15) * 4;
            long base = ((long)b*S_ + kt*64 + c)*D2_ + h*64 + kk;
            *(float4*)&Ks[c][kk] = *(const float4*)&kv[base];
            *(float4*)&Vs[c][kk] = *(const float4*)&kv[base + D_];
        }
        __syncthreads();

        // scores
        float sc[4];
        #pragma unroll
        for (int j = 0; j < 4; j++) {
            const int c = ci + 16*j;
            float ax=0.f, ay=0.f, az=0.f, aw=0.f;
            #pragma unroll
            for (int k4 = 0; k4 < 16; k4++) {
                float4 kvv = *(const float4*)&Ks[c][k4*4];
                float4 qv = qreg[k4];
                ax += qv.x*kvv.x; ay += qv.y*kvv.y;
                az += qv.z*kvv.z; aw += qv.w*kvv.w;
            }
            sc[j] = (ax+ay)+(az+aw);
        }

        // online softmax (row = 16 consecutive lanes -> shfl_xor within group)
        float tmax = fmaxf(fmaxf(sc[0],sc[1]), fmaxf(sc[2],sc[3]));
        #pragma unroll
        for (int off = 1; off < 16; off <<= 1)
            tmax = fmaxf(tmax, __shfl_xor(tmax, off));
        const float m_new = fmaxf(m_i, tmax);
        const float alpha = expf(m_i - m_new);
        float p[4], lsum = 0.f;
        #pragma unroll
        for (int j = 0; j < 4; j++) { p[j] = expf(sc[j] - m_new); lsum += p[j]; }
        #pragma unroll
        for (int off = 1; off < 16; off <<= 1)
            lsum += __shfl_xor(lsum, off);
        l_i = l_i * alpha + lsum;
        m_i = m_new;
        o0 *= alpha; o1 *= alpha; o2 *= alpha; o3 *= alpha;

        #pragma unroll
        for (int j = 0; j < 4; j++) Ps[r][ci + 16*j] = p[j];
        __syncthreads();

        // O += P @ V
        #pragma unroll 8
        for (int c = 0; c < 64; c++) {
            float pv = Ps[r][c];
            float4 vv = *(const float4*)&Vs[c][ci*4];
            o0 += pv*vv.x; o1 += pv*vv.y; o2 += pv*vv.z; o3 += pv*vv.w;
        }
        __syncthreads();
    }

    const float inv_l = 1.0f / l_i;
    const long sidx = ((long)b*S_ + qt*16 + r)*FD_ + f*D_ + h*64 + ci*4;
    float4 outv = {o0*inv_l, o1*inv_l, o2*inv_l, o3*inv_l};
    *(float4*)&stacked[sidx] = outv;
}

// ---------------------------------------------------------------------------
// gates[m,f] = softmax_f( g1[m,:] @ W_g2 + b_g2 ), one wave per row
// ---------------------------------------------------------------------------
__global__ __launch_bounds__(64) void gates_kernel(
    const float* __restrict__ g1, const float* __restrict__ W_g2,
    const float* __restrict__ b_g2, float* __restrict__ gates)
{
    const int m = blockIdx.x;
    const int lane = threadIdx.x;
    float p[6] = {0.f,0.f,0.f,0.f,0.f,0.f};
    for (int k = lane; k < FD4_; k += 64) {
        float g = g1[(long)m*FD4_ + k];
        #pragma unroll
        for (int f = 0; f < 6; f++) p[f] += g * W_g2[k*6 + f];
    }
    #pragma unroll
    for (int f = 0; f < 6; f++) {
        float v = p[f];
        #pragma unroll
        for (int off = 1; off < 64; off <<= 1) v += __shfl_xor(v, off);
        p[f] = v + b_g2[f];
    }
    float mx = p[0];
    #pragma unroll
    for (int f = 1; f < 6; f++) mx = fmaxf(mx, p[f]);
    float se = 0.f;
    #pragma unroll
    for (int f = 0; f < 6; f++) { p[f] = expf(p[f] - mx); se += p[f]; }
    const float inv = 1.0f / se;
    if (lane < 6) gates[m*6 + lane] = p[lane] * inv;
}

// ---------------------------------------------------------------------------
// comb[m,d] = sum_f mixed[m, f*768+d] * gates[m,f]   (float4 per thread)
// ---------------------------------------------------------------------------
__global__ __launch_bounds__(256) void combine_kernel(
    const float* __restrict__ mixed, const float* __restrict__ gates,
    float* __restrict__ comb)
{
    const int idx = blockIdx.x * 256 + threadIdx.x;   // < 2048*192
    const int m = idx / 192;
    const int d4 = idx - m*192;
    const float4* mrow = (const float4*)(mixed + (long)m * FD_);
    float4 a = {0.f,0.f,0.f,0.f};
    #pragma unroll
    for (int f = 0; f < 6; f++) {
        float g = gates[m*6 + f];
        float4 v = mrow[f*192 + d4];
        a.x += g*v.x; a.y += g*v.y; a.z += g*v.z; a.w += g*v.w;
    }
    ((float4*)comb)[idx] = a;
}

// ---------------------------------------------------------------------------
// In-place LayerNorm over D=768, one block per row (values cached in regs)
// ---------------------------------------------------------------------------
__global__ __launch_bounds__(256) void ln_kernel(
    const float* __restrict__ preY,
    const float* __restrict__ ln_g, const float* __restrict__ ln_b,
    float* __restrict__ out)
{
    __shared__ float red[8];
    const int m = blockIdx.x;
    const float* row = preY + (long)m * D_;
    const int tid = threadIdx.x;
    float vals[3];
    float s = 0.f, s2 = 0.f;
    #pragma unroll
    for (int i = 0; i < 3; i++) {
        float v = row[tid + 256*i];
        vals[i] = v;
        s += v; s2 += v*v;
    }
    #pragma unroll
    for (int off = 32; off >= 1; off >>= 1) {
        s  += __shfl_xor(s, off);
        s2 += __shfl_xor(s2, off);
    }
    const int wave = tid >> 6;
    if ((tid & 63) == 0) { red[wave*2] = s; red[wave*2+1] = s2; }
    __syncthreads();
    s  = red[0]+red[2]+red[4]+red[6];
    s2 = red[1]+red[3]+red[5]+red[7];
    const float mu  = s * (1.0f/D_);
    const float var = s2 * (1.0f/D_) - mu*mu;
    const float inv = rsqrtf(var + 1e-5f);
    #pragma unroll
    for (int i = 0; i < 3; i++) {
        const int d = tid + 256*i;
        out[(long)m*D_ + d] = (vals[i] - mu) * inv * ln_g[d] + ln_b[d];
    }
}

// ---------------------------------------------------------------------------
extern "C" void kernel_launch(void* const* d_in, const int* in_sizes, int n_in,
                              void* d_out, int out_size, void* d_ws, size_t ws_size,
                              hipStream_t stream)
{
    const float* x     = (const float*)d_in[0];
    const float* W_kv  = (const float*)d_in[1];
    const float* b_kv  = (const float*)d_in[2];
    const float* W_q   = (const float*)d_in[3];
    const float* b_q   = (const float*)d_in[4];
    const float* W_m1  = (const float*)d_in[5];
    const float* b_m1  = (const float*)d_in[6];
    const float* W_m2  = (const float*)d_in[7];
    const float* b_m2  = (const float*)d_in[8];
    const float* cross = (const float*)d_in[9];
    const float* W_g1  = (const float*)d_in[10];
    const float* b_g1  = (const float*)d_in[11];
    const float* W_g2  = (const float*)d_in[12];
    const float* b_g2  = (const float*)d_in[13];
    const float* W_out = (const float*)d_in[14];
    const float* b_out = (const float*)d_in[15];
    const float* ln_g  = (const float*)d_in[16];
    const float* ln_b  = (const float*)d_in[17];
    float* out = (float*)d_out;

    // workspace layout (floats); reuse: bufA = q then mixed; bufB = kv then h1;
    // bufC = g1 then comb.  Total ~97.6 MB.
    float* ws      = (float*)d_ws;
    float* bufA    = ws;                                   // 9,437,184
    float* bufB    = bufA + (size_t)F_*BS_*D_;             // 3,145,728
    float* stacked = bufB + (size_t)BS_*D2_;               // 9,437,184
    float* bufC    = stacked + (size_t)BS_*FD_;            // 2,359,296
    float* gates   = bufC + (size_t)BS_*FD4_;              // 12,288

    dim3 blk(256);

    // 1. kv = x @ W_kv + b_kv                       [2048,1536]
    gemm_kernel<0><<<dim3(D2_/64, BS_/64, 1), blk, 0, stream>>>(
        x, W_kv, b_kv, bufB, BS_, D2_, D_, 0, 0, 0, nullptr, nullptr);
    // 2. q[f] = x @ W_q[f] + b_q[f]                 6 x [2048,768]
    gemm_kernel<0><<<dim3(D_/64, BS_/64, F_), blk, 0, stream>>>(
        x, W_q, b_q, bufA, BS_, D_, D_,
        (long)D_*D_, (long)D_, (long)BS_*D_, nullptr, nullptr);
    // 3. flash attention -> stacked [B,S,F*D]
    attn_kernel<<<dim3(B_*F_*H_*(S_/16)), blk, 0, stream>>>(bufA, bufB, stacked);
    // 4. g1 = gelu(x @ W_g1 + b_g1)                 [2048,1152]
    gemm_kernel<1><<<dim3(FD4_/64, BS_/64, 1), blk, 0, stream>>>(
        x, W_g1, b_g1, bufC, BS_, FD4_, D_, 0, 0, 0, nullptr, nullptr);
    // 5. gates = softmax(g1 @ W_g2 + b_g2)
    gates_kernel<<<dim3(BS_), dim3(64), 0, stream>>>(bufC, W_g2, b_g2, gates);
    // 6. h1 = gelu(stacked @ W_m1 + b_m1)           [2048,1536]
    gemm_kernel<1><<<dim3(D2_/64, BS_/64, 1), blk, 0, stream>>>(
        stacked, W_m1, b_m1, bufB, BS_, D2_, FD_, 0, 0, 0, nullptr, nullptr);
    // 7. mixed = stacked + cross*(h1 @ W_m2 + b_m2) [2048,4608]
    gemm_kernel<2><<<dim3(FD_/64, BS_/64, 1), blk, 0, stream>>>(
        bufB, W_m2, b_m2, bufA, BS_, FD_, D2_, 0, 0, 0, stacked, cross);
    // 8. comb = sum_f mixed*gates                   [2048,768]
    combine_kernel<<<dim3(BS_*(D_/4)/256), blk, 0, stream>>>(bufA, gates, bufC);
    // 9. preY = x + comb @ W_out + b_out  -> d_out
    gemm_kernel<3><<<dim3(D_/64, BS_/64, 1), blk, 0, stream>>>(
        bufC, W_out, b_out, out, BS_, D_, D_, 0, 0, 0, x, nullptr);
    // 10. LayerNorm in place on d_out
    ln_kernel<<<dim3(BS_), blk, 0, stream>>>(out, ln_g, ln_b, out);
}

// Round 2
// 1494.249 us; speedup vs baseline: 1.6227x; 1.6227x over previous
//
#include <hip/hip_runtime.h>
#include <hip/hip_bf16.h>

#define B_ 2
#define S_ 1024
#define D_ 768
#define H_ 12
#define F_ 6
#define DH_ 64
#define BS_ (B_*S_)   // 2048
#define D2_ (2*D_)    // 1536
#define FD_ (F_*D_)   // 4608
#define FD4_ (FD_/4)  // 1152

typedef __attribute__((ext_vector_type(8))) short bf16x8;
typedef __attribute__((ext_vector_type(4))) float f32x4;

__device__ __forceinline__ float gelu_exact(float x) {
    return 0.5f * x * (1.0f + erff(x * 0.70710678118654752f));
}

// fp32 -> bf16 bits, round-to-nearest-even
__device__ __forceinline__ short f2bf(float f) {
    union { float f; unsigned u; } v; v.f = f;
    unsigned r = v.u + 0x7fff + ((v.u >> 16) & 1);
    return (short)(r >> 16);
}

// ---------------------------------------------------------------------------
// Generic tiled fp32 GEMM: C[M,N] = epilogue(A[M,K] @ W[K,N] + bias)
// MODE 0: none; 1: gelu; 2: C = addend + (*scale_ptr)*v; 3: C = v + addend
// ---------------------------------------------------------------------------
template<int MODE>
__global__ __launch_bounds__(256) void gemm_kernel(
    const float* __restrict__ A, const float* __restrict__ W,
    const float* __restrict__ bias, float* __restrict__ C,
    int M, int N, int K,
    long wStrideZ, long bStrideZ, long cStrideZ,
    const float* __restrict__ addend, const float* __restrict__ scale_ptr)
{
    if (blockIdx.z) {
        W    += (long)blockIdx.z * wStrideZ;
        bias += (long)blockIdx.z * bStrideZ;
        C    += (long)blockIdx.z * cStrideZ;
    }
    __shared__ float As[16][68];
    __shared__ float Bs[16][68];

    const int tid = threadIdx.x;
    const int tx = tid & 15;
    const int ty = tid >> 4;
    const int rowBase = blockIdx.y * 64;
    const int colBase = blockIdx.x * 64;

    const int la_k = tid & 15;
    const int la_r = tid >> 4;
    const int lb_c = tid & 63;
    const int lb_k = tid >> 6;

    float acc[4][4] = {};

    for (int k0 = 0; k0 < K; k0 += 16) {
        #pragma unroll
        for (int i = 0; i < 4; i++)
            As[la_k][la_r + 16*i] = A[(long)(rowBase + la_r + 16*i)*K + (k0 + la_k)];
        #pragma unroll
        for (int i = 0; i < 4; i++)
            Bs[lb_k + 4*i][lb_c] = W[(long)(k0 + lb_k + 4*i)*N + (colBase + lb_c)];
        __syncthreads();
        #pragma unroll
        for (int kk = 0; kk < 16; kk++) {
            float4 av = *(const float4*)&As[kk][ty*4];
            float4 bv = *(const float4*)&Bs[kk][tx*4];
            float a0=av.x,a1=av.y,a2=av.z,a3=av.w;
            float b0=bv.x,b1=bv.y,b2=bv.z,b3=bv.w;
            acc[0][0]+=a0*b0; acc[0][1]+=a0*b1; acc[0][2]+=a0*b2; acc[0][3]+=a0*b3;
            acc[1][0]+=a1*b0; acc[1][1]+=a1*b1; acc[1][2]+=a1*b2; acc[1][3]+=a1*b3;
            acc[2][0]+=a2*b0; acc[2][1]+=a2*b1; acc[2][2]+=a2*b2; acc[2][3]+=a2*b3;
            acc[3][0]+=a3*b0; acc[3][1]+=a3*b1; acc[3][2]+=a3*b2; acc[3][3]+=a3*b3;
        }
        __syncthreads();
    }

    float scale = 0.0f;
    if (MODE == 2) scale = *scale_ptr;
    #pragma unroll
    for (int i = 0; i < 4; i++) {
        const int r = rowBase + ty*4 + i;
        #pragma unroll
        for (int j = 0; j < 4; j++) {
            const int c = colBase + tx*4 + j;
            float v = acc[i][j] + bias[c];
            if (MODE == 1) v = gelu_exact(v);
            if (MODE == 2) v = addend[(long)r*N + c] + scale * v;
            if (MODE == 3) v = v + addend[(long)r*N + c];
            C[(long)r*N + c] = v;
        }
    }
}

// ---------------------------------------------------------------------------
// MFMA flash attention (bf16 inputs, fp32 accum/softmax).
// Block = one (b,f,h) x 64 q-rows; 4 waves x 16 rows each. K-tiles of 64 keys.
// q layout [F,B,S,D]; kv layout [B,S,2D]; writes stacked [B,S,F*D].
// LDS: Ks[key][dim] bf16, Vt[dim][key] bf16 (transposed), Ps[wave][row][key].
// All tiles 64x64 bf16 with 8-element XOR swizzle (chunk ^= row&7):
//   frag reads are contiguous 16B ds_read_b128, conflict-free.
// Fragment layouts (verified m89/m91/m120):
//   A: m=lane&15, k=quad*8+j ; B: n=lane&15, k=quad*8+j ; C: col=lane&15, row=quad*4+reg
// ---------------------------------------------------------------------------
__device__ __forceinline__ int swz64(int row, int col) {
    return row*64 + ((col & 7) | ((((col >> 3) ^ row) & 7) << 3));
}

__global__ __launch_bounds__(256) void attn_mfma(
    const float* __restrict__ q,
    const float* __restrict__ kv,
    float* __restrict__ stacked)
{
    __shared__ __align__(16) short Ks[64*64];
    __shared__ __align__(16) short Vt[64*64];
    __shared__ __align__(16) short Ps[4][16*64];

    const int bx = blockIdx.x;
    const int qt = bx & 15;            // 16 q-tiles of 64 rows
    const int rest = bx >> 4;          // 0..143
    const int h = rest % 12;
    const int r2 = rest / 12;
    const int f = r2 % 6;
    const int b = r2 / 6;

    const int tid  = threadIdx.x;
    const int wave = tid >> 6;
    const int lane = tid & 63;
    const int l15  = lane & 15;
    const int quad = lane >> 4;

    // staging assignment: thread -> key row, 4-dim column chunks
    const int skey = tid >> 2;          // 0..63
    const int sdc  = (tid & 3) * 4;     // dims sdc + 16c, c=0..3
    const float* kbase = kv + ((long)(b*S_) /*+ kt*64*/ + skey) * D2_ + h*64;

    // Q A-fragments (rows = qt*64 + wave*16 + l15), pre-scaled by 1/sqrt(64)
    bf16x8 aq[2];
    {
        const float* qp = q + (((long)f*B_ + b)*S_ + qt*64 + wave*16 + l15)*(long)D_
                          + h*64 + quad*8;
        #pragma unroll
        for (int ks = 0; ks < 2; ks++) {
            float4 q0 = *(const float4*)(qp + ks*32);
            float4 q1 = *(const float4*)(qp + ks*32 + 4);
            bf16x8 a;
            a[0]=f2bf(q0.x*0.125f); a[1]=f2bf(q0.y*0.125f);
            a[2]=f2bf(q0.z*0.125f); a[3]=f2bf(q0.w*0.125f);
            a[4]=f2bf(q1.x*0.125f); a[5]=f2bf(q1.y*0.125f);
            a[6]=f2bf(q1.z*0.125f); a[7]=f2bf(q1.w*0.125f);
            aq[ks] = a;
        }
    }

    short* Psw = Ps[wave];

    f32x4 o[4];
    #pragma unroll
    for (int nt = 0; nt < 4; nt++) o[nt] = (f32x4){0.f,0.f,0.f,0.f};
    float m_i[4] = {-INFINITY,-INFINITY,-INFINITY,-INFINITY};
    float l_i[4] = {0.f,0.f,0.f,0.f};

    for (int kt = 0; kt < 16; kt++) {
        // ---- stage K (as-is) and V (transposed) as bf16 with XOR swizzle ----
        const float* kb = kbase + (long)kt*64*D2_;
        #pragma unroll
        for (int c = 0; c < 4; c++) {
            const int dim = sdc + 16*c;
            float4 kf = *(const float4*)(kb + dim);
            float4 vf = *(const float4*)(kb + D_ + dim);
            unsigned k01 = (unsigned short)f2bf(kf.x) |
                           ((unsigned)(unsigned short)f2bf(kf.y) << 16);
            unsigned k23 = (unsigned short)f2bf(kf.z) |
                           ((unsigned)(unsigned short)f2bf(kf.w) << 16);
            uint2 kp; kp.x = k01; kp.y = k23;
            *(uint2*)&Ks[swz64(skey, dim)] = kp;      // dim%8 in {0,4}: stays in chunk
            Vt[swz64(dim+0, skey)] = f2bf(vf.x);
            Vt[swz64(dim+1, skey)] = f2bf(vf.y);
            Vt[swz64(dim+2, skey)] = f2bf(vf.z);
            Vt[swz64(dim+3, skey)] = f2bf(vf.w);
        }
        __syncthreads();

        // ---- S = Q @ K^T (C-layout: row=quad*4+r, col=l15 -> key nt*16+l15) ----
        f32x4 st[4];
        #pragma unroll
        for (int nt = 0; nt < 4; nt++) st[nt] = (f32x4){0.f,0.f,0.f,0.f};
        #pragma unroll
        for (int nt = 0; nt < 4; nt++) {
            const int key = nt*16 + l15;
            #pragma unroll
            for (int ks = 0; ks < 2; ks++) {
                const int chunk = ks*4 + quad;
                const bf16x8 kbf = *(const bf16x8*)
                    &Ks[key*64 + (((chunk ^ key) & 7) << 3)];
                st[nt] = __builtin_amdgcn_mfma_f32_16x16x32_bf16(aq[ks], kbf, st[nt], 0, 0, 0);
            }
        }

        // ---- online softmax per row (16-lane groups) ----
        float alpha[4];
        #pragma unroll
        for (int r = 0; r < 4; r++) {
            float t = fmaxf(fmaxf(st[0][r], st[1][r]), fmaxf(st[2][r], st[3][r]));
            t = fmaxf(t, __shfl_xor(t, 1));
            t = fmaxf(t, __shfl_xor(t, 2));
            t = fmaxf(t, __shfl_xor(t, 4));
            t = fmaxf(t, __shfl_xor(t, 8));
            const float mn = fmaxf(m_i[r], t);
            const float a  = __expf(m_i[r] - mn);
            m_i[r] = mn;
            float ls = 0.f;
            const int row = quad*4 + r;
            #pragma unroll
            for (int nt = 0; nt < 4; nt++) {
                const float p = __expf(st[nt][r] - mn);
                ls += p;
                Psw[swz64(row, nt*16 + l15)] = f2bf(p);
            }
            ls += __shfl_xor(ls, 1);
            ls += __shfl_xor(ls, 2);
            ls += __shfl_xor(ls, 4);
            ls += __shfl_xor(ls, 8);
            l_i[r] = l_i[r]*a + ls;
            alpha[r] = a;
        }
        #pragma unroll
        for (int nt = 0; nt < 4; nt++) {
            o[nt][0] *= alpha[0]; o[nt][1] *= alpha[1];
            o[nt][2] *= alpha[2]; o[nt][3] *= alpha[3];
        }

        // ---- P A-fragments from per-wave LDS (same-wave dep, lgkmcnt only) ----
        bf16x8 pa[2];
        #pragma unroll
        for (int ks = 0; ks < 2; ks++) {
            const int chunk = ks*4 + quad;
            pa[ks] = *(const bf16x8*)&Psw[l15*64 + (((chunk ^ l15) & 7) << 3)];
        }

        // ---- O += P @ V ----
        #pragma unroll
        for (int nt = 0; nt < 4; nt++) {
            const int dim = nt*16 + l15;
            #pragma unroll
            for (int ks = 0; ks < 2; ks++) {
                const int chunk = ks*4 + quad;
                const bf16x8 vb = *(const bf16x8*)
                    &Vt[dim*64 + (((chunk ^ dim) & 7) << 3)];
                o[nt] = __builtin_amdgcn_mfma_f32_16x16x32_bf16(pa[ks], vb, o[nt], 0, 0, 0);
            }
        }
        __syncthreads();   // protect Ks/Vt before next stage
    }

    // ---- epilogue: O / l -> stacked[B,S,F*D] ----
    float inv[4];
    #pragma unroll
    for (int r = 0; r < 4; r++) inv[r] = 1.0f / l_i[r];
    const long rowBase = (long)(b*S_ + qt*64 + wave*16);
    #pragma unroll
    for (int nt = 0; nt < 4; nt++) {
        #pragma unroll
        for (int r = 0; r < 4; r++) {
            const long row = rowBase + quad*4 + r;
            stacked[row*FD_ + f*D_ + h*64 + nt*16 + l15] = o[nt][r] * inv[r];
        }
    }
}

// ---------------------------------------------------------------------------
// gates[m,f] = softmax_f( g1[m,:] @ W_g2 + b_g2 ), one wave per row
// ---------------------------------------------------------------------------
__global__ __launch_bounds__(64) void gates_kernel(
    const float* __restrict__ g1, const float* __restrict__ W_g2,
    const float* __restrict__ b_g2, float* __restrict__ gates)
{
    const int m = blockIdx.x;
    const int lane = threadIdx.x;
    float p[6] = {0.f,0.f,0.f,0.f,0.f,0.f};
    for (int k = lane; k < FD4_; k += 64) {
        float g = g1[(long)m*FD4_ + k];
        #pragma unroll
        for (int f = 0; f < 6; f++) p[f] += g * W_g2[k*6 + f];
    }
    #pragma unroll
    for (int f = 0; f < 6; f++) {
        float v = p[f];
        #pragma unroll
        for (int off = 1; off < 64; off <<= 1) v += __shfl_xor(v, off);
        p[f] = v + b_g2[f];
    }
    float mx = p[0];
    #pragma unroll
    for (int f = 1; f < 6; f++) mx = fmaxf(mx, p[f]);
    float se = 0.f;
    #pragma unroll
    for (int f = 0; f < 6; f++) { p[f] = expf(p[f] - mx); se += p[f]; }
    const float inv = 1.0f / se;
    if (lane < 6) gates[m*6 + lane] = p[lane] * inv;
}

// ---------------------------------------------------------------------------
// comb[m,d] = sum_f mixed[m, f*768+d] * gates[m,f]
// ---------------------------------------------------------------------------
__global__ __launch_bounds__(256) void combine_kernel(
    const float* __restrict__ mixed, const float* __restrict__ gates,
    float* __restrict__ comb)
{
    const int idx = blockIdx.x * 256 + threadIdx.x;
    const int m = idx / 192;
    const int d4 = idx - m*192;
    const float4* mrow = (const float4*)(mixed + (long)m * FD_);
    float4 a = {0.f,0.f,0.f,0.f};
    #pragma unroll
    for (int f = 0; f < 6; f++) {
        float g = gates[m*6 + f];
        float4 v = mrow[f*192 + d4];
        a.x += g*v.x; a.y += g*v.y; a.z += g*v.z; a.w += g*v.w;
    }
    ((float4*)comb)[idx] = a;
}

// ---------------------------------------------------------------------------
// In-place LayerNorm over D=768, one block per row
// ---------------------------------------------------------------------------
__global__ __launch_bounds__(256) void ln_kernel(
    const float* __restrict__ preY,
    const float* __restrict__ ln_g, const float* __restrict__ ln_b,
    float* __restrict__ out)
{
    __shared__ float red[8];
    const int m = blockIdx.x;
    const float* row = preY + (long)m * D_;
    const int tid = threadIdx.x;
    float vals[3];
    float s = 0.f, s2 = 0.f;
    #pragma unroll
    for (int i = 0; i < 3; i++) {
        float v = row[tid + 256*i];
        vals[i] = v;
        s += v; s2 += v*v;
    }
    #pragma unroll
    for (int off = 32; off >= 1; off >>= 1) {
        s  += __shfl_xor(s, off);
        s2 += __shfl_xor(s2, off);
    }
    const int wave = tid >> 6;
    if ((tid & 63) == 0) { red[wave*2] = s; red[wave*2+1] = s2; }
    __syncthreads();
    s  = red[0]+red[2]+red[4]+red[6];
    s2 = red[1]+red[3]+red[5]+red[7];
    const float mu  = s * (1.0f/D_);
    const float var = s2 * (1.0f/D_) - mu*mu;
    const float inv = rsqrtf(var + 1e-5f);
    #pragma unroll
    for (int i = 0; i < 3; i++) {
        const int d = tid + 256*i;
        out[(long)m*D_ + d] = (vals[i] - mu) * inv * ln_g[d] + ln_b[d];
    }
}

// ---------------------------------------------------------------------------
extern "C" void kernel_launch(void* const* d_in, const int* in_sizes, int n_in,
                              void* d_out, int out_size, void* d_ws, size_t ws_size,
                              hipStream_t stream)
{
    const float* x     = (const float*)d_in[0];
    const float* W_kv  = (const float*)d_in[1];
    const float* b_kv  = (const float*)d_in[2];
    const float* W_q   = (const float*)d_in[3];
    const float* b_q   = (const float*)d_in[4];
    const float* W_m1  = (const float*)d_in[5];
    const float* b_m1  = (const float*)d_in[6];
    const float* W_m2  = (const float*)d_in[7];
    const float* b_m2  = (const float*)d_in[8];
    const float* cross = (const float*)d_in[9];
    const float* W_g1  = (const float*)d_in[10];
    const float* b_g1  = (const float*)d_in[11];
    const float* W_g2  = (const float*)d_in[12];
    const float* b_g2  = (const float*)d_in[13];
    const float* W_out = (const float*)d_in[14];
    const float* b_out = (const float*)d_in[15];
    const float* ln_g  = (const float*)d_in[16];
    const float* ln_b  = (const float*)d_in[17];
    float* out = (float*)d_out;

    float* ws      = (float*)d_ws;
    float* bufA    = ws;                                   // q, then mixed
    float* bufB    = bufA + (size_t)F_*BS_*D_;             // kv, then h1
    float* stacked = bufB + (size_t)BS_*D2_;
    float* bufC    = stacked + (size_t)BS_*FD_;            // g1, then comb
    float* gates   = bufC + (size_t)BS_*FD4_;

    dim3 blk(256);

    // 1. kv = x @ W_kv + b_kv
    gemm_kernel<0><<<dim3(D2_/64, BS_/64, 1), blk, 0, stream>>>(
        x, W_kv, b_kv, bufB, BS_, D2_, D_, 0, 0, 0, nullptr, nullptr);
    // 2. q[f] = x @ W_q[f] + b_q[f]
    gemm_kernel<0><<<dim3(D_/64, BS_/64, F_), blk, 0, stream>>>(
        x, W_q, b_q, bufA, BS_, D_, D_,
        (long)D_*D_, (long)D_, (long)BS_*D_, nullptr, nullptr);
    // 3. MFMA flash attention -> stacked
    attn_mfma<<<dim3(16 * 144), blk, 0, stream>>>(bufA, bufB, stacked);
    // 4. g1 = gelu(x @ W_g1 + b_g1)
    gemm_kernel<1><<<dim3(FD4_/64, BS_/64, 1), blk, 0, stream>>>(
        x, W_g1, b_g1, bufC, BS_, FD4_, D_, 0, 0, 0, nullptr, nullptr);
    // 5. gates = softmax(g1 @ W_g2 + b_g2)
    gates_kernel<<<dim3(BS_), dim3(64), 0, stream>>>(bufC, W_g2, b_g2, gates);
    // 6. h1 = gelu(stacked @ W_m1 + b_m1)
    gemm_kernel<1><<<dim3(D2_/64, BS_/64, 1), blk, 0, stream>>>(
        stacked, W_m1, b_m1, bufB, BS_, D2_, FD_, 0, 0, 0, nullptr, nullptr);
    // 7. mixed = stacked + cross*(h1 @ W_m2 + b_m2)
    gemm_kernel<2><<<dim3(FD_/64, BS_/64, 1), blk, 0, stream>>>(
        bufB, W_m2, b_m2, bufA, BS_, FD_, D2_, 0, 0, 0, stacked, cross);
    // 8. comb = sum_f mixed*gates
    combine_kernel<<<dim3(BS_*(D_/4)/256), blk, 0, stream>>>(bufA, gates, bufC);
    // 9. preY = x + comb @ W_out + b_out -> d_out
    gemm_kernel<3><<<dim3(D_/64, BS_/64, 1), blk, 0, stream>>>(
        bufC, W_out, b_out, out, BS_, D_, D_, 0, 0, 0, x, nullptr);
    // 10. LayerNorm in place
    ln_kernel<<<dim3(BS_), blk, 0, stream>>>(out, ln_g, ln_b, out);
}

// Round 3
// 1090.101 us; speedup vs baseline: 2.2243x; 1.3707x over previous
//
#include <hip/hip_runtime.h>
#include <hip/hip_bf16.h>

#define B_ 2
#define S_ 1024
#define D_ 768
#define H_ 12
#define F_ 6
#define DH_ 64
#define BS_ (B_*S_)   // 2048
#define D2_ (2*D_)    // 1536
#define FD_ (F_*D_)   // 4608
#define FD4_ (FD_/4)  // 1152

typedef __attribute__((ext_vector_type(8))) short bf16x8;
typedef __attribute__((ext_vector_type(4))) float f32x4;

__device__ __forceinline__ float gelu_exact(float x) {
    return 0.5f * x * (1.0f + erff(x * 0.70710678118654752f));
}

// fp32 -> bf16 bits, round-to-nearest-even
__device__ __forceinline__ short f2bf(float f) {
    union { float f; unsigned u; } v; v.f = f;
    unsigned r = v.u + 0x7fff + ((v.u >> 16) & 1);
    return (short)(r >> 16);
}

// ---------------------------------------------------------------------------
// bf16-MFMA GEMM: C[M,N] = epilogue(A[M,K] @ W[K,N] + bias), fp32 in/out.
// MODE 0: none; 1: gelu; 2: C = addend + (*scale_ptr)*v; 3: C = v + addend
// Tile 128x128, BK=64, 256 threads = 4 waves (2x2), wave = 64x64 out.
// LDS layout (both A and B): [tile(8)][kchunk(8)][slot(16)] x 8 shorts,
// slot = l15 ^ kc ^ tile  (XOR swizzle -> <=2-way per 16-lane phase on both
// the b128 staging writes and the b128 frag reads).
// Requires M%128==0, N%128==0, K%64==0 (true for all shapes here).
// ---------------------------------------------------------------------------
template<int MODE>
__global__ __launch_bounds__(256, 2) void mfma_gemm(
    const float* __restrict__ A, const float* __restrict__ W,
    const float* __restrict__ bias, float* __restrict__ C,
    int M, int N, int K,
    long wStrideZ, long bStrideZ, long cStrideZ,
    const float* __restrict__ addend, const float* __restrict__ scale_ptr)
{
    if (blockIdx.z) {
        W    += (long)blockIdx.z * wStrideZ;
        bias += (long)blockIdx.z * bStrideZ;
        C    += (long)blockIdx.z * cStrideZ;
    }
    __shared__ __align__(16) short As[8192];   // 16 KB
    __shared__ __align__(16) short Bs[8192];   // 16 KB

    const int tid  = threadIdx.x;
    const int wave = tid >> 6;
    const int lane = tid & 63;
    const int l15  = lane & 15;
    const int quad = lane >> 4;
    const int wr   = wave >> 1;        // wave row half (0/1)
    const int wc   = wave & 1;         // wave col half (0/1)

    const int m0 = blockIdx.y * 128;
    const int n0 = blockIdx.x * 128;

    // --- staging assignments ---
    // A: thread -> row ar (0..127), k-half akb (0 or 32); reads 32 contig k.
    const int ar   = tid >> 1;
    const int akb  = (tid & 1) * 32;
    const int amt  = ar >> 4;          // tile index 0..7
    const int ar15 = ar & 15;
    // B: thread -> 4 cols starting bn0, k-chunk bkg (8 k rows).
    const int bn0  = (tid & 31) * 4;
    const int bkg  = tid >> 5;         // 0..7

    const float* Ap = A + (long)(m0 + ar) * K + akb;
    const float* Wp = W + (long)(bkg * 8) * N + n0 + bn0;

    f32x4 acc[4][4];
    #pragma unroll
    for (int i = 0; i < 4; i++)
        #pragma unroll
        for (int j = 0; j < 4; j++)
            acc[i][j] = (f32x4){0.f, 0.f, 0.f, 0.f};

    for (int kb = 0; kb < K; kb += 64) {
        // ---- stage A tile (128 x 64) ----
        {
            float av[32];
            #pragma unroll
            for (int i = 0; i < 8; i++)
                *(float4*)&av[i*4] = *(const float4*)(Ap + kb + i*4);
            #pragma unroll
            for (int c = 0; c < 4; c++) {
                const int kc = (akb >> 3) + c;
                bf16x8 s;
                #pragma unroll
                for (int j = 0; j < 8; j++) s[j] = f2bf(av[c*8 + j]);
                const int slot = (ar15 ^ kc ^ amt) & 15;
                *(bf16x8*)&As[((amt*8 + kc)*16 + slot)*8] = s;
            }
        }
        // ---- stage B tile (64 x 128), transposed in regs ----
        {
            float bv[8][4];
            #pragma unroll
            for (int r = 0; r < 8; r++)
                *(float4*)&bv[r][0] = *(const float4*)(Wp + (long)(kb + r) * N);
            #pragma unroll
            for (int j = 0; j < 4; j++) {
                const int n  = bn0 + j;
                const int nt = n >> 4;
                bf16x8 s;
                #pragma unroll
                for (int r = 0; r < 8; r++) s[r] = f2bf(bv[r][j]);
                const int slot = ((n & 15) ^ bkg ^ nt) & 15;
                *(bf16x8*)&Bs[((nt*8 + bkg)*16 + slot)*8] = s;
            }
        }
        __syncthreads();

        // ---- compute: 2 k-steps of 32, 16 MFMAs each ----
        #pragma unroll
        for (int ks = 0; ks < 2; ks++) {
            const int kc = ks*4 + quad;
            bf16x8 af[4], bf[4];
            #pragma unroll
            for (int mt = 0; mt < 4; mt++) {
                const int MT = wr*4 + mt;
                af[mt] = *(const bf16x8*)&As[((MT*8 + kc)*16 + ((l15 ^ kc ^ MT) & 15))*8];
            }
            #pragma unroll
            for (int nt = 0; nt < 4; nt++) {
                const int NT = wc*4 + nt;
                bf[nt] = *(const bf16x8*)&Bs[((NT*8 + kc)*16 + ((l15 ^ kc ^ NT) & 15))*8];
            }
            #pragma unroll
            for (int mt = 0; mt < 4; mt++)
                #pragma unroll
                for (int nt = 0; nt < 4; nt++)
                    acc[mt][nt] = __builtin_amdgcn_mfma_f32_16x16x32_bf16(
                        af[mt], bf[nt], acc[mt][nt], 0, 0, 0);
        }
        __syncthreads();
    }

    // ---- epilogue (C layout: col=l15, row=quad*4+r) ----
    float scale = 0.0f;
    if (MODE == 2) scale = *scale_ptr;
    #pragma unroll
    for (int nt = 0; nt < 4; nt++) {
        const int col = n0 + wc*64 + nt*16 + l15;
        const float bcol = bias[col];
        #pragma unroll
        for (int mt = 0; mt < 4; mt++) {
            #pragma unroll
            for (int r = 0; r < 4; r++) {
                const long row = m0 + wr*64 + mt*16 + quad*4 + r;
                float v = acc[mt][nt][r] + bcol;
                if (MODE == 1) v = gelu_exact(v);
                if (MODE == 2) v = addend[row*N + col] + scale * v;
                if (MODE == 3) v = v + addend[row*N + col];
                C[row*N + col] = v;
            }
        }
    }
}

// ---------------------------------------------------------------------------
// MFMA flash attention (unchanged from round 2)
// ---------------------------------------------------------------------------
__device__ __forceinline__ int swz64(int row, int col) {
    return row*64 + ((col & 7) | ((((col >> 3) ^ row) & 7) << 3));
}

__global__ __launch_bounds__(256) void attn_mfma(
    const float* __restrict__ q,
    const float* __restrict__ kv,
    float* __restrict__ stacked)
{
    __shared__ __align__(16) short Ks[64*64];
    __shared__ __align__(16) short Vt[64*64];
    __shared__ __align__(16) short Ps[4][16*64];

    const int bx = blockIdx.x;
    const int qt = bx & 15;
    const int rest = bx >> 4;
    const int h = rest % 12;
    const int r2 = rest / 12;
    const int f = r2 % 6;
    const int b = r2 / 6;

    const int tid  = threadIdx.x;
    const int wave = tid >> 6;
    const int lane = tid & 63;
    const int l15  = lane & 15;
    const int quad = lane >> 4;

    const int skey = tid >> 2;
    const int sdc  = (tid & 3) * 4;
    const float* kbase = kv + ((long)(b*S_) + skey) * D2_ + h*64;

    bf16x8 aq[2];
    {
        const float* qp = q + (((long)f*B_ + b)*S_ + qt*64 + wave*16 + l15)*(long)D_
                          + h*64 + quad*8;
        #pragma unroll
        for (int ks = 0; ks < 2; ks++) {
            float4 q0 = *(const float4*)(qp + ks*32);
            float4 q1 = *(const float4*)(qp + ks*32 + 4);
            bf16x8 a;
            a[0]=f2bf(q0.x*0.125f); a[1]=f2bf(q0.y*0.125f);
            a[2]=f2bf(q0.z*0.125f); a[3]=f2bf(q0.w*0.125f);
            a[4]=f2bf(q1.x*0.125f); a[5]=f2bf(q1.y*0.125f);
            a[6]=f2bf(q1.z*0.125f); a[7]=f2bf(q1.w*0.125f);
            aq[ks] = a;
        }
    }

    short* Psw = Ps[wave];

    f32x4 o[4];
    #pragma unroll
    for (int nt = 0; nt < 4; nt++) o[nt] = (f32x4){0.f,0.f,0.f,0.f};
    float m_i[4] = {-INFINITY,-INFINITY,-INFINITY,-INFINITY};
    float l_i[4] = {0.f,0.f,0.f,0.f};

    for (int kt = 0; kt < 16; kt++) {
        const float* kb = kbase + (long)kt*64*D2_;
        #pragma unroll
        for (int c = 0; c < 4; c++) {
            const int dim = sdc + 16*c;
            float4 kf = *(const float4*)(kb + dim);
            float4 vf = *(const float4*)(kb + D_ + dim);
            unsigned k01 = (unsigned short)f2bf(kf.x) |
                           ((unsigned)(unsigned short)f2bf(kf.y) << 16);
            unsigned k23 = (unsigned short)f2bf(kf.z) |
                           ((unsigned)(unsigned short)f2bf(kf.w) << 16);
            uint2 kp; kp.x = k01; kp.y = k23;
            *(uint2*)&Ks[swz64(skey, dim)] = kp;
            Vt[swz64(dim+0, skey)] = f2bf(vf.x);
            Vt[swz64(dim+1, skey)] = f2bf(vf.y);
            Vt[swz64(dim+2, skey)] = f2bf(vf.z);
            Vt[swz64(dim+3, skey)] = f2bf(vf.w);
        }
        __syncthreads();

        f32x4 st[4];
        #pragma unroll
        for (int nt = 0; nt < 4; nt++) st[nt] = (f32x4){0.f,0.f,0.f,0.f};
        #pragma unroll
        for (int nt = 0; nt < 4; nt++) {
            const int key = nt*16 + l15;
            #pragma unroll
            for (int ks = 0; ks < 2; ks++) {
                const int chunk = ks*4 + quad;
                const bf16x8 kbf = *(const bf16x8*)
                    &Ks[key*64 + (((chunk ^ key) & 7) << 3)];
                st[nt] = __builtin_amdgcn_mfma_f32_16x16x32_bf16(aq[ks], kbf, st[nt], 0, 0, 0);
            }
        }

        float alpha[4];
        #pragma unroll
        for (int r = 0; r < 4; r++) {
            float t = fmaxf(fmaxf(st[0][r], st[1][r]), fmaxf(st[2][r], st[3][r]));
            t = fmaxf(t, __shfl_xor(t, 1));
            t = fmaxf(t, __shfl_xor(t, 2));
            t = fmaxf(t, __shfl_xor(t, 4));
            t = fmaxf(t, __shfl_xor(t, 8));
            const float mn = fmaxf(m_i[r], t);
            const float a  = __expf(m_i[r] - mn);
            m_i[r] = mn;
            float ls = 0.f;
            const int row = quad*4 + r;
            #pragma unroll
            for (int nt = 0; nt < 4; nt++) {
                const float p = __expf(st[nt][r] - mn);
                ls += p;
                Psw[swz64(row, nt*16 + l15)] = f2bf(p);
            }
            ls += __shfl_xor(ls, 1);
            ls += __shfl_xor(ls, 2);
            ls += __shfl_xor(ls, 4);
            ls += __shfl_xor(ls, 8);
            l_i[r] = l_i[r]*a + ls;
            alpha[r] = a;
        }
        #pragma unroll
        for (int nt = 0; nt < 4; nt++) {
            o[nt][0] *= alpha[0]; o[nt][1] *= alpha[1];
            o[nt][2] *= alpha[2]; o[nt][3] *= alpha[3];
        }

        bf16x8 pa[2];
        #pragma unroll
        for (int ks = 0; ks < 2; ks++) {
            const int chunk = ks*4 + quad;
            pa[ks] = *(const bf16x8*)&Psw[l15*64 + (((chunk ^ l15) & 7) << 3)];
        }

        #pragma unroll
        for (int nt = 0; nt < 4; nt++) {
            const int dim = nt*16 + l15;
            #pragma unroll
            for (int ks = 0; ks < 2; ks++) {
                const int chunk = ks*4 + quad;
                const bf16x8 vb = *(const bf16x8*)
                    &Vt[dim*64 + (((chunk ^ dim) & 7) << 3)];
                o[nt] = __builtin_amdgcn_mfma_f32_16x16x32_bf16(pa[ks], vb, o[nt], 0, 0, 0);
            }
        }
        __syncthreads();
    }

    float inv[4];
    #pragma unroll
    for (int r = 0; r < 4; r++) inv[r] = 1.0f / l_i[r];
    const long rowBase = (long)(b*S_ + qt*64 + wave*16);
    #pragma unroll
    for (int nt = 0; nt < 4; nt++) {
        #pragma unroll
        for (int r = 0; r < 4; r++) {
            const long row = rowBase + quad*4 + r;
            stacked[row*FD_ + f*D_ + h*64 + nt*16 + l15] = o[nt][r] * inv[r];
        }
    }
}

// ---------------------------------------------------------------------------
// gates[m,f] = softmax_f( g1[m,:] @ W_g2 + b_g2 ), one wave per row
// ---------------------------------------------------------------------------
__global__ __launch_bounds__(64) void gates_kernel(
    const float* __restrict__ g1, const float* __restrict__ W_g2,
    const float* __restrict__ b_g2, float* __restrict__ gates)
{
    const int m = blockIdx.x;
    const int lane = threadIdx.x;
    float p[6] = {0.f,0.f,0.f,0.f,0.f,0.f};
    for (int k = lane; k < FD4_; k += 64) {
        float g = g1[(long)m*FD4_ + k];
        #pragma unroll
        for (int f = 0; f < 6; f++) p[f] += g * W_g2[k*6 + f];
    }
    #pragma unroll
    for (int f = 0; f < 6; f++) {
        float v = p[f];
        #pragma unroll
        for (int off = 1; off < 64; off <<= 1) v += __shfl_xor(v, off);
        p[f] = v + b_g2[f];
    }
    float mx = p[0];
    #pragma unroll
    for (int f = 1; f < 6; f++) mx = fmaxf(mx, p[f]);
    float se = 0.f;
    #pragma unroll
    for (int f = 0; f < 6; f++) { p[f] = expf(p[f] - mx); se += p[f]; }
    const float inv = 1.0f / se;
    if (lane < 6) gates[m*6 + lane] = p[lane] * inv;
}

// ---------------------------------------------------------------------------
// comb[m,d] = sum_f mixed[m, f*768+d] * gates[m,f]
// ---------------------------------------------------------------------------
__global__ __launch_bounds__(256) void combine_kernel(
    const float* __restrict__ mixed, const float* __restrict__ gates,
    float* __restrict__ comb)
{
    const int idx = blockIdx.x * 256 + threadIdx.x;
    const int m = idx / 192;
    const int d4 = idx - m*192;
    const float4* mrow = (const float4*)(mixed + (long)m * FD_);
    float4 a = {0.f,0.f,0.f,0.f};
    #pragma unroll
    for (int f = 0; f < 6; f++) {
        float g = gates[m*6 + f];
        float4 v = mrow[f*192 + d4];
        a.x += g*v.x; a.y += g*v.y; a.z += g*v.z; a.w += g*v.w;
    }
    ((float4*)comb)[idx] = a;
}

// ---------------------------------------------------------------------------
// In-place LayerNorm over D=768, one block per row
// ---------------------------------------------------------------------------
__global__ __launch_bounds__(256) void ln_kernel(
    const float* __restrict__ preY,
    const float* __restrict__ ln_g, const float* __restrict__ ln_b,
    float* __restrict__ out)
{
    __shared__ float red[8];
    const int m = blockIdx.x;
    const float* row = preY + (long)m * D_;
    const int tid = threadIdx.x;
    float vals[3];
    float s = 0.f, s2 = 0.f;
    #pragma unroll
    for (int i = 0; i < 3; i++) {
        float v = row[tid + 256*i];
        vals[i] = v;
        s += v; s2 += v*v;
    }
    #pragma unroll
    for (int off = 32; off >= 1; off >>= 1) {
        s  += __shfl_xor(s, off);
        s2 += __shfl_xor(s2, off);
    }
    const int wave = tid >> 6;
    if ((tid & 63) == 0) { red[wave*2] = s; red[wave*2+1] = s2; }
    __syncthreads();
    s  = red[0]+red[2]+red[4]+red[6];
    s2 = red[1]+red[3]+red[5]+red[7];
    const float mu  = s * (1.0f/D_);
    const float var = s2 * (1.0f/D_) - mu*mu;
    const float inv = rsqrtf(var + 1e-5f);
    #pragma unroll
    for (int i = 0; i < 3; i++) {
        const int d = tid + 256*i;
        out[(long)m*D_ + d] = (vals[i] - mu) * inv * ln_g[d] + ln_b[d];
    }
}

// ---------------------------------------------------------------------------
extern "C" void kernel_launch(void* const* d_in, const int* in_sizes, int n_in,
                              void* d_out, int out_size, void* d_ws, size_t ws_size,
                              hipStream_t stream)
{
    const float* x     = (const float*)d_in[0];
    const float* W_kv  = (const float*)d_in[1];
    const float* b_kv  = (const float*)d_in[2];
    const float* W_q   = (const float*)d_in[3];
    const float* b_q   = (const float*)d_in[4];
    const float* W_m1  = (const float*)d_in[5];
    const float* b_m1  = (const float*)d_in[6];
    const float* W_m2  = (const float*)d_in[7];
    const float* b_m2  = (const float*)d_in[8];
    const float* cross = (const float*)d_in[9];
    const float* W_g1  = (const float*)d_in[10];
    const float* b_g1  = (const float*)d_in[11];
    const float* W_g2  = (const float*)d_in[12];
    const float* b_g2  = (const float*)d_in[13];
    const float* W_out = (const float*)d_in[14];
    const float* b_out = (const float*)d_in[15];
    const float* ln_g  = (const float*)d_in[16];
    const float* ln_b  = (const float*)d_in[17];
    float* out = (float*)d_out;

    float* ws      = (float*)d_ws;
    float* bufA    = ws;                                   // q, then mixed
    float* bufB    = bufA + (size_t)F_*BS_*D_;             // kv, then h1
    float* stacked = bufB + (size_t)BS_*D2_;
    float* bufC    = stacked + (size_t)BS_*FD_;            // g1, then comb
    float* gates   = bufC + (size_t)BS_*FD4_;

    dim3 blk(256);

    // 1. kv = x @ W_kv + b_kv                    [2048,1536] K=768
    mfma_gemm<0><<<dim3(D2_/128, BS_/128, 1), blk, 0, stream>>>(
        x, W_kv, b_kv, bufB, BS_, D2_, D_, 0, 0, 0, nullptr, nullptr);
    // 2. q[f] = x @ W_q[f] + b_q[f]              6 x [2048,768] K=768
    mfma_gemm<0><<<dim3(D_/128, BS_/128, F_), blk, 0, stream>>>(
        x, W_q, b_q, bufA, BS_, D_, D_,
        (long)D_*D_, (long)D_, (long)BS_*D_, nullptr, nullptr);
    // 3. MFMA flash attention -> stacked
    attn_mfma<<<dim3(16 * 144), blk, 0, stream>>>(bufA, bufB, stacked);
    // 4. g1 = gelu(x @ W_g1 + b_g1)              [2048,1152] K=768
    mfma_gemm<1><<<dim3(FD4_/128, BS_/128, 1), blk, 0, stream>>>(
        x, W_g1, b_g1, bufC, BS_, FD4_, D_, 0, 0, 0, nullptr, nullptr);
    // 5. gates = softmax(g1 @ W_g2 + b_g2)
    gates_kernel<<<dim3(BS_), dim3(64), 0, stream>>>(bufC, W_g2, b_g2, gates);
    // 6. h1 = gelu(stacked @ W_m1 + b_m1)        [2048,1536] K=4608
    mfma_gemm<1><<<dim3(D2_/128, BS_/128, 1), blk, 0, stream>>>(
        stacked, W_m1, b_m1, bufB, BS_, D2_, FD_, 0, 0, 0, nullptr, nullptr);
    // 7. mixed = stacked + cross*(h1 @ W_m2 + b_m2)  [2048,4608] K=1536
    mfma_gemm<2><<<dim3(FD_/128, BS_/128, 1), blk, 0, stream>>>(
        bufB, W_m2, b_m2, bufA, BS_, FD_, D2_, 0, 0, 0, stacked, cross);
    // 8. comb = sum_f mixed*gates                [2048,768]
    combine_kernel<<<dim3(BS_*(D_/4)/256), blk, 0, stream>>>(bufA, gates, bufC);
    // 9. preY = x + comb @ W_out + b_out -> d_out    [2048,768] K=768
    mfma_gemm<3><<<dim3(D_/128, BS_/128, 1), blk, 0, stream>>>(
        bufC, W_out, b_out, out, BS_, D_, D_, 0, 0, 0, x, nullptr);
    // 10. LayerNorm in place
    ln_kernel<<<dim3(BS_), blk, 0, stream>>>(out, ln_g, ln_b, out);
}

// Round 4
// 701.979 us; speedup vs baseline: 3.4542x; 1.5529x over previous
//
#include <hip/hip_runtime.h>
#include <hip/hip_bf16.h>

#define B_ 2
#define S_ 1024
#define D_ 768
#define H_ 12
#define F_ 6
#define DH_ 64
#define BS_ (B_*S_)   // 2048
#define D2_ (2*D_)    // 1536
#define FD_ (F_*D_)   // 4608
#define FD4_ (FD_/4)  // 1152

typedef __attribute__((ext_vector_type(8))) short bf16x8;
typedef __attribute__((ext_vector_type(4))) float f32x4;

__device__ __forceinline__ float gelu_exact(float x) {
    return 0.5f * x * (1.0f + erff(x * 0.70710678118654752f));
}

// fp32 -> bf16 bits, round-to-nearest-even
__device__ __forceinline__ short f2bf(float f) {
    union { float f; unsigned u; } v; v.f = f;
    unsigned r = v.u + 0x7fff + ((v.u >> 16) & 1);
    return (short)(r >> 16);
}

// ===========================================================================
// Shared GEMM tile machinery (128x128 tile, BK=64, 4 waves 2x2, prefetch).
// LDS layout: [tile(8)][kchunk(8)][slot(16)] x 8 shorts, slot = l15^kc^tile.
// K-loop is unrolled x2 (requires kLen % 128 == 0) with register prefetch:
// next tile's global loads issue between the barriers, hiding HBM latency.
// ===========================================================================

#define GEMM_STAGE_A(av)                                                      \
    {                                                                         \
        _Pragma("unroll")                                                     \
        for (int c = 0; c < 4; c++) {                                         \
            const int kc = (akb >> 3) + c;                                    \
            bf16x8 s;                                                         \
            _Pragma("unroll")                                                 \
            for (int j = 0; j < 8; j++) s[j] = f2bf((av)[c*8 + j]);           \
            *(bf16x8*)&As[((amt*8 + kc)*16 + ((ar15 ^ kc ^ amt) & 15))*8] = s;\
        }                                                                     \
    }

#define GEMM_STAGE_B(bv)                                                      \
    {                                                                         \
        _Pragma("unroll")                                                     \
        for (int j = 0; j < 4; j++) {                                         \
            const int n  = bn0 + j;                                           \
            const int nt = n >> 4;                                            \
            bf16x8 s;                                                         \
            _Pragma("unroll")                                                 \
            for (int r = 0; r < 8; r++) s[r] = f2bf((bv)[r][j]);              \
            *(bf16x8*)&Bs[((nt*8 + bkg)*16 + (((n & 15) ^ bkg ^ nt) & 15))*8] = s; \
        }                                                                     \
    }

#define GEMM_LOAD_A(av, kb)                                                   \
    {                                                                         \
        _Pragma("unroll")                                                     \
        for (int i = 0; i < 8; i++)                                           \
            *(float4*)&(av)[i*4] = *(const float4*)(Ap + (kb) + i*4);         \
    }

#define GEMM_LOAD_B(bv, kb, strideN)                                          \
    {                                                                         \
        _Pragma("unroll")                                                     \
        for (int r = 0; r < 8; r++)                                           \
            *(float4*)&(bv)[r][0] = *(const float4*)(Wp + (long)((kb) + r) * (strideN)); \
    }

#define GEMM_COMPUTE()                                                        \
    {                                                                         \
        _Pragma("unroll")                                                     \
        for (int ks = 0; ks < 2; ks++) {                                      \
            const int kc = ks*4 + quad;                                       \
            bf16x8 af[4], bf[4];                                              \
            _Pragma("unroll")                                                 \
            for (int mt = 0; mt < 4; mt++) {                                  \
                const int MT = wr*4 + mt;                                     \
                af[mt] = *(const bf16x8*)&As[((MT*8 + kc)*16 + ((l15 ^ kc ^ MT) & 15))*8]; \
            }                                                                 \
            _Pragma("unroll")                                                 \
            for (int nt = 0; nt < 4; nt++) {                                  \
                const int NT = wc*4 + nt;                                     \
                bf[nt] = *(const bf16x8*)&Bs[((NT*8 + kc)*16 + ((l15 ^ kc ^ NT) & 15))*8]; \
            }                                                                 \
            _Pragma("unroll")                                                 \
            for (int mt = 0; mt < 4; mt++)                                    \
                _Pragma("unroll")                                             \
                for (int nt = 0; nt < 4; nt++)                                \
                    acc[mt][nt] = __builtin_amdgcn_mfma_f32_16x16x32_bf16(    \
                        af[mt], bf[nt], acc[mt][nt], 0, 0, 0);                \
        }                                                                     \
    }

#define GEMM_COMMON_IDS()                                                     \
    const int tid  = threadIdx.x;                                             \
    const int wave = tid >> 6;                                                \
    const int lane = tid & 63;                                                \
    const int l15  = lane & 15;                                               \
    const int quad = lane >> 4;                                               \
    const int wr   = wave >> 1;                                               \
    const int wc   = wave & 1;                                                \
    const int ar   = tid >> 1;                                                \
    const int akb  = (tid & 1) * 32;                                          \
    const int amt  = ar >> 4;                                                 \
    const int ar15 = ar & 15;                                                 \
    const int bn0  = (tid & 31) * 4;                                          \
    const int bkg  = tid >> 5;

// ---------------------------------------------------------------------------
// mfma_gemm: C = epilogue(A[:, kBeg:kBeg+kLen] @ W[kBeg:kBeg+kLen, :] + bias)
// MODE 2: C = addend + (*scale_ptr)*v ; MODE 3: C = v + addend ;
// MODE 4: C = raw acc (split-K partial; bias/addend ignored)
// kBeg = blockIdx.z * kStrideZ.
// ---------------------------------------------------------------------------
template<int MODE>
__global__ __launch_bounds__(256, 2) void mfma_gemm(
    const float* __restrict__ A, const float* __restrict__ W,
    const float* __restrict__ bias, float* __restrict__ C,
    int M, int N, int K, int kLen,
    long wStrideZ, long bStrideZ, long cStrideZ, long kStrideZ,
    const float* __restrict__ addend, const float* __restrict__ scale_ptr)
{
    if (blockIdx.z) {
        W    += (long)blockIdx.z * wStrideZ;
        bias += (long)blockIdx.z * bStrideZ;
        C    += (long)blockIdx.z * cStrideZ;
    }
    const int kBeg = (int)(blockIdx.z * kStrideZ);
    const int kEnd = kBeg + kLen;

    __shared__ __align__(16) short As[8192];
    __shared__ __align__(16) short Bs[8192];

    GEMM_COMMON_IDS();

    const int m0 = blockIdx.y * 128;
    const int n0 = blockIdx.x * 128;

    const float* Ap = A + (long)(m0 + ar) * K + akb;
    const float* Wp = W + (long)(bkg * 8) * N + n0 + bn0;

    f32x4 acc[4][4];
    #pragma unroll
    for (int i = 0; i < 4; i++)
        #pragma unroll
        for (int j = 0; j < 4; j++)
            acc[i][j] = (f32x4){0.f, 0.f, 0.f, 0.f};

    float a0[32], a1[32], b0[8][4], b1[8][4];
    GEMM_LOAD_A(a0, kBeg);
    GEMM_LOAD_B(b0, kBeg, N);

    for (int kb = kBeg; kb < kEnd; kb += 128) {
        GEMM_STAGE_A(a0); GEMM_STAGE_B(b0);
        __syncthreads();
        GEMM_LOAD_A(a1, kb + 64);
        GEMM_LOAD_B(b1, kb + 64, N);
        GEMM_COMPUTE();
        __syncthreads();
        GEMM_STAGE_A(a1); GEMM_STAGE_B(b1);
        __syncthreads();
        if (kb + 128 < kEnd) {
            GEMM_LOAD_A(a0, kb + 128);
            GEMM_LOAD_B(b0, kb + 128, N);
        }
        GEMM_COMPUTE();
        __syncthreads();
    }

    float scale = 0.0f;
    if (MODE == 2) scale = *scale_ptr;
    #pragma unroll
    for (int nt = 0; nt < 4; nt++) {
        const int col = n0 + wc*64 + nt*16 + l15;
        const float bcol = (MODE == 4) ? 0.0f : bias[col];
        #pragma unroll
        for (int mt = 0; mt < 4; mt++) {
            #pragma unroll
            for (int r = 0; r < 4; r++) {
                const long row = m0 + wr*64 + mt*16 + quad*4 + r;
                float v = acc[mt][nt][r] + bcol;
                if (MODE == 2) v = addend[row*N + col] + scale * v;
                if (MODE == 3) v = v + addend[row*N + col];
                C[row*N + col] = v;
            }
        }
    }
}

// ---------------------------------------------------------------------------
// xproj: fused GEMM1+2+4. A = x [2048,768], K=768. 57 N-tiles of 128:
//   tiles  0..11 -> kv   = x@W_kv + b_kv          (out bufKV, stride 1536)
//   tiles 12..47 -> q[f] = x@W_q[f] + b_q[f]      (out bufQ + f*BS*768, stride 768)
//   tiles 48..56 -> g1   = gelu(x@W_g1 + b_g1)    (out bufG1, stride 1152)
// ---------------------------------------------------------------------------
__global__ __launch_bounds__(256, 2) void xproj_gemm(
    const float* __restrict__ x,
    const float* __restrict__ W_kv, const float* __restrict__ b_kv, float* __restrict__ bufKV,
    const float* __restrict__ W_q,  const float* __restrict__ b_q,  float* __restrict__ bufQ,
    const float* __restrict__ W_g1, const float* __restrict__ b_g1, float* __restrict__ bufG1)
{
    __shared__ __align__(16) short As[8192];
    __shared__ __align__(16) short Bs[8192];

    GEMM_COMMON_IDS();

    const int ntile = blockIdx.x;
    const int m0 = blockIdx.y * 128;

    const float* Wseg; const float* bseg; float* Cseg;
    int Nw, ncol; bool doGelu = false;
    if (ntile < 12) {
        Wseg = W_kv; bseg = b_kv; Cseg = bufKV; Nw = 1536; ncol = ntile * 128;
    } else if (ntile < 48) {
        const int t = ntile - 12; const int f = t / 6;
        ncol = (t % 6) * 128;
        Wseg = W_q + (long)f * D_ * D_; bseg = b_q + f * D_;
        Cseg = bufQ + (long)f * BS_ * D_; Nw = 768;
    } else {
        const int t = ntile - 48;
        Wseg = W_g1; bseg = b_g1; Cseg = bufG1; Nw = 1152; ncol = t * 128;
        doGelu = true;
    }

    const float* Ap = x + (long)(m0 + ar) * D_ + akb;
    const float* Wp = Wseg + (long)(bkg * 8) * Nw + ncol + bn0;

    f32x4 acc[4][4];
    #pragma unroll
    for (int i = 0; i < 4; i++)
        #pragma unroll
        for (int j = 0; j < 4; j++)
            acc[i][j] = (f32x4){0.f, 0.f, 0.f, 0.f};

    float a0[32], a1[32], b0[8][4], b1[8][4];
    GEMM_LOAD_A(a0, 0);
    GEMM_LOAD_B(b0, 0, Nw);

    for (int kb = 0; kb < D_; kb += 128) {
        GEMM_STAGE_A(a0); GEMM_STAGE_B(b0);
        __syncthreads();
        GEMM_LOAD_A(a1, kb + 64);
        GEMM_LOAD_B(b1, kb + 64, Nw);
        GEMM_COMPUTE();
        __syncthreads();
        GEMM_STAGE_A(a1); GEMM_STAGE_B(b1);
        __syncthreads();
        if (kb + 128 < D_) {
            GEMM_LOAD_A(a0, kb + 128);
            GEMM_LOAD_B(b0, kb + 128, Nw);
        }
        GEMM_COMPUTE();
        __syncthreads();
    }

    #pragma unroll
    for (int nt = 0; nt < 4; nt++) {
        const int col = ncol + wc*64 + nt*16 + l15;
        const float bcol = bseg[col];
        #pragma unroll
        for (int mt = 0; mt < 4; mt++) {
            #pragma unroll
            for (int r = 0; r < 4; r++) {
                const long row = m0 + wr*64 + mt*16 + quad*4 + r;
                float v = acc[mt][nt][r] + bcol;
                if (doGelu) v = gelu_exact(v);
                Cseg[row*Nw + col] = v;
            }
        }
    }
}

// ---------------------------------------------------------------------------
// reduce kernels for split-K partials
// ---------------------------------------------------------------------------
__global__ __launch_bounds__(256) void reduce_m1(
    const float* __restrict__ p, const float* __restrict__ bias,
    float* __restrict__ out)   // gelu(p0+p1+p2+bias), [2048,1536]
{
    const int idx = blockIdx.x * 256 + threadIdx.x;          // float4 index
    const int col4 = idx % (D2_/4);
    const long MN4 = (long)BS_ * D2_ / 4;
    float4 a = ((const float4*)p)[idx];
    float4 b = ((const float4*)p)[idx + MN4];
    float4 c = ((const float4*)p)[idx + 2*MN4];
    float4 bb = ((const float4*)bias)[col4];
    float4 o;
    o.x = gelu_exact(a.x + b.x + c.x + bb.x);
    o.y = gelu_exact(a.y + b.y + c.y + bb.y);
    o.z = gelu_exact(a.z + b.z + c.z + bb.z);
    o.w = gelu_exact(a.w + b.w + c.w + bb.w);
    ((float4*)out)[idx] = o;
}

__global__ __launch_bounds__(256) void reduce_out(
    const float* __restrict__ p, const float* __restrict__ bias,
    const float* __restrict__ x, float* __restrict__ out)  // x + p0+p1 + bias, [2048,768]
{
    const int idx = blockIdx.x * 256 + threadIdx.x;
    const int col4 = idx % (D_/4);
    const long MN4 = (long)BS_ * D_ / 4;
    float4 a = ((const float4*)p)[idx];
    float4 b = ((const float4*)p)[idx + MN4];
    float4 xx = ((const float4*)x)[idx];
    float4 bb = ((const float4*)bias)[col4];
    float4 o;
    o.x = xx.x + a.x + b.x + bb.x;
    o.y = xx.y + a.y + b.y + bb.y;
    o.z = xx.z + a.z + b.z + bb.z;
    o.w = xx.w + a.w + b.w + bb.w;
    ((float4*)out)[idx] = o;
}

// ---------------------------------------------------------------------------
// MFMA flash attention (unchanged)
// ---------------------------------------------------------------------------
__device__ __forceinline__ int swz64(int row, int col) {
    return row*64 + ((col & 7) | ((((col >> 3) ^ row) & 7) << 3));
}

__global__ __launch_bounds__(256) void attn_mfma(
    const float* __restrict__ q,
    const float* __restrict__ kv,
    float* __restrict__ stacked)
{
    __shared__ __align__(16) short Ks[64*64];
    __shared__ __align__(16) short Vt[64*64];
    __shared__ __align__(16) short Ps[4][16*64];

    const int bx = blockIdx.x;
    const int qt = bx & 15;
    const int rest = bx >> 4;
    const int h = rest % 12;
    const int r2 = rest / 12;
    const int f = r2 % 6;
    const int b = r2 / 6;

    const int tid  = threadIdx.x;
    const int wave = tid >> 6;
    const int lane = tid & 63;
    const int l15  = lane & 15;
    const int quad = lane >> 4;

    const int skey = tid >> 2;
    const int sdc  = (tid & 3) * 4;
    const float* kbase = kv + ((long)(b*S_) + skey) * D2_ + h*64;

    bf16x8 aq[2];
    {
        const float* qp = q + (((long)f*B_ + b)*S_ + qt*64 + wave*16 + l15)*(long)D_
                          + h*64 + quad*8;
        #pragma unroll
        for (int ks = 0; ks < 2; ks++) {
            float4 q0 = *(const float4*)(qp + ks*32);
            float4 q1 = *(const float4*)(qp + ks*32 + 4);
            bf16x8 a;
            a[0]=f2bf(q0.x*0.125f); a[1]=f2bf(q0.y*0.125f);
            a[2]=f2bf(q0.z*0.125f); a[3]=f2bf(q0.w*0.125f);
            a[4]=f2bf(q1.x*0.125f); a[5]=f2bf(q1.y*0.125f);
            a[6]=f2bf(q1.z*0.125f); a[7]=f2bf(q1.w*0.125f);
            aq[ks] = a;
        }
    }

    short* Psw = Ps[wave];

    f32x4 o[4];
    #pragma unroll
    for (int nt = 0; nt < 4; nt++) o[nt] = (f32x4){0.f,0.f,0.f,0.f};
    float m_i[4] = {-INFINITY,-INFINITY,-INFINITY,-INFINITY};
    float l_i[4] = {0.f,0.f,0.f,0.f};

    for (int kt = 0; kt < 16; kt++) {
        const float* kb = kbase + (long)kt*64*D2_;
        #pragma unroll
        for (int c = 0; c < 4; c++) {
            const int dim = sdc + 16*c;
            float4 kf = *(const float4*)(kb + dim);
            float4 vf = *(const float4*)(kb + D_ + dim);
            unsigned k01 = (unsigned short)f2bf(kf.x) |
                           ((unsigned)(unsigned short)f2bf(kf.y) << 16);
            unsigned k23 = (unsigned short)f2bf(kf.z) |
                           ((unsigned)(unsigned short)f2bf(kf.w) << 16);
            uint2 kp; kp.x = k01; kp.y = k23;
            *(uint2*)&Ks[swz64(skey, dim)] = kp;
            Vt[swz64(dim+0, skey)] = f2bf(vf.x);
            Vt[swz64(dim+1, skey)] = f2bf(vf.y);
            Vt[swz64(dim+2, skey)] = f2bf(vf.z);
            Vt[swz64(dim+3, skey)] = f2bf(vf.w);
        }
        __syncthreads();

        f32x4 st[4];
        #pragma unroll
        for (int nt = 0; nt < 4; nt++) st[nt] = (f32x4){0.f,0.f,0.f,0.f};
        #pragma unroll
        for (int nt = 0; nt < 4; nt++) {
            const int key = nt*16 + l15;
            #pragma unroll
            for (int ks = 0; ks < 2; ks++) {
                const int chunk = ks*4 + quad;
                const bf16x8 kbf = *(const bf16x8*)
                    &Ks[key*64 + (((chunk ^ key) & 7) << 3)];
                st[nt] = __builtin_amdgcn_mfma_f32_16x16x32_bf16(aq[ks], kbf, st[nt], 0, 0, 0);
            }
        }

        float alpha[4];
        #pragma unroll
        for (int r = 0; r < 4; r++) {
            float t = fmaxf(fmaxf(st[0][r], st[1][r]), fmaxf(st[2][r], st[3][r]));
            t = fmaxf(t, __shfl_xor(t, 1));
            t = fmaxf(t, __shfl_xor(t, 2));
            t = fmaxf(t, __shfl_xor(t, 4));
            t = fmaxf(t, __shfl_xor(t, 8));
            const float mn = fmaxf(m_i[r], t);
            const float a  = __expf(m_i[r] - mn);
            m_i[r] = mn;
            float ls = 0.f;
            const int row = quad*4 + r;
            #pragma unroll
            for (int nt = 0; nt < 4; nt++) {
                const float p = __expf(st[nt][r] - mn);
                ls += p;
                Psw[swz64(row, nt*16 + l15)] = f2bf(p);
            }
            ls += __shfl_xor(ls, 1);
            ls += __shfl_xor(ls, 2);
            ls += __shfl_xor(ls, 4);
            ls += __shfl_xor(ls, 8);
            l_i[r] = l_i[r]*a + ls;
            alpha[r] = a;
        }
        #pragma unroll
        for (int nt = 0; nt < 4; nt++) {
            o[nt][0] *= alpha[0]; o[nt][1] *= alpha[1];
            o[nt][2] *= alpha[2]; o[nt][3] *= alpha[3];
        }

        bf16x8 pa[2];
        #pragma unroll
        for (int ks = 0; ks < 2; ks++) {
            const int chunk = ks*4 + quad;
            pa[ks] = *(const bf16x8*)&Psw[l15*64 + (((chunk ^ l15) & 7) << 3)];
        }

        #pragma unroll
        for (int nt = 0; nt < 4; nt++) {
            const int dim = nt*16 + l15;
            #pragma unroll
            for (int ks = 0; ks < 2; ks++) {
                const int chunk = ks*4 + quad;
                const bf16x8 vb = *(const bf16x8*)
                    &Vt[dim*64 + (((chunk ^ dim) & 7) << 3)];
                o[nt] = __builtin_amdgcn_mfma_f32_16x16x32_bf16(pa[ks], vb, o[nt], 0, 0, 0);
            }
        }
        __syncthreads();
    }

    float inv[4];
    #pragma unroll
    for (int r = 0; r < 4; r++) inv[r] = 1.0f / l_i[r];
    const long rowBase = (long)(b*S_ + qt*64 + wave*16);
    #pragma unroll
    for (int nt = 0; nt < 4; nt++) {
        #pragma unroll
        for (int r = 0; r < 4; r++) {
            const long row = rowBase + quad*4 + r;
            stacked[row*FD_ + f*D_ + h*64 + nt*16 + l15] = o[nt][r] * inv[r];
        }
    }
}

// ---------------------------------------------------------------------------
// gates[m,f] = softmax_f( g1[m,:] @ W_g2 + b_g2 ), one wave per row
// ---------------------------------------------------------------------------
__global__ __launch_bounds__(64) void gates_kernel(
    const float* __restrict__ g1, const float* __restrict__ W_g2,
    const float* __restrict__ b_g2, float* __restrict__ gates)
{
    const int m = blockIdx.x;
    const int lane = threadIdx.x;
    float p[6] = {0.f,0.f,0.f,0.f,0.f,0.f};
    for (int k = lane; k < FD4_; k += 64) {
        float g = g1[(long)m*FD4_ + k];
        #pragma unroll
        for (int f = 0; f < 6; f++) p[f] += g * W_g2[k*6 + f];
    }
    #pragma unroll
    for (int f = 0; f < 6; f++) {
        float v = p[f];
        #pragma unroll
        for (int off = 1; off < 64; off <<= 1) v += __shfl_xor(v, off);
        p[f] = v + b_g2[f];
    }
    float mx = p[0];
    #pragma unroll
    for (int f = 1; f < 6; f++) mx = fmaxf(mx, p[f]);
    float se = 0.f;
    #pragma unroll
    for (int f = 0; f < 6; f++) { p[f] = expf(p[f] - mx); se += p[f]; }
    const float inv = 1.0f / se;
    if (lane < 6) gates[m*6 + lane] = p[lane] * inv;
}

// ---------------------------------------------------------------------------
// comb[m,d] = sum_f mixed[m, f*768+d] * gates[m,f]
// ---------------------------------------------------------------------------
__global__ __launch_bounds__(256) void combine_kernel(
    const float* __restrict__ mixed, const float* __restrict__ gates,
    float* __restrict__ comb)
{
    const int idx = blockIdx.x * 256 + threadIdx.x;
    const int m = idx / 192;
    const int d4 = idx - m*192;
    const float4* mrow = (const float4*)(mixed + (long)m * FD_);
    float4 a = {0.f,0.f,0.f,0.f};
    #pragma unroll
    for (int f = 0; f < 6; f++) {
        float g = gates[m*6 + f];
        float4 v = mrow[f*192 + d4];
        a.x += g*v.x; a.y += g*v.y; a.z += g*v.z; a.w += g*v.w;
    }
    ((float4*)comb)[idx] = a;
}

// ---------------------------------------------------------------------------
// In-place LayerNorm over D=768, one block per row
// ---------------------------------------------------------------------------
__global__ __launch_bounds__(256) void ln_kernel(
    const float* __restrict__ preY,
    const float* __restrict__ ln_g, const float* __restrict__ ln_b,
    float* __restrict__ out)
{
    __shared__ float red[8];
    const int m = blockIdx.x;
    const float* row = preY + (long)m * D_;
    const int tid = threadIdx.x;
    float vals[3];
    float s = 0.f, s2 = 0.f;
    #pragma unroll
    for (int i = 0; i < 3; i++) {
        float v = row[tid + 256*i];
        vals[i] = v;
        s += v; s2 += v*v;
    }
    #pragma unroll
    for (int off = 32; off >= 1; off >>= 1) {
        s  += __shfl_xor(s, off);
        s2 += __shfl_xor(s2, off);
    }
    const int wave = tid >> 6;
    if ((tid & 63) == 0) { red[wave*2] = s; red[wave*2+1] = s2; }
    __syncthreads();
    s  = red[0]+red[2]+red[4]+red[6];
    s2 = red[1]+red[3]+red[5]+red[7];
    const float mu  = s * (1.0f/D_);
    const float var = s2 * (1.0f/D_) - mu*mu;
    const float inv = rsqrtf(var + 1e-5f);
    #pragma unroll
    for (int i = 0; i < 3; i++) {
        const int d = tid + 256*i;
        out[(long)m*D_ + d] = (vals[i] - mu) * inv * ln_g[d] + ln_b[d];
    }
}

// ---------------------------------------------------------------------------
extern "C" void kernel_launch(void* const* d_in, const int* in_sizes, int n_in,
                              void* d_out, int out_size, void* d_ws, size_t ws_size,
                              hipStream_t stream)
{
    const float* x     = (const float*)d_in[0];
    const float* W_kv  = (const float*)d_in[1];
    const float* b_kv  = (const float*)d_in[2];
    const float* W_q   = (const float*)d_in[3];
    const float* b_q   = (const float*)d_in[4];
    const float* W_m1  = (const float*)d_in[5];
    const float* b_m1  = (const float*)d_in[6];
    const float* W_m2  = (const float*)d_in[7];
    const float* b_m2  = (const float*)d_in[8];
    const float* cross = (const float*)d_in[9];
    const float* W_g1  = (const float*)d_in[10];
    const float* b_g1  = (const float*)d_in[11];
    const float* W_g2  = (const float*)d_in[12];
    const float* b_g2  = (const float*)d_in[13];
    const float* W_out = (const float*)d_in[14];
    const float* b_out = (const float*)d_in[15];
    const float* ln_g  = (const float*)d_in[16];
    const float* ln_b  = (const float*)d_in[17];
    float* out = (float*)d_out;

    // workspace: bufA = q -> m1 partials -> mixed ; bufB = kv -> h1 ;
    // stacked = attn out -> out partials ; bufC = g1 -> comb
    float* ws      = (float*)d_ws;
    float* bufA    = ws;                                   // 9,437,184 fl
    float* bufB    = bufA + (size_t)F_*BS_*D_;             // 3,145,728 fl
    float* stacked = bufB + (size_t)BS_*D2_;               // 9,437,184 fl
    float* bufC    = stacked + (size_t)BS_*FD_;            // 2,359,296 fl
    float* gates   = bufC + (size_t)BS_*FD4_;              // 12,288 fl

    dim3 blk(256);

    // 1. fused x-projections: kv -> bufB, q -> bufA, g1 -> bufC  (912 blocks)
    xproj_gemm<<<dim3(57, 16, 1), blk, 0, stream>>>(
        x, W_kv, b_kv, bufB, W_q, b_q, bufA, W_g1, b_g1, bufC);
    // 2. MFMA flash attention -> stacked
    attn_mfma<<<dim3(16 * 144), blk, 0, stream>>>(bufA, bufB, stacked);
    // 3. gates = softmax(g1 @ W_g2 + b_g2)
    gates_kernel<<<dim3(BS_), dim3(64), 0, stream>>>(bufC, W_g2, b_g2, gates);
    // 4. h1 partials: split-K x3 of stacked @ W_m1 -> bufA      (576 blocks)
    mfma_gemm<4><<<dim3(D2_/128, BS_/128, 3), blk, 0, stream>>>(
        stacked, W_m1, b_m1, bufA, BS_, D2_, FD_, FD_/3,
        0, 0, (long)BS_*D2_, FD_/3, nullptr, nullptr);
    // 5. h1 = gelu(sum partials + b_m1) -> bufB
    reduce_m1<<<dim3(BS_*D2_/4/256), blk, 0, stream>>>(bufA, b_m1, bufB);
    // 6. mixed = stacked + cross*(h1 @ W_m2 + b_m2) -> bufA     (576 blocks)
    mfma_gemm<2><<<dim3(FD_/128, BS_/128, 1), blk, 0, stream>>>(
        bufB, W_m2, b_m2, bufA, BS_, FD_, D2_, D2_,
        0, 0, 0, 0, stacked, cross);
    // 7. comb = sum_f mixed*gates -> bufC
    combine_kernel<<<dim3(BS_*(D_/4)/256), blk, 0, stream>>>(bufA, gates, bufC);
    // 8. out partials: split-K x2 of comb @ W_out -> stacked    (192 blocks)
    mfma_gemm<4><<<dim3(D_/128, BS_/128, 2), blk, 0, stream>>>(
        bufC, W_out, b_out, stacked, BS_, D_, D_, D_/2,
        0, 0, (long)BS_*D_, D_/2, nullptr, nullptr);
    // 9. preY = x + sum partials + b_out -> d_out
    reduce_out<<<dim3(BS_*D_/4/256), blk, 0, stream>>>(stacked, b_out, x, out);
    // 10. LayerNorm in place
    ln_kernel<<<dim3(BS_), blk, 0, stream>>>(out, ln_g, ln_b, out);
}

// Round 5
// 678.158 us; speedup vs baseline: 3.5755x; 1.0351x over previous
//
#include <hip/hip_runtime.h>
#include <hip/hip_bf16.h>

#define B_ 2
#define S_ 1024
#define D_ 768
#define H_ 12
#define F_ 6
#define DH_ 64
#define BS_ (B_*S_)   // 2048
#define D2_ (2*D_)    // 1536
#define FD_ (F_*D_)   // 4608
#define FD4_ (FD_/4)  // 1152

typedef __attribute__((ext_vector_type(8))) short bf16x8;
typedef __attribute__((ext_vector_type(4))) float f32x4;

__device__ __forceinline__ float gelu_exact(float x) {
    return 0.5f * x * (1.0f + erff(x * 0.70710678118654752f));
}

// fp32 -> bf16 bits, round-to-nearest-even
__device__ __forceinline__ short f2bf(float f) {
    union { float f; unsigned u; } v; v.f = f;
    unsigned r = v.u + 0x7fff + ((v.u >> 16) & 1);
    return (short)(r >> 16);
}

// ===========================================================================
// Shared GEMM tile machinery (128x128 tile, BK=64, 4 waves 2x2, prefetch).
// ===========================================================================

#define GEMM_STAGE_A(av)                                                      \
    {                                                                         \
        _Pragma("unroll")                                                     \
        for (int c = 0; c < 4; c++) {                                         \
            const int kc = (akb >> 3) + c;                                    \
            bf16x8 s;                                                         \
            _Pragma("unroll")                                                 \
            for (int j = 0; j < 8; j++) s[j] = f2bf((av)[c*8 + j]);           \
            *(bf16x8*)&As[((amt*8 + kc)*16 + ((ar15 ^ kc ^ amt) & 15))*8] = s;\
        }                                                                     \
    }

#define GEMM_STAGE_B(bv)                                                      \
    {                                                                         \
        _Pragma("unroll")                                                     \
        for (int j = 0; j < 4; j++) {                                         \
            const int n  = bn0 + j;                                           \
            const int nt = n >> 4;                                            \
            bf16x8 s;                                                         \
            _Pragma("unroll")                                                 \
            for (int r = 0; r < 8; r++) s[r] = f2bf((bv)[r][j]);              \
            *(bf16x8*)&Bs[((nt*8 + bkg)*16 + (((n & 15) ^ bkg ^ nt) & 15))*8] = s; \
        }                                                                     \
    }

#define GEMM_LOAD_A(av, kb)                                                   \
    {                                                                         \
        _Pragma("unroll")                                                     \
        for (int i = 0; i < 8; i++)                                           \
            *(float4*)&(av)[i*4] = *(const float4*)(Ap + (kb) + i*4);         \
    }

#define GEMM_LOAD_B(bv, kb, strideN)                                          \
    {                                                                         \
        _Pragma("unroll")                                                     \
        for (int r = 0; r < 8; r++)                                           \
            *(float4*)&(bv)[r][0] = *(const float4*)(Wp + (long)((kb) + r) * (strideN)); \
    }

#define GEMM_COMPUTE()                                                        \
    {                                                                         \
        _Pragma("unroll")                                                     \
        for (int ks = 0; ks < 2; ks++) {                                      \
            const int kc = ks*4 + quad;                                       \
            bf16x8 af[4], bf[4];                                              \
            _Pragma("unroll")                                                 \
            for (int mt = 0; mt < 4; mt++) {                                  \
                const int MT = wr*4 + mt;                                     \
                af[mt] = *(const bf16x8*)&As[((MT*8 + kc)*16 + ((l15 ^ kc ^ MT) & 15))*8]; \
            }                                                                 \
            _Pragma("unroll")                                                 \
            for (int nt = 0; nt < 4; nt++) {                                  \
                const int NT = wc*4 + nt;                                     \
                bf[nt] = *(const bf16x8*)&Bs[((NT*8 + kc)*16 + ((l15 ^ kc ^ NT) & 15))*8]; \
            }                                                                 \
            _Pragma("unroll")                                                 \
            for (int mt = 0; mt < 4; mt++)                                    \
                _Pragma("unroll")                                             \
                for (int nt = 0; nt < 4; nt++)                                \
                    acc[mt][nt] = __builtin_amdgcn_mfma_f32_16x16x32_bf16(    \
                        af[mt], bf[nt], acc[mt][nt], 0, 0, 0);                \
        }                                                                     \
    }

#define GEMM_COMMON_IDS()                                                     \
    const int tid  = threadIdx.x;                                             \
    const int wave = tid >> 6;                                                \
    const int lane = tid & 63;                                                \
    const int l15  = lane & 15;                                               \
    const int quad = lane >> 4;                                               \
    const int wr   = wave >> 1;                                               \
    const int wc   = wave & 1;                                                \
    const int ar   = tid >> 1;                                                \
    const int akb  = (tid & 1) * 32;                                          \
    const int amt  = ar >> 4;                                                 \
    const int ar15 = ar & 15;                                                 \
    const int bn0  = (tid & 31) * 4;                                          \
    const int bkg  = tid >> 5;

// ---------------------------------------------------------------------------
// mfma_gemm: MODE 2: C = addend + (*scale_ptr)*v ; MODE 4: raw split-K partial
// ---------------------------------------------------------------------------
template<int MODE>
__global__ __launch_bounds__(256, 2) void mfma_gemm(
    const float* __restrict__ A, const float* __restrict__ W,
    const float* __restrict__ bias, float* __restrict__ C,
    int M, int N, int K, int kLen,
    long wStrideZ, long bStrideZ, long cStrideZ, long kStrideZ,
    const float* __restrict__ addend, const float* __restrict__ scale_ptr)
{
    if (blockIdx.z) {
        W    += (long)blockIdx.z * wStrideZ;
        bias += (long)blockIdx.z * bStrideZ;
        C    += (long)blockIdx.z * cStrideZ;
    }
    const int kBeg = (int)(blockIdx.z * kStrideZ);
    const int kEnd = kBeg + kLen;

    __shared__ __align__(16) short As[8192];
    __shared__ __align__(16) short Bs[8192];

    GEMM_COMMON_IDS();

    const int m0 = blockIdx.y * 128;
    const int n0 = blockIdx.x * 128;

    const float* Ap = A + (long)(m0 + ar) * K + akb;
    const float* Wp = W + (long)(bkg * 8) * N + n0 + bn0;

    f32x4 acc[4][4];
    #pragma unroll
    for (int i = 0; i < 4; i++)
        #pragma unroll
        for (int j = 0; j < 4; j++)
            acc[i][j] = (f32x4){0.f, 0.f, 0.f, 0.f};

    float a0[32], a1[32], b0[8][4], b1[8][4];
    GEMM_LOAD_A(a0, kBeg);
    GEMM_LOAD_B(b0, kBeg, N);

    for (int kb = kBeg; kb < kEnd; kb += 128) {
        GEMM_STAGE_A(a0); GEMM_STAGE_B(b0);
        __syncthreads();
        GEMM_LOAD_A(a1, kb + 64);
        GEMM_LOAD_B(b1, kb + 64, N);
        GEMM_COMPUTE();
        __syncthreads();
        GEMM_STAGE_A(a1); GEMM_STAGE_B(b1);
        __syncthreads();
        if (kb + 128 < kEnd) {
            GEMM_LOAD_A(a0, kb + 128);
            GEMM_LOAD_B(b0, kb + 128, N);
        }
        GEMM_COMPUTE();
        __syncthreads();
    }

    float scale = 0.0f;
    if (MODE == 2) scale = *scale_ptr;
    #pragma unroll
    for (int nt = 0; nt < 4; nt++) {
        const int col = n0 + wc*64 + nt*16 + l15;
        const float bcol = (MODE == 4) ? 0.0f : bias[col];
        #pragma unroll
        for (int mt = 0; mt < 4; mt++) {
            #pragma unroll
            for (int r = 0; r < 4; r++) {
                const long row = m0 + wr*64 + mt*16 + quad*4 + r;
                float v = acc[mt][nt][r] + bcol;
                if (MODE == 2) v = addend[row*N + col] + scale * v;
                C[row*N + col] = v;
            }
        }
    }
}

// ---------------------------------------------------------------------------
// xproj: fused projections of x. 57 N-tiles of 128:
//   tiles  0..11 -> kv fp32 [B*S,1536]
//   tiles 12..47 -> q bf16 pre-scaled*0.125 -> qb [F][B][H][S][64]
//   tiles 48..56 -> g1 = gelu(..) fp32 [B*S,1152]
// ---------------------------------------------------------------------------
__global__ __launch_bounds__(256, 2) void xproj_gemm(
    const float* __restrict__ x,
    const float* __restrict__ W_kv, const float* __restrict__ b_kv, float* __restrict__ bufKV,
    const float* __restrict__ W_q,  const float* __restrict__ b_q,  short* __restrict__ qb,
    const float* __restrict__ W_g1, const float* __restrict__ b_g1, float* __restrict__ bufG1)
{
    __shared__ __align__(16) short As[8192];
    __shared__ __align__(16) short Bs[8192];

    GEMM_COMMON_IDS();

    const int ntile = blockIdx.x;
    const int m0 = blockIdx.y * 128;

    const float* Wseg; const float* bseg; float* Cseg = nullptr;
    int Nw, ncol, fidx = 0, mode;   // mode 0=kv,1=q,2=g1
    if (ntile < 12) {
        Wseg = W_kv; bseg = b_kv; Cseg = bufKV; Nw = 1536; ncol = ntile * 128; mode = 0;
    } else if (ntile < 48) {
        const int t = ntile - 12; fidx = t / 6;
        ncol = (t % 6) * 128;
        Wseg = W_q + (long)fidx * D_ * D_; bseg = b_q + fidx * D_;
        Nw = 768; mode = 1;
    } else {
        const int t = ntile - 48;
        Wseg = W_g1; bseg = b_g1; Cseg = bufG1; Nw = 1152; ncol = t * 128; mode = 2;
    }

    const float* Ap = x + (long)(m0 + ar) * D_ + akb;
    const float* Wp = Wseg + (long)(bkg * 8) * Nw + ncol + bn0;

    f32x4 acc[4][4];
    #pragma unroll
    for (int i = 0; i < 4; i++)
        #pragma unroll
        for (int j = 0; j < 4; j++)
            acc[i][j] = (f32x4){0.f, 0.f, 0.f, 0.f};

    float a0[32], a1[32], b0[8][4], b1[8][4];
    GEMM_LOAD_A(a0, 0);
    GEMM_LOAD_B(b0, 0, Nw);

    for (int kb = 0; kb < D_; kb += 128) {
        GEMM_STAGE_A(a0); GEMM_STAGE_B(b0);
        __syncthreads();
        GEMM_LOAD_A(a1, kb + 64);
        GEMM_LOAD_B(b1, kb + 64, Nw);
        GEMM_COMPUTE();
        __syncthreads();
        GEMM_STAGE_A(a1); GEMM_STAGE_B(b1);
        __syncthreads();
        if (kb + 128 < D_) {
            GEMM_LOAD_A(a0, kb + 128);
            GEMM_LOAD_B(b0, kb + 128, Nw);
        }
        GEMM_COMPUTE();
        __syncthreads();
    }

    if (mode == 1) {
        // bf16 pre-scaled write into qb [F][B][H][S][64]
        const int bb = m0 >> 10;
        const int sBase = (m0 & 1023) + wr*64;
        #pragma unroll
        for (int nt = 0; nt < 4; nt++) {
            const int col = ncol + wc*64 + nt*16 + l15;   // 0..767
            const int hh = col >> 6, dd = col & 63;
            const float bcol = bseg[col];
            short* qBase = qb + ((((long)fidx*B_ + bb)*H_ + hh)*S_)*64 + dd;
            #pragma unroll
            for (int mt = 0; mt < 4; mt++) {
                #pragma unroll
                for (int r = 0; r < 4; r++) {
                    const int s = sBase + mt*16 + quad*4 + r;
                    qBase[(long)s*64] = f2bf((acc[mt][nt][r] + bcol) * 0.125f);
                }
            }
        }
    } else {
        #pragma unroll
        for (int nt = 0; nt < 4; nt++) {
            const int col = ncol + wc*64 + nt*16 + l15;
            const float bcol = bseg[col];
            #pragma unroll
            for (int mt = 0; mt < 4; mt++) {
                #pragma unroll
                for (int r = 0; r < 4; r++) {
                    const long row = m0 + wr*64 + mt*16 + quad*4 + r;
                    float v = acc[mt][nt][r] + bcol;
                    if (mode == 2) v = gelu_exact(v);
                    Cseg[row*Nw + col] = v;
                }
            }
        }
    }
}

// ---------------------------------------------------------------------------
// repack_kv: kv fp32 [B*S,1536] -> Kb bf16 [B][H][S][64], Vt bf16 [B][H][64][S]
// One block per (b,h,s-tile of 64). V transposed through swizzled LDS.
// ---------------------------------------------------------------------------
__global__ __launch_bounds__(256) void repack_kv(
    const float* __restrict__ kvf, short* __restrict__ Kb, short* __restrict__ Vtb)
{
    __shared__ __align__(16) short T[64*64];
    const int bx = blockIdx.x;         // b*192 + h*16 + st
    const int st = bx & 15;
    const int h  = (bx >> 4) % 12;
    const int b  = bx / 192;
    const int tid = threadIdx.x;
    const int s_loc = tid & 63;
    const int dch  = (tid >> 6) * 16;
    const int s0 = st * 64;

    const float* kr = kvf + (long)(b*S_ + s0 + s_loc) * D2_ + h*64 + dch;
    float v[16];

    // K straight copy (16 dims/thread, contiguous)
    #pragma unroll
    for (int i = 0; i < 4; i++) *(float4*)&v[i*4] = *(const float4*)(kr + i*4);
    {
        short* kw = Kb + ((long)(b*H_ + h)*S_ + s0 + s_loc)*64 + dch;
        bf16x8 p0, p1;
        #pragma unroll
        for (int i = 0; i < 8; i++) { p0[i] = f2bf(v[i]); p1[i] = f2bf(v[8+i]); }
        *(bf16x8*)&kw[0] = p0;
        *(bf16x8*)&kw[8] = p1;
    }

    // V transpose
    #pragma unroll
    for (int i = 0; i < 4; i++) *(float4*)&v[i*4] = *(const float4*)(kr + D_ + i*4);
    #pragma unroll
    for (int i = 0; i < 16; i++) {
        const int d = dch + i;
        T[d*64 + ((((s_loc >> 3) ^ d) & 7) << 3) + (s_loc & 7)] = f2bf(v[i]);
    }
    __syncthreads();
    const int d_loc = tid >> 2;
    const int sc = (tid & 3) * 16;
    const int c0 = sc >> 3;
    bf16x8 o0 = *(const bf16x8*)&T[d_loc*64 + (((c0 ^ d_loc) & 7) << 3)];
    bf16x8 o1 = *(const bf16x8*)&T[d_loc*64 + ((((c0+1) ^ d_loc) & 7) << 3)];
    short* vw = Vtb + ((long)(b*H_ + h)*64 + d_loc)*S_ + s0 + sc;
    *(bf16x8*)&vw[0] = o0;
    *(bf16x8*)&vw[8] = o1;
}

// ---------------------------------------------------------------------------
// MFMA flash attention v2: pre-packed bf16 inputs, 128 q-rows/block (32/wave).
// qb [F][B][H][S][64] (pre-scaled), Kb [B][H][S][64], Vt [B][H][64][S].
// LDS tiles 64x64 bf16, chunk-XOR swizzle; K-tiles of 64 keys.
// ---------------------------------------------------------------------------
__global__ __launch_bounds__(256, 2) void attn_mfma2(
    const short* __restrict__ qb,
    const short* __restrict__ Kb,
    const short* __restrict__ Vt,
    float* __restrict__ stacked)
{
    __shared__ __align__(16) short Ks[64*64];
    __shared__ __align__(16) short Vs[64*64];
    __shared__ __align__(16) short Ps[4][32*64];

    const int bx = blockIdx.x;
    const int qt = bx & 7;            // 8 q-tiles of 128 rows
    const int rest = bx >> 3;         // 0..143
    const int h = rest % 12;
    const int r2 = rest / 12;
    const int f = r2 % 6;
    const int b = r2 / 6;

    const int tid  = threadIdx.x;
    const int wave = tid >> 6;
    const int lane = tid & 63;
    const int l15  = lane & 15;
    const int quad = lane >> 4;

    const short* Kg = Kb + (long)(b*H_ + h) * S_ * 64;
    const short* Vg = Vt + (long)(b*H_ + h) * 64 * S_;

    // Q fragments: 2 row-tiles of 16 per wave
    bf16x8 aq[2][2];
    {
        const short* qp = qb + ((((long)f*B_ + b)*H_ + h)*S_ + qt*128 + wave*32)*64;
        #pragma unroll
        for (int rt = 0; rt < 2; rt++)
            #pragma unroll
            for (int ks = 0; ks < 2; ks++)
                aq[rt][ks] = *(const bf16x8*)&qp[(rt*16 + l15)*64 + ks*32 + quad*8];
    }

    const int skey = tid >> 2;        // staging row 0..63
    const int sch  = (tid & 3) * 2;   // chunk pair

    short* Psw = Ps[wave];

    f32x4 o[2][4];
    #pragma unroll
    for (int rt = 0; rt < 2; rt++)
        #pragma unroll
        for (int nt = 0; nt < 4; nt++) o[rt][nt] = (f32x4){0.f,0.f,0.f,0.f};
    float m_i[2][4], l_i[2][4];
    #pragma unroll
    for (int rt = 0; rt < 2; rt++)
        #pragma unroll
        for (int r = 0; r < 4; r++) { m_i[rt][r] = -INFINITY; l_i[rt][r] = 0.f; }

    for (int kt = 0; kt < 16; kt++) {
        // ---- stage K and Vt tiles: pure 16B copies with swizzle ----
        #pragma unroll
        for (int j = 0; j < 2; j++) {
            const int ch = sch + j;
            const int slot = ((ch ^ skey) & 7) << 3;
            bf16x8 kx = *(const bf16x8*)&Kg[(long)(kt*64 + skey)*64 + ch*8];
            bf16x8 vx = *(const bf16x8*)&Vg[(long)skey*S_ + kt*64 + ch*8];
            *(bf16x8*)&Ks[skey*64 + slot] = kx;
            *(bf16x8*)&Vs[skey*64 + slot] = vx;
        }
        __syncthreads();

        // ---- S = Q @ K^T ----
        f32x4 st[2][4];
        #pragma unroll
        for (int rt = 0; rt < 2; rt++)
            #pragma unroll
            for (int nt = 0; nt < 4; nt++) st[rt][nt] = (f32x4){0.f,0.f,0.f,0.f};
        #pragma unroll
        for (int nt = 0; nt < 4; nt++) {
            const int key = nt*16 + l15;
            #pragma unroll
            for (int ks = 0; ks < 2; ks++) {
                const bf16x8 kf = *(const bf16x8*)
                    &Ks[key*64 + ((((ks*4 + quad) ^ key) & 7) << 3)];
                st[0][nt] = __builtin_amdgcn_mfma_f32_16x16x32_bf16(aq[0][ks], kf, st[0][nt], 0, 0, 0);
                st[1][nt] = __builtin_amdgcn_mfma_f32_16x16x32_bf16(aq[1][ks], kf, st[1][nt], 0, 0, 0);
            }
        }

        // ---- online softmax per row ----
        #pragma unroll
        for (int rt = 0; rt < 2; rt++) {
            float alpha[4];
            #pragma unroll
            for (int r = 0; r < 4; r++) {
                float t = fmaxf(fmaxf(st[rt][0][r], st[rt][1][r]),
                                fmaxf(st[rt][2][r], st[rt][3][r]));
                t = fmaxf(t, __shfl_xor(t, 1));
                t = fmaxf(t, __shfl_xor(t, 2));
                t = fmaxf(t, __shfl_xor(t, 4));
                t = fmaxf(t, __shfl_xor(t, 8));
                const float mn = fmaxf(m_i[rt][r], t);
                const float a  = __expf(m_i[rt][r] - mn);
                m_i[rt][r] = mn;
                float ls = 0.f;
                const int row = rt*16 + quad*4 + r;
                #pragma unroll
                for (int nt = 0; nt < 4; nt++) {
                    const float p = __expf(st[rt][nt][r] - mn);
                    ls += p;
                    const int col = nt*16 + l15;
                    Psw[row*64 + ((((col >> 3) ^ row) & 7) << 3) + (col & 7)] = f2bf(p);
                }
                ls += __shfl_xor(ls, 1);
                ls += __shfl_xor(ls, 2);
                ls += __shfl_xor(ls, 4);
                ls += __shfl_xor(ls, 8);
                l_i[rt][r] = l_i[rt][r]*a + ls;
                alpha[r] = a;
            }
            #pragma unroll
            for (int nt = 0; nt < 4; nt++) {
                o[rt][nt][0] *= alpha[0]; o[rt][nt][1] *= alpha[1];
                o[rt][nt][2] *= alpha[2]; o[rt][nt][3] *= alpha[3];
            }
        }

        // ---- P fragments (same-wave LDS round-trip) ----
        bf16x8 pa[2][2];
        #pragma unroll
        for (int rt = 0; rt < 2; rt++)
            #pragma unroll
            for (int ks = 0; ks < 2; ks++)
                pa[rt][ks] = *(const bf16x8*)
                    &Psw[(rt*16 + l15)*64 + ((((ks*4 + quad) ^ l15) & 7) << 3)];

        // ---- O += P @ V ----
        #pragma unroll
        for (int nt = 0; nt < 4; nt++) {
            const int dim = nt*16 + l15;
            #pragma unroll
            for (int ks = 0; ks < 2; ks++) {
                const bf16x8 vf = *(const bf16x8*)
                    &Vs[dim*64 + ((((ks*4 + quad) ^ dim) & 7) << 3)];
                o[0][nt] = __builtin_amdgcn_mfma_f32_16x16x32_bf16(pa[0][ks], vf, o[0][nt], 0, 0, 0);
                o[1][nt] = __builtin_amdgcn_mfma_f32_16x16x32_bf16(pa[1][ks], vf, o[1][nt], 0, 0, 0);
            }
        }
        __syncthreads();
    }

    // ---- epilogue ----
    #pragma unroll
    for (int rt = 0; rt < 2; rt++) {
        float inv[4];
        #pragma unroll
        for (int r = 0; r < 4; r++) inv[r] = 1.0f / l_i[rt][r];
        const long rowBase = (long)(b*S_ + qt*128 + wave*32 + rt*16 + quad*4);
        #pragma unroll
        for (int nt = 0; nt < 4; nt++) {
            #pragma unroll
            for (int r = 0; r < 4; r++) {
                stacked[(rowBase + r)*FD_ + f*D_ + h*64 + nt*16 + l15] = o[rt][nt][r] * inv[r];
            }
        }
    }
}

// ---------------------------------------------------------------------------
// gates[m,f] = softmax_f( g1[m,:] @ W_g2 + b_g2 ), one wave per row
// ---------------------------------------------------------------------------
__global__ __launch_bounds__(64) void gates_kernel(
    const float* __restrict__ g1, const float* __restrict__ W_g2,
    const float* __restrict__ b_g2, float* __restrict__ gates)
{
    const int m = blockIdx.x;
    const int lane = threadIdx.x;
    float p[6] = {0.f,0.f,0.f,0.f,0.f,0.f};
    for (int k = lane; k < FD4_; k += 64) {
        float g = g1[(long)m*FD4_ + k];
        #pragma unroll
        for (int f = 0; f < 6; f++) p[f] += g * W_g2[k*6 + f];
    }
    #pragma unroll
    for (int f = 0; f < 6; f++) {
        float v = p[f];
        #pragma unroll
        for (int off = 1; off < 64; off <<= 1) v += __shfl_xor(v, off);
        p[f] = v + b_g2[f];
    }
    float mx = p[0];
    #pragma unroll
    for (int f = 1; f < 6; f++) mx = fmaxf(mx, p[f]);
    float se = 0.f;
    #pragma unroll
    for (int f = 0; f < 6; f++) { p[f] = expf(p[f] - mx); se += p[f]; }
    const float inv = 1.0f / se;
    if (lane < 6) gates[m*6 + lane] = p[lane] * inv;
}

// ---------------------------------------------------------------------------
// reduce kernels for split-K partials
// ---------------------------------------------------------------------------
__global__ __launch_bounds__(256) void reduce_m1(
    const float* __restrict__ p, const float* __restrict__ bias,
    float* __restrict__ out)
{
    const int idx = blockIdx.x * 256 + threadIdx.x;
    const int col4 = idx % (D2_/4);
    const long MN4 = (long)BS_ * D2_ / 4;
    float4 a = ((const float4*)p)[idx];
    float4 b = ((const float4*)p)[idx + MN4];
    float4 c = ((const float4*)p)[idx + 2*MN4];
    float4 bb = ((const float4*)bias)[col4];
    float4 o;
    o.x = gelu_exact(a.x + b.x + c.x + bb.x);
    o.y = gelu_exact(a.y + b.y + c.y + bb.y);
    o.z = gelu_exact(a.z + b.z + c.z + bb.z);
    o.w = gelu_exact(a.w + b.w + c.w + bb.w);
    ((float4*)out)[idx] = o;
}

__global__ __launch_bounds__(256) void reduce_out(
    const float* __restrict__ p, const float* __restrict__ bias,
    const float* __restrict__ x, float* __restrict__ out)
{
    const int idx = blockIdx.x * 256 + threadIdx.x;
    const int col4 = idx % (D_/4);
    const long MN4 = (long)BS_ * D_ / 4;
    float4 a = ((const float4*)p)[idx];
    float4 b = ((const float4*)p)[idx + MN4];
    float4 xx = ((const float4*)x)[idx];
    float4 bb = ((const float4*)bias)[col4];
    float4 o;
    o.x = xx.x + a.x + b.x + bb.x;
    o.y = xx.y + a.y + b.y + bb.y;
    o.z = xx.z + a.z + b.z + bb.z;
    o.w = xx.w + a.w + b.w + bb.w;
    ((float4*)out)[idx] = o;
}

// ---------------------------------------------------------------------------
// comb[m,d] = sum_f mixed[m, f*768+d] * gates[m,f]
// ---------------------------------------------------------------------------
__global__ __launch_bounds__(256) void combine_kernel(
    const float* __restrict__ mixed, const float* __restrict__ gates,
    float* __restrict__ comb)
{
    const int idx = blockIdx.x * 256 + threadIdx.x;
    const int m = idx / 192;
    const int d4 = idx - m*192;
    const float4* mrow = (const float4*)(mixed + (long)m * FD_);
    float4 a = {0.f,0.f,0.f,0.f};
    #pragma unroll
    for (int f = 0; f < 6; f++) {
        float g = gates[m*6 + f];
        float4 v = mrow[f*192 + d4];
        a.x += g*v.x; a.y += g*v.y; a.z += g*v.z; a.w += g*v.w;
    }
    ((float4*)comb)[idx] = a;
}

// ---------------------------------------------------------------------------
// In-place LayerNorm over D=768, one block per row
// ---------------------------------------------------------------------------
__global__ __launch_bounds__(256) void ln_kernel(
    const float* __restrict__ preY,
    const float* __restrict__ ln_g, const float* __restrict__ ln_b,
    float* __restrict__ out)
{
    __shared__ float red[8];
    const int m = blockIdx.x;
    const float* row = preY + (long)m * D_;
    const int tid = threadIdx.x;
    float vals[3];
    float s = 0.f, s2 = 0.f;
    #pragma unroll
    for (int i = 0; i < 3; i++) {
        float v = row[tid + 256*i];
        vals[i] = v;
        s += v; s2 += v*v;
    }
    #pragma unroll
    for (int off = 32; off >= 1; off >>= 1) {
        s  += __shfl_xor(s, off);
        s2 += __shfl_xor(s2, off);
    }
    const int wave = tid >> 6;
    if ((tid & 63) == 0) { red[wave*2] = s; red[wave*2+1] = s2; }
    __syncthreads();
    s  = red[0]+red[2]+red[4]+red[6];
    s2 = red[1]+red[3]+red[5]+red[7];
    const float mu  = s * (1.0f/D_);
    const float var = s2 * (1.0f/D_) - mu*mu;
    const float inv = rsqrtf(var + 1e-5f);
    #pragma unroll
    for (int i = 0; i < 3; i++) {
        const int d = tid + 256*i;
        out[(long)m*D_ + d] = (vals[i] - mu) * inv * ln_g[d] + ln_b[d];
    }
}

// ---------------------------------------------------------------------------
extern "C" void kernel_launch(void* const* d_in, const int* in_sizes, int n_in,
                              void* d_out, int out_size, void* d_ws, size_t ws_size,
                              hipStream_t stream)
{
    const float* x     = (const float*)d_in[0];
    const float* W_kv  = (const float*)d_in[1];
    const float* b_kv  = (const float*)d_in[2];
    const float* W_q   = (const float*)d_in[3];
    const float* b_q   = (const float*)d_in[4];
    const float* W_m1  = (const float*)d_in[5];
    const float* b_m1  = (const float*)d_in[6];
    const float* W_m2  = (const float*)d_in[7];
    const float* b_m2  = (const float*)d_in[8];
    const float* cross = (const float*)d_in[9];
    const float* W_g1  = (const float*)d_in[10];
    const float* b_g1  = (const float*)d_in[11];
    const float* W_g2  = (const float*)d_in[12];
    const float* b_g2  = (const float*)d_in[13];
    const float* W_out = (const float*)d_in[14];
    const float* b_out = (const float*)d_in[15];
    const float* ln_g  = (const float*)d_in[16];
    const float* ln_b  = (const float*)d_in[17];
    float* out = (float*)d_out;

    // workspace layout (floats):
    //  bufA    [9,437,184]  : qb bf16 (first half) -> m1 partials -> mixed
    //  bufB    [3,145,728]  : kv fp32 -> h1
    //  stacked [9,437,184]  : attn out -> out partials
    //  bufC    [2,359,296]  : g1 fp32 -> Kb/Vt bf16 -> comb
    //  gates   [12,288]
    float* ws      = (float*)d_ws;
    float* bufA    = ws;
    float* bufB    = bufA + (size_t)F_*BS_*D_;
    float* stacked = bufB + (size_t)BS_*D2_;
    float* bufC    = stacked + (size_t)BS_*FD_;
    float* gates   = bufC + (size_t)BS_*FD4_;

    short* qb = (short*)bufA;                       // 9,437,184 shorts
    short* Kb = (short*)bufC;                       // 1,572,864 shorts
    short* Vt = Kb + (size_t)B_*H_*S_*DH_;          // 1,572,864 shorts

    dim3 blk(256);

    // 1. fused x-projections: kv fp32 -> bufB, q bf16 -> qb, g1 fp32 -> bufC
    xproj_gemm<<<dim3(57, 16, 1), blk, 0, stream>>>(
        x, W_kv, b_kv, bufB, W_q, b_q, qb, W_g1, b_g1, bufC);
    // 2. gates = softmax(g1 @ W_g2 + b_g2)   (consumes g1 before Kb/Vt overwrite)
    gates_kernel<<<dim3(BS_), dim3(64), 0, stream>>>(bufC, W_g2, b_g2, gates);
    // 3. repack kv fp32 -> Kb, Vt bf16 (overwrites g1 region)
    repack_kv<<<dim3(B_*H_*16), blk, 0, stream>>>(bufB, Kb, Vt);
    // 4. MFMA flash attention -> stacked
    attn_mfma2<<<dim3(8 * 144), blk, 0, stream>>>(qb, Kb, Vt, stacked);
    // 5. h1 partials: split-K x3 of stacked @ W_m1 -> bufA (qb dead now)
    mfma_gemm<4><<<dim3(D2_/128, BS_/128, 3), blk, 0, stream>>>(
        stacked, W_m1, b_m1, bufA, BS_, D2_, FD_, FD_/3,
        0, 0, (long)BS_*D2_, FD_/3, nullptr, nullptr);
    // 6. h1 = gelu(sum partials + b_m1) -> bufB
    reduce_m1<<<dim3(BS_*D2_/4/256), blk, 0, stream>>>(bufA, b_m1, bufB);
    // 7. mixed = stacked + cross*(h1 @ W_m2 + b_m2) -> bufA
    mfma_gemm<2><<<dim3(FD_/128, BS_/128, 1), blk, 0, stream>>>(
        bufB, W_m2, b_m2, bufA, BS_, FD_, D2_, D2_,
        0, 0, 0, 0, stacked, cross);
    // 8. comb = sum_f mixed*gates -> bufC (Kb/Vt dead now)
    combine_kernel<<<dim3(BS_*(D_/4)/256), blk, 0, stream>>>(bufA, gates, bufC);
    // 9. out partials: split-K x2 of comb @ W_out -> stacked
    mfma_gemm<4><<<dim3(D_/128, BS_/128, 2), blk, 0, stream>>>(
        bufC, W_out, b_out, stacked, BS_, D_, D_, D_/2,
        0, 0, (long)BS_*D_, D_/2, nullptr, nullptr);
    // 10. preY = x + sum partials + b_out -> d_out
    reduce_out<<<dim3(BS_*D_/4/256), blk, 0, stream>>>(stacked, b_out, x, out);
    // 11. LayerNorm in place
    ln_kernel<<<dim3(BS_), blk, 0, stream>>>(out, ln_g, ln_b, out);
}

// Round 6
// 578.496 us; speedup vs baseline: 4.1915x; 1.1723x over previous
//
#include <hip/hip_runtime.h>
#include <hip/hip_bf16.h>

#define B_ 2
#define S_ 1024
#define D_ 768
#define H_ 12
#define F_ 6
#define DH_ 64
#define BS_ (B_*S_)   // 2048
#define D2_ (2*D_)    // 1536
#define FD_ (F_*D_)   // 4608
#define FD4_ (FD_/4)  // 1152

typedef __attribute__((ext_vector_type(8))) short bf16x8;
typedef __attribute__((ext_vector_type(4))) short bf16x4;
typedef __attribute__((ext_vector_type(4))) float f32x4;

__device__ __forceinline__ float gelu_exact(float x) {
    return 0.5f * x * (1.0f + erff(x * 0.70710678118654752f));
}

// fp32 -> bf16 bits, round-to-nearest-even
__device__ __forceinline__ short f2bf(float f) {
    union { float f; unsigned u; } v; v.f = f;
    unsigned r = v.u + 0x7fff + ((v.u >> 16) & 1);
    return (short)(r >> 16);
}
__device__ __forceinline__ float bf2f(short b) {
    union { unsigned u; float f; } v;
    v.u = ((unsigned)(unsigned short)b) << 16;
    return v.f;
}

// ===========================================================================
// Shared GEMM tile machinery (128x128 tile, BK=64, 4 waves 2x2, prefetch).
// LDS layout: [tile(8)][kchunk(8)][slot(16)] x 8 shorts, slot = l15^kc^tile.
// ===========================================================================

#define GEMM_STAGE_AF(av)                                                     \
    {                                                                         \
        _Pragma("unroll")                                                     \
        for (int c = 0; c < 4; c++) {                                         \
            const int kc = (akb >> 3) + c;                                    \
            bf16x8 s;                                                         \
            _Pragma("unroll")                                                 \
            for (int j = 0; j < 8; j++) s[j] = f2bf((av)[c*8 + j]);           \
            *(bf16x8*)&As[((amt*8 + kc)*16 + ((ar15 ^ kc ^ amt) & 15))*8] = s;\
        }                                                                     \
    }

#define GEMM_STAGE_A16(av)                                                    \
    {                                                                         \
        _Pragma("unroll")                                                     \
        for (int c = 0; c < 4; c++) {                                         \
            const int kc = (akb >> 3) + c;                                    \
            *(bf16x8*)&As[((amt*8 + kc)*16 + ((ar15 ^ kc ^ amt) & 15))*8] = (av)[c]; \
        }                                                                     \
    }

#define GEMM_STAGE_B(bv)                                                      \
    {                                                                         \
        _Pragma("unroll")                                                     \
        for (int j = 0; j < 4; j++) {                                         \
            const int n  = bn0 + j;                                           \
            const int nt = n >> 4;                                            \
            bf16x8 s;                                                         \
            _Pragma("unroll")                                                 \
            for (int r = 0; r < 8; r++) s[r] = f2bf((bv)[r][j]);              \
            *(bf16x8*)&Bs[((nt*8 + bkg)*16 + (((n & 15) ^ bkg ^ nt) & 15))*8] = s; \
        }                                                                     \
    }

#define GEMM_LOAD_AF(av, kb)                                                  \
    {                                                                         \
        _Pragma("unroll")                                                     \
        for (int i = 0; i < 8; i++)                                           \
            *(float4*)&(av)[i*4] = *(const float4*)(Ap + (kb) + i*4);         \
    }

#define GEMM_LOAD_A16(av, kb)                                                 \
    {                                                                         \
        _Pragma("unroll")                                                     \
        for (int c = 0; c < 4; c++)                                           \
            (av)[c] = *(const bf16x8*)(Ap + (kb) + c*8);                      \
    }

#define GEMM_LOAD_B(bv, kb, strideN)                                          \
    {                                                                         \
        _Pragma("unroll")                                                     \
        for (int r = 0; r < 8; r++)                                           \
            *(float4*)&(bv)[r][0] = *(const float4*)(Wp + (long)((kb) + r) * (strideN)); \
    }

#define GEMM_COMPUTE()                                                        \
    {                                                                         \
        _Pragma("unroll")                                                     \
        for (int ks = 0; ks < 2; ks++) {                                      \
            const int kc = ks*4 + quad;                                       \
            bf16x8 af[4], bf[4];                                              \
            _Pragma("unroll")                                                 \
            for (int mt = 0; mt < 4; mt++) {                                  \
                const int MT = wr*4 + mt;                                     \
                af[mt] = *(const bf16x8*)&As[((MT*8 + kc)*16 + ((l15 ^ kc ^ MT) & 15))*8]; \
            }                                                                 \
            _Pragma("unroll")                                                 \
            for (int nt = 0; nt < 4; nt++) {                                  \
                const int NT = wc*4 + nt;                                     \
                bf[nt] = *(const bf16x8*)&Bs[((NT*8 + kc)*16 + ((l15 ^ kc ^ NT) & 15))*8]; \
            }                                                                 \
            _Pragma("unroll")                                                 \
            for (int mt = 0; mt < 4; mt++)                                    \
                _Pragma("unroll")                                             \
                for (int nt = 0; nt < 4; nt++)                                \
                    acc[mt][nt] = __builtin_amdgcn_mfma_f32_16x16x32_bf16(    \
                        af[mt], bf[nt], acc[mt][nt], 0, 0, 0);                \
        }                                                                     \
    }

#define GEMM_COMMON_IDS()                                                     \
    const int tid  = threadIdx.x;                                             \
    const int wave = tid >> 6;                                                \
    const int lane = tid & 63;                                                \
    const int l15  = lane & 15;                                               \
    const int quad = lane >> 4;                                               \
    const int wr   = wave >> 1;                                               \
    const int wc   = wave & 1;                                                \
    const int ar   = tid >> 1;                                                \
    const int akb  = (tid & 1) * 32;                                          \
    const int amt  = ar >> 4;                                                 \
    const int ar15 = ar & 15;                                                 \
    const int bn0  = (tid & 31) * 4;                                          \
    const int bkg  = tid >> 5;

// ---------------------------------------------------------------------------
// mfma_gemm: bf16 A, fp32 W/out.
// MODE 2: C = bf2f(addend) + (*scale_ptr)*v ; MODE 4: raw split-K partial
// split-K via blockIdx.z: C += z*cStrideZ, kBeg = z*kStrideZ. kLen%128==0.
// ---------------------------------------------------------------------------
template<int MODE>
__global__ __launch_bounds__(256, 2) void mfma_gemm(
    const short* __restrict__ A, const float* __restrict__ W,
    const float* __restrict__ bias, float* __restrict__ C,
    int M, int N, int K, int kLen,
    long cStrideZ, long kStrideZ,
    const short* __restrict__ addend, const float* __restrict__ scale_ptr)
{
    if (blockIdx.z) C += (long)blockIdx.z * cStrideZ;
    const int kBeg = (int)(blockIdx.z * kStrideZ);
    const int kEnd = kBeg + kLen;

    __shared__ __align__(16) short As[8192];
    __shared__ __align__(16) short Bs[8192];

    GEMM_COMMON_IDS();

    const int m0 = blockIdx.y * 128;
    const int n0 = blockIdx.x * 128;

    const short* Ap = A + (long)(m0 + ar) * K + akb;
    const float* Wp = W + (long)(bkg * 8) * N + n0 + bn0;

    f32x4 acc[4][4];
    #pragma unroll
    for (int i = 0; i < 4; i++)
        #pragma unroll
        for (int j = 0; j < 4; j++)
            acc[i][j] = (f32x4){0.f, 0.f, 0.f, 0.f};

    bf16x8 a0[4], a1[4];
    float b0[8][4], b1[8][4];
    GEMM_LOAD_A16(a0, kBeg);
    GEMM_LOAD_B(b0, kBeg, N);

    for (int kb = kBeg; kb < kEnd; kb += 128) {
        GEMM_STAGE_A16(a0); GEMM_STAGE_B(b0);
        __syncthreads();
        GEMM_LOAD_A16(a1, kb + 64);
        GEMM_LOAD_B(b1, kb + 64, N);
        GEMM_COMPUTE();
        __syncthreads();
        GEMM_STAGE_A16(a1); GEMM_STAGE_B(b1);
        __syncthreads();
        if (kb + 128 < kEnd) {
            GEMM_LOAD_A16(a0, kb + 128);
            GEMM_LOAD_B(b0, kb + 128, N);
        }
        GEMM_COMPUTE();
        __syncthreads();
    }

    float scale = 0.0f;
    if (MODE == 2) scale = *scale_ptr;
    #pragma unroll
    for (int nt = 0; nt < 4; nt++) {
        const int col = n0 + wc*64 + nt*16 + l15;
        const float bcol = (MODE == 4) ? 0.0f : bias[col];
        #pragma unroll
        for (int mt = 0; mt < 4; mt++) {
            #pragma unroll
            for (int r = 0; r < 4; r++) {
                const long row = m0 + wr*64 + mt*16 + quad*4 + r;
                float v = acc[mt][nt][r] + bcol;
                if (MODE == 2) v = bf2f(addend[row*N + col]) + scale * v;
                C[row*N + col] = v;
            }
        }
    }
}

// ---------------------------------------------------------------------------
// xproj: fused projections of x (fp32 A). 57 N-tiles of 128:
//   tiles  0..11 -> kv fp32 [B*S,1536]
//   tiles 12..47 -> q bf16 pre-scaled*0.125 -> qb [F][B][H][S][64]
//   tiles 48..56 -> g1 = gelu(..) fp32 [B*S,1152]
// ---------------------------------------------------------------------------
__global__ __launch_bounds__(256, 2) void xproj_gemm(
    const float* __restrict__ x,
    const float* __restrict__ W_kv, const float* __restrict__ b_kv, float* __restrict__ bufKV,
    const float* __restrict__ W_q,  const float* __restrict__ b_q,  short* __restrict__ qb,
    const float* __restrict__ W_g1, const float* __restrict__ b_g1, float* __restrict__ bufG1)
{
    __shared__ __align__(16) short As[8192];
    __shared__ __align__(16) short Bs[8192];

    GEMM_COMMON_IDS();

    const int ntile = blockIdx.x;
    const int m0 = blockIdx.y * 128;

    const float* Wseg; const float* bseg; float* Cseg = nullptr;
    int Nw, ncol, fidx = 0, mode;   // mode 0=kv,1=q,2=g1
    if (ntile < 12) {
        Wseg = W_kv; bseg = b_kv; Cseg = bufKV; Nw = 1536; ncol = ntile * 128; mode = 0;
    } else if (ntile < 48) {
        const int t = ntile - 12; fidx = t / 6;
        ncol = (t % 6) * 128;
        Wseg = W_q + (long)fidx * D_ * D_; bseg = b_q + fidx * D_;
        Nw = 768; mode = 1;
    } else {
        const int t = ntile - 48;
        Wseg = W_g1; bseg = b_g1; Cseg = bufG1; Nw = 1152; ncol = t * 128; mode = 2;
    }

    const float* Ap = x + (long)(m0 + ar) * D_ + akb;
    const float* Wp = Wseg + (long)(bkg * 8) * Nw + ncol + bn0;

    f32x4 acc[4][4];
    #pragma unroll
    for (int i = 0; i < 4; i++)
        #pragma unroll
        for (int j = 0; j < 4; j++)
            acc[i][j] = (f32x4){0.f, 0.f, 0.f, 0.f};

    float a0[32], a1[32], b0[8][4], b1[8][4];
    GEMM_LOAD_AF(a0, 0);
    GEMM_LOAD_B(b0, 0, Nw);

    for (int kb = 0; kb < D_; kb += 128) {
        GEMM_STAGE_AF(a0); GEMM_STAGE_B(b0);
        __syncthreads();
        GEMM_LOAD_AF(a1, kb + 64);
        GEMM_LOAD_B(b1, kb + 64, Nw);
        GEMM_COMPUTE();
        __syncthreads();
        GEMM_STAGE_AF(a1); GEMM_STAGE_B(b1);
        __syncthreads();
        if (kb + 128 < D_) {
            GEMM_LOAD_AF(a0, kb + 128);
            GEMM_LOAD_B(b0, kb + 128, Nw);
        }
        GEMM_COMPUTE();
        __syncthreads();
    }

    if (mode == 1) {
        const int bb = m0 >> 10;
        const int sBase = (m0 & 1023) + wr*64;
        #pragma unroll
        for (int nt = 0; nt < 4; nt++) {
            const int col = ncol + wc*64 + nt*16 + l15;   // 0..767
            const int hh = col >> 6, dd = col & 63;
            const float bcol = bseg[col];
            short* qBase = qb + ((((long)fidx*B_ + bb)*H_ + hh)*S_)*64 + dd;
            #pragma unroll
            for (int mt = 0; mt < 4; mt++) {
                #pragma unroll
                for (int r = 0; r < 4; r++) {
                    const int s = sBase + mt*16 + quad*4 + r;
                    qBase[(long)s*64] = f2bf((acc[mt][nt][r] + bcol) * 0.125f);
                }
            }
        }
    } else {
        #pragma unroll
        for (int nt = 0; nt < 4; nt++) {
            const int col = ncol + wc*64 + nt*16 + l15;
            const float bcol = bseg[col];
            #pragma unroll
            for (int mt = 0; mt < 4; mt++) {
                #pragma unroll
                for (int r = 0; r < 4; r++) {
                    const long row = m0 + wr*64 + mt*16 + quad*4 + r;
                    float v = acc[mt][nt][r] + bcol;
                    if (mode == 2) v = gelu_exact(v);
                    Cseg[row*Nw + col] = v;
                }
            }
        }
    }
}

// ---------------------------------------------------------------------------
// repack_kv: kv fp32 [B*S,1536] -> Kb bf16 [B][H][S][64], Vt bf16 [B][H][64][S]
// ---------------------------------------------------------------------------
__global__ __launch_bounds__(256) void repack_kv(
    const float* __restrict__ kvf, short* __restrict__ Kb, short* __restrict__ Vtb)
{
    __shared__ __align__(16) short T[64*64];
    const int bx = blockIdx.x;         // b*192 + h*16 + st
    const int st = bx & 15;
    const int h  = (bx >> 4) % 12;
    const int b  = bx / 192;
    const int tid = threadIdx.x;
    const int s_loc = tid & 63;
    const int dch  = (tid >> 6) * 16;
    const int s0 = st * 64;

    const float* kr = kvf + (long)(b*S_ + s0 + s_loc) * D2_ + h*64 + dch;
    float v[16];

    #pragma unroll
    for (int i = 0; i < 4; i++) *(float4*)&v[i*4] = *(const float4*)(kr + i*4);
    {
        short* kw = Kb + ((long)(b*H_ + h)*S_ + s0 + s_loc)*64 + dch;
        bf16x8 p0, p1;
        #pragma unroll
        for (int i = 0; i < 8; i++) { p0[i] = f2bf(v[i]); p1[i] = f2bf(v[8+i]); }
        *(bf16x8*)&kw[0] = p0;
        *(bf16x8*)&kw[8] = p1;
    }

    #pragma unroll
    for (int i = 0; i < 4; i++) *(float4*)&v[i*4] = *(const float4*)(kr + D_ + i*4);
    #pragma unroll
    for (int i = 0; i < 16; i++) {
        const int d = dch + i;
        T[d*64 + ((((s_loc >> 3) ^ d) & 7) << 3) + (s_loc & 7)] = f2bf(v[i]);
    }
    __syncthreads();
    const int d_loc = tid >> 2;
    const int sc = (tid & 3) * 16;
    const int c0 = sc >> 3;
    bf16x8 o0 = *(const bf16x8*)&T[d_loc*64 + (((c0 ^ d_loc) & 7) << 3)];
    bf16x8 o1 = *(const bf16x8*)&T[d_loc*64 + ((((c0+1) ^ d_loc) & 7) << 3)];
    short* vw = Vtb + ((long)(b*H_ + h)*64 + d_loc)*S_ + s0 + sc;
    *(bf16x8*)&vw[0] = o0;
    *(bf16x8*)&vw[8] = o1;
}

// ---------------------------------------------------------------------------
// MFMA flash attention v3: 128-key tiles, ones-column l-accumulation.
// qb [F][B][H][S][64] (pre-scaled), Kb [B][H][S][64], Vt [B][H][64][S].
// Block = 128 q-rows x one (b,f,h); 4 waves x 32 rows; 8 K-tile iterations.
// Ks[key][64] swz8; Vs[dim][128] swz16; Ps[wave][32][128] swz16.
// Output: stacked bf16 [B*S, F*D].
// ---------------------------------------------------------------------------
__global__ __launch_bounds__(256, 2) void attn_mfma3(
    const short* __restrict__ qb,
    const short* __restrict__ Kb,
    const short* __restrict__ Vt,
    short* __restrict__ stackedb)
{
    __shared__ __align__(16) short Ks[128*64];
    __shared__ __align__(16) short Vs[64*128];
    __shared__ __align__(16) short Ps[4][32*128];

    const int bx = blockIdx.x;
    const int qt = bx & 7;            // 8 q-tiles of 128 rows
    const int rest = bx >> 3;         // 0..143
    const int h = rest % 12;
    const int r2 = rest / 12;
    const int f = r2 % 6;
    const int b = r2 / 6;

    const int tid  = threadIdx.x;
    const int wave = tid >> 6;
    const int lane = tid & 63;
    const int l15  = lane & 15;
    const int quad = lane >> 4;

    const short* Kg = Kb + (long)(b*H_ + h) * S_ * 64;
    const short* Vg = Vt + (long)(b*H_ + h) * 64 * S_;

    bf16x8 aq[2][2];
    {
        const short* qp = qb + ((((long)f*B_ + b)*H_ + h)*S_ + qt*128 + wave*32)*64;
        #pragma unroll
        for (int rt = 0; rt < 2; rt++)
            #pragma unroll
            for (int ks = 0; ks < 2; ks++)
                aq[rt][ks] = *(const bf16x8*)&qp[(rt*16 + l15)*64 + ks*32 + quad*8];
    }

    // ones B-fragment: B[n][k] = (n==0) -> rowsum lands in output col 0
    bf16x8 onesf;
    {
        const short ONE = (short)0x3F80;
        #pragma unroll
        for (int j = 0; j < 8; j++) onesf[j] = (l15 == 0) ? ONE : (short)0;
    }

    short* Psw = Ps[wave];

    f32x4 o[2][4], lo[2];
    #pragma unroll
    for (int rt = 0; rt < 2; rt++) {
        lo[rt] = (f32x4){0.f,0.f,0.f,0.f};
        #pragma unroll
        for (int nt = 0; nt < 4; nt++) o[rt][nt] = (f32x4){0.f,0.f,0.f,0.f};
    }
    float m_i[2][4];
    #pragma unroll
    for (int rt = 0; rt < 2; rt++)
        #pragma unroll
        for (int r = 0; r < 4; r++) m_i[rt][r] = -INFINITY;

    for (int kt = 0; kt < 8; kt++) {
        // ---- stage K (128x64) and V^T (64x128) ----
        #pragma unroll
        for (int i = 0; i < 4; i++) {
            const int idx = i*256 + tid;
            const int key = idx >> 3, kch = idx & 7;
            *(bf16x8*)&Ks[key*64 + (((kch ^ key) & 7) << 3)] =
                *(const bf16x8*)&Kg[(long)(kt*128 + key)*64 + kch*8];
            const int dim = idx >> 4, vch = idx & 15;
            *(bf16x8*)&Vs[dim*128 + (((vch ^ dim) & 15) << 3)] =
                *(const bf16x8*)&Vg[(long)dim*S_ + kt*128 + vch*8];
        }
        __syncthreads();

        // ---- S = Q @ K^T  (8 key-tiles of 16) ----
        f32x4 st[2][8];
        #pragma unroll
        for (int rt = 0; rt < 2; rt++)
            #pragma unroll
            for (int nt = 0; nt < 8; nt++) st[rt][nt] = (f32x4){0.f,0.f,0.f,0.f};
        #pragma unroll
        for (int nt = 0; nt < 8; nt++) {
            const int key = nt*16 + l15;
            #pragma unroll
            for (int ks = 0; ks < 2; ks++) {
                const bf16x8 kf = *(const bf16x8*)
                    &Ks[key*64 + ((((ks*4 + quad) ^ key) & 7) << 3)];
                st[0][nt] = __builtin_amdgcn_mfma_f32_16x16x32_bf16(aq[0][ks], kf, st[0][nt], 0, 0, 0);
                st[1][nt] = __builtin_amdgcn_mfma_f32_16x16x32_bf16(aq[1][ks], kf, st[1][nt], 0, 0, 0);
            }
        }

        // ---- online softmax: max-chain only; l via ones-column MFMA ----
        #pragma unroll
        for (int rt = 0; rt < 2; rt++) {
            float alpha[4];
            #pragma unroll
            for (int r = 0; r < 4; r++) {
                float t = st[rt][0][r];
                #pragma unroll
                for (int nt = 1; nt < 8; nt++) t = fmaxf(t, st[rt][nt][r]);
                t = fmaxf(t, __shfl_xor(t, 1));
                t = fmaxf(t, __shfl_xor(t, 2));
                t = fmaxf(t, __shfl_xor(t, 4));
                t = fmaxf(t, __shfl_xor(t, 8));
                const float mn = fmaxf(m_i[rt][r], t);
                alpha[r] = __expf(m_i[rt][r] - mn);
                m_i[rt][r] = mn;
                const int row = rt*16 + quad*4 + r;
                #pragma unroll
                for (int nt = 0; nt < 8; nt++) {
                    const float p = __expf(st[rt][nt][r] - mn);
                    const int col = nt*16 + l15;
                    Psw[row*128 + ((((col >> 3) ^ row) & 15) << 3) + (col & 7)] = f2bf(p);
                }
            }
            #pragma unroll
            for (int nt = 0; nt < 4; nt++) {
                o[rt][nt][0] *= alpha[0]; o[rt][nt][1] *= alpha[1];
                o[rt][nt][2] *= alpha[2]; o[rt][nt][3] *= alpha[3];
            }
            lo[rt][0] *= alpha[0]; lo[rt][1] *= alpha[1];
            lo[rt][2] *= alpha[2]; lo[rt][3] *= alpha[3];
        }

        // ---- P A-fragments (same-wave LDS round-trip), k = 128 ----
        bf16x8 pa[2][4];
        #pragma unroll
        for (int rt = 0; rt < 2; rt++)
            #pragma unroll
            for (int c = 0; c < 4; c++)
                pa[rt][c] = *(const bf16x8*)
                    &Psw[(rt*16 + l15)*128 + ((((c*4 + quad) ^ l15) & 15) << 3)];

        // ---- O += P @ V ; l += P @ ones ----
        #pragma unroll
        for (int nt = 0; nt < 4; nt++) {
            const int dim = nt*16 + l15;
            #pragma unroll
            for (int c = 0; c < 4; c++) {
                const bf16x8 vf = *(const bf16x8*)
                    &Vs[dim*128 + ((((c*4 + quad) ^ dim) & 15) << 3)];
                o[0][nt] = __builtin_amdgcn_mfma_f32_16x16x32_bf16(pa[0][c], vf, o[0][nt], 0, 0, 0);
                o[1][nt] = __builtin_amdgcn_mfma_f32_16x16x32_bf16(pa[1][c], vf, o[1][nt], 0, 0, 0);
            }
        }
        #pragma unroll
        for (int c = 0; c < 4; c++) {
            lo[0] = __builtin_amdgcn_mfma_f32_16x16x32_bf16(pa[0][c], onesf, lo[0], 0, 0, 0);
            lo[1] = __builtin_amdgcn_mfma_f32_16x16x32_bf16(pa[1][c], onesf, lo[1], 0, 0, 0);
        }
        __syncthreads();
    }

    // ---- epilogue: broadcast l from col-0 lanes, scale, store bf16 ----
    #pragma unroll
    for (int rt = 0; rt < 2; rt++) {
        float inv[4];
        #pragma unroll
        for (int r = 0; r < 4; r++)
            inv[r] = 1.0f / __shfl(lo[rt][r], quad << 4);
        const long rowBase = (long)(b*S_ + qt*128 + wave*32 + rt*16 + quad*4);
        #pragma unroll
        for (int nt = 0; nt < 4; nt++) {
            #pragma unroll
            for (int r = 0; r < 4; r++) {
                stackedb[(rowBase + r)*FD_ + f*D_ + h*64 + nt*16 + l15] =
                    f2bf(o[rt][nt][r] * inv[r]);
            }
        }
    }
}

// ---------------------------------------------------------------------------
// gates[m,f] = softmax_f( g1[m,:] @ W_g2 + b_g2 ), one wave per row
// ---------------------------------------------------------------------------
__global__ __launch_bounds__(64) void gates_kernel(
    const float* __restrict__ g1, const float* __restrict__ W_g2,
    const float* __restrict__ b_g2, float* __restrict__ gates)
{
    const int m = blockIdx.x;
    const int lane = threadIdx.x;
    float p[6] = {0.f,0.f,0.f,0.f,0.f,0.f};
    for (int k = lane; k < FD4_; k += 64) {
        float g = g1[(long)m*FD4_ + k];
        #pragma unroll
        for (int f = 0; f < 6; f++) p[f] += g * W_g2[k*6 + f];
    }
    #pragma unroll
    for (int f = 0; f < 6; f++) {
        float v = p[f];
        #pragma unroll
        for (int off = 1; off < 64; off <<= 1) v += __shfl_xor(v, off);
        p[f] = v + b_g2[f];
    }
    float mx = p[0];
    #pragma unroll
    for (int f = 1; f < 6; f++) mx = fmaxf(mx, p[f]);
    float se = 0.f;
    #pragma unroll
    for (int f = 0; f < 6; f++) { p[f] = expf(p[f] - mx); se += p[f]; }
    const float inv = 1.0f / se;
    if (lane < 6) gates[m*6 + lane] = p[lane] * inv;
}

// ---------------------------------------------------------------------------
// reduce_m1: h1 = gelu(p0+p1+p2+bias) -> bf16 [2048,1536]
// ---------------------------------------------------------------------------
__global__ __launch_bounds__(256) void reduce_m1(
    const float* __restrict__ p, const float* __restrict__ bias,
    short* __restrict__ out)
{
    const int idx = blockIdx.x * 256 + threadIdx.x;
    const int col4 = idx % (D2_/4);
    const long MN4 = (long)BS_ * D2_ / 4;
    float4 a = ((const float4*)p)[idx];
    float4 b = ((const float4*)p)[idx + MN4];
    float4 c = ((const float4*)p)[idx + 2*MN4];
    float4 bb = ((const float4*)bias)[col4];
    bf16x4 o;
    o[0] = f2bf(gelu_exact(a.x + b.x + c.x + bb.x));
    o[1] = f2bf(gelu_exact(a.y + b.y + c.y + bb.y));
    o[2] = f2bf(gelu_exact(a.z + b.z + c.z + bb.z));
    o[3] = f2bf(gelu_exact(a.w + b.w + c.w + bb.w));
    ((bf16x4*)out)[idx] = o;
}

// ---------------------------------------------------------------------------
// comb[m,d] = sum_f mixed[m, f*768+d] * gates[m,f]  -> bf16
// ---------------------------------------------------------------------------
__global__ __launch_bounds__(256) void combine_kernel(
    const float* __restrict__ mixed, const float* __restrict__ gates,
    short* __restrict__ comb)
{
    const int idx = blockIdx.x * 256 + threadIdx.x;
    const int m = idx / 192;
    const int d4 = idx - m*192;
    const float4* mrow = (const float4*)(mixed + (long)m * FD_);
    float4 a = {0.f,0.f,0.f,0.f};
    #pragma unroll
    for (int f = 0; f < 6; f++) {
        float g = gates[m*6 + f];
        float4 v = mrow[f*192 + d4];
        a.x += g*v.x; a.y += g*v.y; a.z += g*v.z; a.w += g*v.w;
    }
    bf16x4 o;
    o[0] = f2bf(a.x); o[1] = f2bf(a.y); o[2] = f2bf(a.z); o[3] = f2bf(a.w);
    ((bf16x4*)comb)[idx] = o;
}

// ---------------------------------------------------------------------------
// reduce_ln: preY = x + p0 + p1 + b_out, then LayerNorm -> out. One block/row.
// ---------------------------------------------------------------------------
__global__ __launch_bounds__(256) void reduce_ln(
    const float* __restrict__ p, const float* __restrict__ bias,
    const float* __restrict__ x,
    const float* __restrict__ ln_g, const float* __restrict__ ln_b,
    float* __restrict__ out)
{
    __shared__ float red[8];
    const int m = blockIdx.x;
    const int tid = threadIdx.x;
    const long MN = (long)BS_ * D_;
    float vals[3];
    float s = 0.f, s2 = 0.f;
    #pragma unroll
    for (int i = 0; i < 3; i++) {
        const int d = tid + 256*i;
        const long o = (long)m*D_ + d;
        float v = x[o] + p[o] + p[MN + o] + bias[d];
        vals[i] = v;
        s += v; s2 += v*v;
    }
    #pragma unroll
    for (int off = 32; off >= 1; off >>= 1) {
        s  += __shfl_xor(s, off);
        s2 += __shfl_xor(s2, off);
    }
    const int wave = tid >> 6;
    if ((tid & 63) == 0) { red[wave*2] = s; red[wave*2+1] = s2; }
    __syncthreads();
    s  = red[0]+red[2]+red[4]+red[6];
    s2 = red[1]+red[3]+red[5]+red[7];
    const float mu  = s * (1.0f/D_);
    const float var = s2 * (1.0f/D_) - mu*mu;
    const float inv = rsqrtf(var + 1e-5f);
    #pragma unroll
    for (int i = 0; i < 3; i++) {
        const int d = tid + 256*i;
        out[(long)m*D_ + d] = (vals[i] - mu) * inv * ln_g[d] + ln_b[d];
    }
}

// ---------------------------------------------------------------------------
extern "C" void kernel_launch(void* const* d_in, const int* in_sizes, int n_in,
                              void* d_out, int out_size, void* d_ws, size_t ws_size,
                              hipStream_t stream)
{
    const float* x     = (const float*)d_in[0];
    const float* W_kv  = (const float*)d_in[1];
    const float* b_kv  = (const float*)d_in[2];
    const float* W_q   = (const float*)d_in[3];
    const float* b_q   = (const float*)d_in[4];
    const float* W_m1  = (const float*)d_in[5];
    const float* b_m1  = (const float*)d_in[6];
    const float* W_m2  = (const float*)d_in[7];
    const float* b_m2  = (const float*)d_in[8];
    const float* cross = (const float*)d_in[9];
    const float* W_g1  = (const float*)d_in[10];
    const float* b_g1  = (const float*)d_in[11];
    const float* W_g2  = (const float*)d_in[12];
    const float* b_g2  = (const float*)d_in[13];
    const float* W_out = (const float*)d_in[14];
    const float* b_out = (const float*)d_in[15];
    const float* ln_g  = (const float*)d_in[16];
    const float* ln_b  = (const float*)d_in[17];
    float* out = (float*)d_out;

    // workspace layout (float units):
    //  bufA    [9,437,184] : qb bf16 (first half) -> m1 partials fp32 -> mixed fp32
    //  bufB    [3,145,728] : kv fp32 -> h1 bf16
    //  stackedS[4,718,592] : stacked bf16 -> out partials fp32 (12.6MB<=18.9MB)
    //  bufC    [2,359,296] : g1 fp32 -> Kb/Vt bf16 -> comb bf16
    //  gates   [12,288]
    float* ws       = (float*)d_ws;
    float* bufA     = ws;
    float* bufB     = bufA + (size_t)9437184;
    short* stackedS = (short*)(bufB + (size_t)3145728);
    float* bufC     = (float*)(stackedS + (size_t)BS_*FD_);
    float* gates    = bufC + (size_t)BS_*FD4_;

    short* qb = (short*)bufA;
    short* Kb = (short*)bufC;
    short* Vt = Kb + (size_t)B_*H_*S_*DH_;
    short* h1b = (short*)bufB;
    short* combb = (short*)bufC;
    float* mixed = bufA;
    float* outPart = (float*)stackedS;

    dim3 blk(256);

    // 1. fused x-projections: kv fp32 -> bufB, q bf16 -> qb, g1 fp32 -> bufC
    xproj_gemm<<<dim3(57, 16, 1), blk, 0, stream>>>(
        x, W_kv, b_kv, bufB, W_q, b_q, qb, W_g1, b_g1, bufC);
    // 2. gates = softmax(g1 @ W_g2 + b_g2)  (consumes g1 before Kb/Vt overwrite)
    gates_kernel<<<dim3(BS_), dim3(64), 0, stream>>>(bufC, W_g2, b_g2, gates);
    // 3. repack kv fp32 -> Kb, Vt bf16
    repack_kv<<<dim3(B_*H_*16), blk, 0, stream>>>(bufB, Kb, Vt);
    // 4. MFMA flash attention v3 -> stacked bf16
    attn_mfma3<<<dim3(8 * 144), blk, 0, stream>>>(qb, Kb, Vt, stackedS);
    // 5. h1 partials: split-K x3 of stacked(bf16) @ W_m1 -> bufA fp32
    mfma_gemm<4><<<dim3(D2_/128, BS_/128, 3), blk, 0, stream>>>(
        stackedS, W_m1, b_m1, bufA, BS_, D2_, FD_, FD_/3,
        (long)BS_*D2_, FD_/3, nullptr, nullptr);
    // 6. h1 = gelu(sum partials + b_m1) -> bf16 bufB
    reduce_m1<<<dim3(BS_*D2_/4/256), blk, 0, stream>>>(bufA, b_m1, h1b);
    // 7. mixed = stacked + cross*(h1(bf16) @ W_m2 + b_m2) -> fp32 bufA
    mfma_gemm<2><<<dim3(FD_/128, BS_/128, 1), blk, 0, stream>>>(
        h1b, W_m2, b_m2, mixed, BS_, FD_, D2_, D2_,
        0, 0, stackedS, cross);
    // 8. comb = sum_f mixed*gates -> bf16 bufC (Kb/Vt dead)
    combine_kernel<<<dim3(BS_*(D_/4)/256), blk, 0, stream>>>(mixed, gates, combb);
    // 9. out partials: split-K x2 of comb(bf16) @ W_out -> fp32 (stacked region)
    mfma_gemm<4><<<dim3(D_/128, BS_/128, 2), blk, 0, stream>>>(
        combb, W_out, b_out, outPart, BS_, D_, D_, D_/2,
        (long)BS_*D_, D_/2, nullptr, nullptr);
    // 10. preY = x + partials + b_out, LayerNorm -> d_out (fused)
    reduce_ln<<<dim3(BS_), blk, 0, stream>>>(outPart, b_out, x, ln_g, ln_b, out);
}

// Round 7
// 524.799 us; speedup vs baseline: 4.6204x; 1.1023x over previous
//
#include <hip/hip_runtime.h>
#include <hip/hip_bf16.h>

#define B_ 2
#define S_ 1024
#define D_ 768
#define H_ 12
#define F_ 6
#define DH_ 64
#define BS_ (B_*S_)   // 2048
#define D2_ (2*D_)    // 1536
#define FD_ (F_*D_)   // 4608
#define FD4_ (FD_/4)  // 1152

typedef __attribute__((ext_vector_type(8))) short bf16x8;
typedef __attribute__((ext_vector_type(4))) short bf16x4;
typedef __attribute__((ext_vector_type(4))) float f32x4;

__device__ __forceinline__ float gelu_exact(float x) {
    return 0.5f * x * (1.0f + erff(x * 0.70710678118654752f));
}

// fp32 -> bf16 bits, round-to-nearest-even
__device__ __forceinline__ short f2bf(float f) {
    union { float f; unsigned u; } v; v.f = f;
    unsigned r = v.u + 0x7fff + ((v.u >> 16) & 1);
    return (short)(r >> 16);
}
__device__ __forceinline__ float bf2f(short b) {
    union { unsigned u; float f; } v;
    v.u = ((unsigned)(unsigned short)b) << 16;
    return v.f;
}

// ===========================================================================
// Shared GEMM tile machinery (128x128 tile, BK=64, 4 waves 2x2, prefetch).
// LDS layout: [tile(8)][kchunk(8)][slot(16)] x 8 shorts, slot = l15^kc^tile.
// ===========================================================================

#define GEMM_STAGE_AF(av)                                                     \
    {                                                                         \
        _Pragma("unroll")                                                     \
        for (int c = 0; c < 4; c++) {                                         \
            const int kc = (akb >> 3) + c;                                    \
            bf16x8 s;                                                         \
            _Pragma("unroll")                                                 \
            for (int j = 0; j < 8; j++) s[j] = f2bf((av)[c*8 + j]);           \
            *(bf16x8*)&As[((amt*8 + kc)*16 + ((ar15 ^ kc ^ amt) & 15))*8] = s;\
        }                                                                     \
    }

#define GEMM_STAGE_A16(av)                                                    \
    {                                                                         \
        _Pragma("unroll")                                                     \
        for (int c = 0; c < 4; c++) {                                         \
            const int kc = (akb >> 3) + c;                                    \
            *(bf16x8*)&As[((amt*8 + kc)*16 + ((ar15 ^ kc ^ amt) & 15))*8] = (av)[c]; \
        }                                                                     \
    }

#define GEMM_STAGE_B(bv)                                                      \
    {                                                                         \
        _Pragma("unroll")                                                     \
        for (int j = 0; j < 4; j++) {                                         \
            const int n  = bn0 + j;                                           \
            const int nt = n >> 4;                                            \
            bf16x8 s;                                                         \
            _Pragma("unroll")                                                 \
            for (int r = 0; r < 8; r++) s[r] = f2bf((bv)[r][j]);              \
            *(bf16x8*)&Bs[((nt*8 + bkg)*16 + (((n & 15) ^ bkg ^ nt) & 15))*8] = s; \
        }                                                                     \
    }

#define GEMM_LOAD_AF(av, kb)                                                  \
    {                                                                         \
        _Pragma("unroll")                                                     \
        for (int i = 0; i < 8; i++)                                           \
            *(float4*)&(av)[i*4] = *(const float4*)(Ap + (kb) + i*4);         \
    }

#define GEMM_LOAD_A16(av, kb)                                                 \
    {                                                                         \
        _Pragma("unroll")                                                     \
        for (int c = 0; c < 4; c++)                                           \
            (av)[c] = *(const bf16x8*)(Ap + (kb) + c*8);                      \
    }

#define GEMM_LOAD_B(bv, kb, strideN)                                          \
    {                                                                         \
        _Pragma("unroll")                                                     \
        for (int r = 0; r < 8; r++)                                           \
            *(float4*)&(bv)[r][0] = *(const float4*)(Wp + (long)((kb) + r) * (strideN)); \
    }

#define GEMM_COMPUTE()                                                        \
    {                                                                         \
        _Pragma("unroll")                                                     \
        for (int ks = 0; ks < 2; ks++) {                                      \
            const int kc = ks*4 + quad;                                       \
            bf16x8 af[4], bf[4];                                              \
            _Pragma("unroll")                                                 \
            for (int mt = 0; mt < 4; mt++) {                                  \
                const int MT = wr*4 + mt;                                     \
                af[mt] = *(const bf16x8*)&As[((MT*8 + kc)*16 + ((l15 ^ kc ^ MT) & 15))*8]; \
            }                                                                 \
            _Pragma("unroll")                                                 \
            for (int nt = 0; nt < 4; nt++) {                                  \
                const int NT = wc*4 + nt;                                     \
                bf[nt] = *(const bf16x8*)&Bs[((NT*8 + kc)*16 + ((l15 ^ kc ^ NT) & 15))*8]; \
            }                                                                 \
            _Pragma("unroll")                                                 \
            for (int mt = 0; mt < 4; mt++)                                    \
                _Pragma("unroll")                                             \
                for (int nt = 0; nt < 4; nt++)                                \
                    acc[mt][nt] = __builtin_amdgcn_mfma_f32_16x16x32_bf16(    \
                        af[mt], bf[nt], acc[mt][nt], 0, 0, 0);                \
        }                                                                     \
    }

#define GEMM_COMMON_IDS()                                                     \
    const int tid  = threadIdx.x;                                             \
    const int wave = tid >> 6;                                                \
    const int lane = tid & 63;                                                \
    const int l15  = lane & 15;                                               \
    const int quad = lane >> 4;                                               \
    const int wr   = wave >> 1;                                               \
    const int wc   = wave & 1;                                                \
    const int ar   = tid >> 1;                                                \
    const int akb  = (tid & 1) * 32;                                          \
    const int amt  = ar >> 4;                                                 \
    const int ar15 = ar & 15;                                                 \
    const int bn0  = (tid & 31) * 4;                                          \
    const int bkg  = tid >> 5;

// ---------------------------------------------------------------------------
// mfma_gemm: bf16 A, fp32 W/out.
// MODE 2: C = bf2f(addend) + (*scale_ptr)*v ; MODE 4: raw split-K partial
// ---------------------------------------------------------------------------
template<int MODE>
__global__ __launch_bounds__(256, 2) void mfma_gemm(
    const short* __restrict__ A, const float* __restrict__ W,
    const float* __restrict__ bias, float* __restrict__ C,
    int M, int N, int K, int kLen,
    long cStrideZ, long kStrideZ,
    const short* __restrict__ addend, const float* __restrict__ scale_ptr)
{
    if (blockIdx.z) C += (long)blockIdx.z * cStrideZ;
    const int kBeg = (int)(blockIdx.z * kStrideZ);
    const int kEnd = kBeg + kLen;

    __shared__ __align__(16) short As[8192];
    __shared__ __align__(16) short Bs[8192];

    GEMM_COMMON_IDS();

    const int m0 = blockIdx.y * 128;
    const int n0 = blockIdx.x * 128;

    const short* Ap = A + (long)(m0 + ar) * K + akb;
    const float* Wp = W + (long)(bkg * 8) * N + n0 + bn0;

    f32x4 acc[4][4];
    #pragma unroll
    for (int i = 0; i < 4; i++)
        #pragma unroll
        for (int j = 0; j < 4; j++)
            acc[i][j] = (f32x4){0.f, 0.f, 0.f, 0.f};

    bf16x8 a0[4], a1[4];
    float b0[8][4], b1[8][4];
    GEMM_LOAD_A16(a0, kBeg);
    GEMM_LOAD_B(b0, kBeg, N);

    for (int kb = kBeg; kb < kEnd; kb += 128) {
        GEMM_STAGE_A16(a0); GEMM_STAGE_B(b0);
        __syncthreads();
        GEMM_LOAD_A16(a1, kb + 64);
        GEMM_LOAD_B(b1, kb + 64, N);
        GEMM_COMPUTE();
        __syncthreads();
        GEMM_STAGE_A16(a1); GEMM_STAGE_B(b1);
        __syncthreads();
        if (kb + 128 < kEnd) {
            GEMM_LOAD_A16(a0, kb + 128);
            GEMM_LOAD_B(b0, kb + 128, N);
        }
        GEMM_COMPUTE();
        __syncthreads();
    }

    float scale = 0.0f;
    if (MODE == 2) scale = *scale_ptr;
    #pragma unroll
    for (int nt = 0; nt < 4; nt++) {
        const int col = n0 + wc*64 + nt*16 + l15;
        const float bcol = (MODE == 4) ? 0.0f : bias[col];
        #pragma unroll
        for (int mt = 0; mt < 4; mt++) {
            #pragma unroll
            for (int r = 0; r < 4; r++) {
                const long row = m0 + wr*64 + mt*16 + quad*4 + r;
                float v = acc[mt][nt][r] + bcol;
                if (MODE == 2) v = bf2f(addend[row*N + col]) + scale * v;
                C[row*N + col] = v;
            }
        }
    }
}

// ---------------------------------------------------------------------------
// xproj: fused projections of x (fp32 A). 57 N-tiles of 128:
//   tiles  0..11 -> kv fp32 [B*S,1536]
//   tiles 12..47 -> q bf16 pre-scaled*0.125 -> qb [F][B][H][S][64]
//   tiles 48..56 -> g1 = gelu(..) fp32 [B*S,1152]
// ---------------------------------------------------------------------------
__global__ __launch_bounds__(256, 2) void xproj_gemm(
    const float* __restrict__ x,
    const float* __restrict__ W_kv, const float* __restrict__ b_kv, float* __restrict__ bufKV,
    const float* __restrict__ W_q,  const float* __restrict__ b_q,  short* __restrict__ qb,
    const float* __restrict__ W_g1, const float* __restrict__ b_g1, float* __restrict__ bufG1)
{
    __shared__ __align__(16) short As[8192];
    __shared__ __align__(16) short Bs[8192];

    GEMM_COMMON_IDS();

    const int ntile = blockIdx.x;
    const int m0 = blockIdx.y * 128;

    const float* Wseg; const float* bseg; float* Cseg = nullptr;
    int Nw, ncol, fidx = 0, mode;   // mode 0=kv,1=q,2=g1
    if (ntile < 12) {
        Wseg = W_kv; bseg = b_kv; Cseg = bufKV; Nw = 1536; ncol = ntile * 128; mode = 0;
    } else if (ntile < 48) {
        const int t = ntile - 12; fidx = t / 6;
        ncol = (t % 6) * 128;
        Wseg = W_q + (long)fidx * D_ * D_; bseg = b_q + fidx * D_;
        Nw = 768; mode = 1;
    } else {
        const int t = ntile - 48;
        Wseg = W_g1; bseg = b_g1; Cseg = bufG1; Nw = 1152; ncol = t * 128; mode = 2;
    }

    const float* Ap = x + (long)(m0 + ar) * D_ + akb;
    const float* Wp = Wseg + (long)(bkg * 8) * Nw + ncol + bn0;

    f32x4 acc[4][4];
    #pragma unroll
    for (int i = 0; i < 4; i++)
        #pragma unroll
        for (int j = 0; j < 4; j++)
            acc[i][j] = (f32x4){0.f, 0.f, 0.f, 0.f};

    float a0[32], a1[32], b0[8][4], b1[8][4];
    GEMM_LOAD_AF(a0, 0);
    GEMM_LOAD_B(b0, 0, Nw);

    for (int kb = 0; kb < D_; kb += 128) {
        GEMM_STAGE_AF(a0); GEMM_STAGE_B(b0);
        __syncthreads();
        GEMM_LOAD_AF(a1, kb + 64);
        GEMM_LOAD_B(b1, kb + 64, Nw);
        GEMM_COMPUTE();
        __syncthreads();
        GEMM_STAGE_AF(a1); GEMM_STAGE_B(b1);
        __syncthreads();
        if (kb + 128 < D_) {
            GEMM_LOAD_AF(a0, kb + 128);
            GEMM_LOAD_B(b0, kb + 128, Nw);
        }
        GEMM_COMPUTE();
        __syncthreads();
    }

    if (mode == 1) {
        const int bb = m0 >> 10;
        const int sBase = (m0 & 1023) + wr*64;
        #pragma unroll
        for (int nt = 0; nt < 4; nt++) {
            const int col = ncol + wc*64 + nt*16 + l15;   // 0..767
            const int hh = col >> 6, dd = col & 63;
            const float bcol = bseg[col];
            short* qBase = qb + ((((long)fidx*B_ + bb)*H_ + hh)*S_)*64 + dd;
            #pragma unroll
            for (int mt = 0; mt < 4; mt++) {
                #pragma unroll
                for (int r = 0; r < 4; r++) {
                    const int s = sBase + mt*16 + quad*4 + r;
                    qBase[(long)s*64] = f2bf((acc[mt][nt][r] + bcol) * 0.125f);
                }
            }
        }
    } else {
        #pragma unroll
        for (int nt = 0; nt < 4; nt++) {
            const int col = ncol + wc*64 + nt*16 + l15;
            const float bcol = bseg[col];
            #pragma unroll
            for (int mt = 0; mt < 4; mt++) {
                #pragma unroll
                for (int r = 0; r < 4; r++) {
                    const long row = m0 + wr*64 + mt*16 + quad*4 + r;
                    float v = acc[mt][nt][r] + bcol;
                    if (mode == 2) v = gelu_exact(v);
                    Cseg[row*Nw + col] = v;
                }
            }
        }
    }
}

// ---------------------------------------------------------------------------
// repack_kv: kv fp32 [B*S,1536] -> Kb bf16 [B][H][S][64], Vt bf16 [B][H][64][S]
// ---------------------------------------------------------------------------
__global__ __launch_bounds__(256) void repack_kv(
    const float* __restrict__ kvf, short* __restrict__ Kb, short* __restrict__ Vtb)
{
    __shared__ __align__(16) short T[64*64];
    const int bx = blockIdx.x;         // b*192 + h*16 + st
    const int st = bx & 15;
    const int h  = (bx >> 4) % 12;
    const int b  = bx / 192;
    const int tid = threadIdx.x;
    const int s_loc = tid & 63;
    const int dch  = (tid >> 6) * 16;
    const int s0 = st * 64;

    const float* kr = kvf + (long)(b*S_ + s0 + s_loc) * D2_ + h*64 + dch;
    float v[16];

    #pragma unroll
    for (int i = 0; i < 4; i++) *(float4*)&v[i*4] = *(const float4*)(kr + i*4);
    {
        short* kw = Kb + ((long)(b*H_ + h)*S_ + s0 + s_loc)*64 + dch;
        bf16x8 p0, p1;
        #pragma unroll
        for (int i = 0; i < 8; i++) { p0[i] = f2bf(v[i]); p1[i] = f2bf(v[8+i]); }
        *(bf16x8*)&kw[0] = p0;
        *(bf16x8*)&kw[8] = p1;
    }

    #pragma unroll
    for (int i = 0; i < 4; i++) *(float4*)&v[i*4] = *(const float4*)(kr + D_ + i*4);
    #pragma unroll
    for (int i = 0; i < 16; i++) {
        const int d = dch + i;
        T[d*64 + ((((s_loc >> 3) ^ d) & 7) << 3) + (s_loc & 7)] = f2bf(v[i]);
    }
    __syncthreads();
    const int d_loc = tid >> 2;
    const int sc = (tid & 3) * 16;
    const int c0 = sc >> 3;
    bf16x8 o0 = *(const bf16x8*)&T[d_loc*64 + (((c0 ^ d_loc) & 7) << 3)];
    bf16x8 o1 = *(const bf16x8*)&T[d_loc*64 + ((((c0+1) ^ d_loc) & 7) << 3)];
    short* vw = Vtb + ((long)(b*H_ + h)*64 + d_loc)*S_ + s0 + sc;
    *(bf16x8*)&vw[0] = o0;
    *(bf16x8*)&vw[8] = o1;
}

// ---------------------------------------------------------------------------
// MFMA flash attention v4: 64 q-rows/block, 64-key tiles, register prefetch
// of next K/V tile, ones-column l-accumulation. 24 KB LDS -> high occupancy.
// qb [F][B][H][S][64] (pre-scaled), Kb [B][H][S][64], Vt [B][H][64][S].
// Grid = 16 qt x 144 (b,f,h) = 2304 blocks; 4 waves x 16 rows.
// ---------------------------------------------------------------------------
__global__ __launch_bounds__(256, 4) void attn_mfma4(
    const short* __restrict__ qb,
    const short* __restrict__ Kb,
    const short* __restrict__ Vt,
    short* __restrict__ stackedb)
{
    __shared__ __align__(16) short Ks[64*64];
    __shared__ __align__(16) short Vs[64*64];
    __shared__ __align__(16) short Ps[4][16*64];

    const int bx = blockIdx.x;
    const int qt = bx & 15;           // 16 q-tiles of 64 rows
    const int rest = bx >> 4;         // 0..143
    const int h = rest % 12;
    const int r2 = rest / 12;
    const int f = r2 % 6;
    const int b = r2 / 6;

    const int tid  = threadIdx.x;
    const int wave = tid >> 6;
    const int lane = tid & 63;
    const int l15  = lane & 15;
    const int quad = lane >> 4;

    const short* Kg = Kb + (long)(b*H_ + h) * S_ * 64;
    const short* Vg = Vt + (long)(b*H_ + h) * 64 * S_;

    // Q fragments (16 rows/wave)
    bf16x8 aq[2];
    {
        const short* qp = qb + ((((long)f*B_ + b)*H_ + h)*S_ + qt*64 + wave*16)*64;
        #pragma unroll
        for (int ks = 0; ks < 2; ks++)
            aq[ks] = *(const bf16x8*)&qp[l15*64 + ks*32 + quad*8];
    }

    // ones B-fragment: B[n][k] = (n==0) -> rowsum lands in output col 0
    bf16x8 onesf;
    {
        const short ONE = (short)0x3F80;
        #pragma unroll
        for (int j = 0; j < 8; j++) onesf[j] = (l15 == 0) ? ONE : (short)0;
    }

    const int skey = tid >> 2;         // staging row 0..63
    const int sch  = (tid & 3) * 2;    // chunk pair

    short* Psw = Ps[wave];

    f32x4 st[4], o[4], lo;
    lo = (f32x4){0.f,0.f,0.f,0.f};
    #pragma unroll
    for (int nt = 0; nt < 4; nt++) o[nt] = (f32x4){0.f,0.f,0.f,0.f};
    float m_i[4] = {-INFINITY,-INFINITY,-INFINITY,-INFINITY};

    // prefetch tile 0
    bf16x8 kc[2], vc[2], kn[2], vn[2];
    #pragma unroll
    for (int j = 0; j < 2; j++) {
        const int ch = sch + j;
        kc[j] = *(const bf16x8*)&Kg[(long)skey*64 + ch*8];
        vc[j] = *(const bf16x8*)&Vg[(long)skey*S_ + ch*8];
    }

    for (int kt = 0; kt < 16; kt++) {
        // ---- stage current tile (pure swizzled b128 writes) ----
        #pragma unroll
        for (int j = 0; j < 2; j++) {
            const int ch = sch + j;
            const int slot = ((ch ^ skey) & 7) << 3;
            *(bf16x8*)&Ks[skey*64 + slot] = kc[j];
            *(bf16x8*)&Vs[skey*64 + slot] = vc[j];
        }
        __syncthreads();

        // ---- prefetch next tile into registers ----
        if (kt + 1 < 16) {
            #pragma unroll
            for (int j = 0; j < 2; j++) {
                const int ch = sch + j;
                kn[j] = *(const bf16x8*)&Kg[(long)((kt+1)*64 + skey)*64 + ch*8];
                vn[j] = *(const bf16x8*)&Vg[(long)skey*S_ + (kt+1)*64 + ch*8];
            }
        }

        // ---- S = Q @ K^T ----
        #pragma unroll
        for (int nt = 0; nt < 4; nt++) st[nt] = (f32x4){0.f,0.f,0.f,0.f};
        #pragma unroll
        for (int nt = 0; nt < 4; nt++) {
            const int key = nt*16 + l15;
            #pragma unroll
            for (int ks = 0; ks < 2; ks++) {
                const bf16x8 kf = *(const bf16x8*)
                    &Ks[key*64 + ((((ks*4 + quad) ^ key) & 7) << 3)];
                st[nt] = __builtin_amdgcn_mfma_f32_16x16x32_bf16(aq[ks], kf, st[nt], 0, 0, 0);
            }
        }

        // ---- online softmax: max chain; l via ones-column MFMA ----
        float alpha[4];
        #pragma unroll
        for (int r = 0; r < 4; r++) {
            float t = fmaxf(fmaxf(st[0][r], st[1][r]), fmaxf(st[2][r], st[3][r]));
            t = fmaxf(t, __shfl_xor(t, 1));
            t = fmaxf(t, __shfl_xor(t, 2));
            t = fmaxf(t, __shfl_xor(t, 4));
            t = fmaxf(t, __shfl_xor(t, 8));
            const float mn = fmaxf(m_i[r], t);
            alpha[r] = __expf(m_i[r] - mn);
            m_i[r] = mn;
            const int row = quad*4 + r;
            #pragma unroll
            for (int nt = 0; nt < 4; nt++) {
                const float p = __expf(st[nt][r] - mn);
                const int col = nt*16 + l15;
                Psw[row*64 + ((((col >> 3) ^ row) & 7) << 3) + (col & 7)] = f2bf(p);
            }
        }
        #pragma unroll
        for (int nt = 0; nt < 4; nt++) {
            o[nt][0] *= alpha[0]; o[nt][1] *= alpha[1];
            o[nt][2] *= alpha[2]; o[nt][3] *= alpha[3];
        }
        lo[0] *= alpha[0]; lo[1] *= alpha[1];
        lo[2] *= alpha[2]; lo[3] *= alpha[3];

        // ---- P A-fragments (same-wave LDS round-trip) ----
        bf16x8 pa[2];
        #pragma unroll
        for (int ks = 0; ks < 2; ks++)
            pa[ks] = *(const bf16x8*)
                &Psw[l15*64 + ((((ks*4 + quad) ^ l15) & 7) << 3)];

        // ---- O += P @ V ; l += P @ ones ----
        #pragma unroll
        for (int nt = 0; nt < 4; nt++) {
            const int dim = nt*16 + l15;
            #pragma unroll
            for (int ks = 0; ks < 2; ks++) {
                const bf16x8 vf = *(const bf16x8*)
                    &Vs[dim*64 + ((((ks*4 + quad) ^ dim) & 7) << 3)];
                o[nt] = __builtin_amdgcn_mfma_f32_16x16x32_bf16(pa[ks], vf, o[nt], 0, 0, 0);
            }
        }
        #pragma unroll
        for (int ks = 0; ks < 2; ks++)
            lo = __builtin_amdgcn_mfma_f32_16x16x32_bf16(pa[ks], onesf, lo, 0, 0, 0);

        __syncthreads();
        #pragma unroll
        for (int j = 0; j < 2; j++) { kc[j] = kn[j]; vc[j] = vn[j]; }
    }

    // ---- epilogue: broadcast l from col-0 lanes, scale, store bf16 ----
    float inv[4];
    #pragma unroll
    for (int r = 0; r < 4; r++)
        inv[r] = 1.0f / __shfl(lo[r], quad << 4);
    const long rowBase = (long)(b*S_ + qt*64 + wave*16 + quad*4);
    #pragma unroll
    for (int nt = 0; nt < 4; nt++) {
        #pragma unroll
        for (int r = 0; r < 4; r++) {
            stackedb[(rowBase + r)*FD_ + f*D_ + h*64 + nt*16 + l15] =
                f2bf(o[nt][r] * inv[r]);
        }
    }
}

// ---------------------------------------------------------------------------
// gates[m,f] = softmax_f( g1[m,:] @ W_g2 + b_g2 ), one wave per row
// ---------------------------------------------------------------------------
__global__ __launch_bounds__(64) void gates_kernel(
    const float* __restrict__ g1, const float* __restrict__ W_g2,
    const float* __restrict__ b_g2, float* __restrict__ gates)
{
    const int m = blockIdx.x;
    const int lane = threadIdx.x;
    float p[6] = {0.f,0.f,0.f,0.f,0.f,0.f};
    for (int k = lane; k < FD4_; k += 64) {
        float g = g1[(long)m*FD4_ + k];
        #pragma unroll
        for (int f = 0; f < 6; f++) p[f] += g * W_g2[k*6 + f];
    }
    #pragma unroll
    for (int f = 0; f < 6; f++) {
        float v = p[f];
        #pragma unroll
        for (int off = 1; off < 64; off <<= 1) v += __shfl_xor(v, off);
        p[f] = v + b_g2[f];
    }
    float mx = p[0];
    #pragma unroll
    for (int f = 1; f < 6; f++) mx = fmaxf(mx, p[f]);
    float se = 0.f;
    #pragma unroll
    for (int f = 0; f < 6; f++) { p[f] = expf(p[f] - mx); se += p[f]; }
    const float inv = 1.0f / se;
    if (lane < 6) gates[m*6 + lane] = p[lane] * inv;
}

// ---------------------------------------------------------------------------
// reduce_m1: h1 = gelu(p0+p1+p2+bias) -> bf16 [2048,1536]
// ---------------------------------------------------------------------------
__global__ __launch_bounds__(256) void reduce_m1(
    const float* __restrict__ p, const float* __restrict__ bias,
    short* __restrict__ out)
{
    const int idx = blockIdx.x * 256 + threadIdx.x;
    const int col4 = idx % (D2_/4);
    const long MN4 = (long)BS_ * D2_ / 4;
    float4 a = ((const float4*)p)[idx];
    float4 b = ((const float4*)p)[idx + MN4];
    float4 c = ((const float4*)p)[idx + 2*MN4];
    float4 bb = ((const float4*)bias)[col4];
    bf16x4 o;
    o[0] = f2bf(gelu_exact(a.x + b.x + c.x + bb.x));
    o[1] = f2bf(gelu_exact(a.y + b.y + c.y + bb.y));
    o[2] = f2bf(gelu_exact(a.z + b.z + c.z + bb.z));
    o[3] = f2bf(gelu_exact(a.w + b.w + c.w + bb.w));
    ((bf16x4*)out)[idx] = o;
}

// ---------------------------------------------------------------------------
// comb[m,d] = sum_f mixed[m, f*768+d] * gates[m,f]  -> bf16
// ---------------------------------------------------------------------------
__global__ __launch_bounds__(256) void combine_kernel(
    const float* __restrict__ mixed, const float* __restrict__ gates,
    short* __restrict__ comb)
{
    const int idx = blockIdx.x * 256 + threadIdx.x;
    const int m = idx / 192;
    const int d4 = idx - m*192;
    const float4* mrow = (const float4*)(mixed + (long)m * FD_);
    float4 a = {0.f,0.f,0.f,0.f};
    #pragma unroll
    for (int f = 0; f < 6; f++) {
        float g = gates[m*6 + f];
        float4 v = mrow[f*192 + d4];
        a.x += g*v.x; a.y += g*v.y; a.z += g*v.z; a.w += g*v.w;
    }
    bf16x4 o;
    o[0] = f2bf(a.x); o[1] = f2bf(a.y); o[2] = f2bf(a.z); o[3] = f2bf(a.w);
    ((bf16x4*)comb)[idx] = o;
}

// ---------------------------------------------------------------------------
// reduce_ln: preY = x + p0 + p1 + b_out, then LayerNorm -> out. One block/row.
// ---------------------------------------------------------------------------
__global__ __launch_bounds__(256) void reduce_ln(
    const float* __restrict__ p, const float* __restrict__ bias,
    const float* __restrict__ x,
    const float* __restrict__ ln_g, const float* __restrict__ ln_b,
    float* __restrict__ out)
{
    __shared__ float red[8];
    const int m = blockIdx.x;
    const int tid = threadIdx.x;
    const long MN = (long)BS_ * D_;
    float vals[3];
    float s = 0.f, s2 = 0.f;
    #pragma unroll
    for (int i = 0; i < 3; i++) {
        const int d = tid + 256*i;
        const long o = (long)m*D_ + d;
        float v = x[o] + p[o] + p[MN + o] + bias[d];
        vals[i] = v;
        s += v; s2 += v*v;
    }
    #pragma unroll
    for (int off = 32; off >= 1; off >>= 1) {
        s  += __shfl_xor(s, off);
        s2 += __shfl_xor(s2, off);
    }
    const int wave = tid >> 6;
    if ((tid & 63) == 0) { red[wave*2] = s; red[wave*2+1] = s2; }
    __syncthreads();
    s  = red[0]+red[2]+red[4]+red[6];
    s2 = red[1]+red[3]+red[5]+red[7];
    const float mu  = s * (1.0f/D_);
    const float var = s2 * (1.0f/D_) - mu*mu;
    const float inv = rsqrtf(var + 1e-5f);
    #pragma unroll
    for (int i = 0; i < 3; i++) {
        const int d = tid + 256*i;
        out[(long)m*D_ + d] = (vals[i] - mu) * inv * ln_g[d] + ln_b[d];
    }
}

// ---------------------------------------------------------------------------
extern "C" void kernel_launch(void* const* d_in, const int* in_sizes, int n_in,
                              void* d_out, int out_size, void* d_ws, size_t ws_size,
                              hipStream_t stream)
{
    const float* x     = (const float*)d_in[0];
    const float* W_kv  = (const float*)d_in[1];
    const float* b_kv  = (const float*)d_in[2];
    const float* W_q   = (const float*)d_in[3];
    const float* b_q   = (const float*)d_in[4];
    const float* W_m1  = (const float*)d_in[5];
    const float* b_m1  = (const float*)d_in[6];
    const float* W_m2  = (const float*)d_in[7];
    const float* b_m2  = (const float*)d_in[8];
    const float* cross = (const float*)d_in[9];
    const float* W_g1  = (const float*)d_in[10];
    const float* b_g1  = (const float*)d_in[11];
    const float* W_g2  = (const float*)d_in[12];
    const float* b_g2  = (const float*)d_in[13];
    const float* W_out = (const float*)d_in[14];
    const float* b_out = (const float*)d_in[15];
    const float* ln_g  = (const float*)d_in[16];
    const float* ln_b  = (const float*)d_in[17];
    float* out = (float*)d_out;

    // workspace layout (float units):
    //  bufA    [9,437,184] : qb bf16 (first half) -> m1 partials fp32 -> mixed fp32
    //  bufB    [3,145,728] : kv fp32 -> h1 bf16
    //  stackedS[4,718,592] : stacked bf16 -> out partials fp32
    //  bufC    [2,359,296] : g1 fp32 -> Kb/Vt bf16 -> comb bf16
    //  gates   [12,288]
    float* ws       = (float*)d_ws;
    float* bufA     = ws;
    float* bufB     = bufA + (size_t)9437184;
    short* stackedS = (short*)(bufB + (size_t)3145728);
    float* bufC     = (float*)(stackedS + (size_t)BS_*FD_);
    float* gates    = bufC + (size_t)BS_*FD4_;

    short* qb = (short*)bufA;
    short* Kb = (short*)bufC;
    short* Vt = Kb + (size_t)B_*H_*S_*DH_;
    short* h1b = (short*)bufB;
    short* combb = (short*)bufC;
    float* mixed = bufA;
    float* outPart = (float*)stackedS;

    dim3 blk(256);

    // 1. fused x-projections: kv fp32 -> bufB, q bf16 -> qb, g1 fp32 -> bufC
    xproj_gemm<<<dim3(57, 16, 1), blk, 0, stream>>>(
        x, W_kv, b_kv, bufB, W_q, b_q, qb, W_g1, b_g1, bufC);
    // 2. gates = softmax(g1 @ W_g2 + b_g2)  (consumes g1 before Kb/Vt overwrite)
    gates_kernel<<<dim3(BS_), dim3(64), 0, stream>>>(bufC, W_g2, b_g2, gates);
    // 3. repack kv fp32 -> Kb, Vt bf16
    repack_kv<<<dim3(B_*H_*16), blk, 0, stream>>>(bufB, Kb, Vt);
    // 4. MFMA flash attention v4 -> stacked bf16
    attn_mfma4<<<dim3(16 * 144), blk, 0, stream>>>(qb, Kb, Vt, stackedS);
    // 5. h1 partials: split-K x3 of stacked(bf16) @ W_m1 -> bufA fp32
    mfma_gemm<4><<<dim3(D2_/128, BS_/128, 3), blk, 0, stream>>>(
        stackedS, W_m1, b_m1, bufA, BS_, D2_, FD_, FD_/3,
        (long)BS_*D2_, FD_/3, nullptr, nullptr);
    // 6. h1 = gelu(sum partials + b_m1) -> bf16 bufB
    reduce_m1<<<dim3(BS_*D2_/4/256), blk, 0, stream>>>(bufA, b_m1, h1b);
    // 7. mixed = stacked + cross*(h1(bf16) @ W_m2 + b_m2) -> fp32 bufA
    mfma_gemm<2><<<dim3(FD_/128, BS_/128, 1), blk, 0, stream>>>(
        h1b, W_m2, b_m2, mixed, BS_, FD_, D2_, D2_,
        0, 0, stackedS, cross);
    // 8. comb = sum_f mixed*gates -> bf16 bufC (Kb/Vt dead)
    combine_kernel<<<dim3(BS_*(D_/4)/256), blk, 0, stream>>>(mixed, gates, combb);
    // 9. out partials: split-K x2 of comb(bf16) @ W_out -> fp32 (stacked region)
    mfma_gemm<4><<<dim3(D_/128, BS_/128, 2), blk, 0, stream>>>(
        combb, W_out, b_out, outPart, BS_, D_, D_, D_/2,
        (long)BS_*D_, D_/2, nullptr, nullptr);
    // 10. preY = x + partials + b_out, LayerNorm -> d_out (fused)
    reduce_ln<<<dim3(BS_), blk, 0, stream>>>(outPart, b_out, x, ln_g, ln_b, out);
}

// Round 8
// 501.548 us; speedup vs baseline: 4.8346x; 1.0464x over previous
//
#include <hip/hip_runtime.h>
#include <hip/hip_bf16.h>

#define B_ 2
#define S_ 1024
#define D_ 768
#define H_ 12
#define F_ 6
#define DH_ 64
#define BS_ (B_*S_)   // 2048
#define D2_ (2*D_)    // 1536
#define FD_ (F_*D_)   // 4608
#define FD4_ (FD_/4)  // 1152

typedef __attribute__((ext_vector_type(8))) short bf16x8;
typedef __attribute__((ext_vector_type(4))) short bf16x4;
typedef __attribute__((ext_vector_type(4))) float f32x4;

__device__ __forceinline__ float gelu_exact(float x) {
    return 0.5f * x * (1.0f + erff(x * 0.70710678118654752f));
}

// fp32 -> bf16 bits, round-to-nearest-even
__device__ __forceinline__ short f2bf(float f) {
    union { float f; unsigned u; } v; v.f = f;
    unsigned r = v.u + 0x7fff + ((v.u >> 16) & 1);
    return (short)(r >> 16);
}
// truncating fp32->bf16 (1 op; for P in [0,1] where l uses the same values)
__device__ __forceinline__ short f2bf_t(float f) {
    return (short)(__float_as_uint(f) >> 16);
}
__device__ __forceinline__ float bf2f(short b) {
    union { unsigned u; float f; } v;
    v.u = ((unsigned)(unsigned short)b) << 16;
    return v.f;
}

// ===========================================================================
// Shared GEMM tile machinery (128x128 tile, BK=64, 4 waves 2x2, prefetch).
// LDS layout: [tile(8)][kchunk(8)][slot(16)] x 8 shorts, slot = l15^kc^tile.
// ===========================================================================

#define GEMM_STAGE_A16(av)                                                    \
    {                                                                         \
        _Pragma("unroll")                                                     \
        for (int c = 0; c < 4; c++) {                                         \
            const int kc = (akb >> 3) + c;                                    \
            *(bf16x8*)&As[((amt*8 + kc)*16 + ((ar15 ^ kc ^ amt) & 15))*8] = (av)[c]; \
        }                                                                     \
    }

#define GEMM_STAGE_B(bv)                                                      \
    {                                                                         \
        _Pragma("unroll")                                                     \
        for (int j = 0; j < 4; j++) {                                         \
            const int n  = bn0 + j;                                           \
            const int nt = n >> 4;                                            \
            bf16x8 s;                                                         \
            _Pragma("unroll")                                                 \
            for (int r = 0; r < 8; r++) s[r] = f2bf((bv)[r][j]);              \
            *(bf16x8*)&Bs[((nt*8 + bkg)*16 + (((n & 15) ^ bkg ^ nt) & 15))*8] = s; \
        }                                                                     \
    }

#define GEMM_STAGE_B16(bv)                                                    \
    {                                                                         \
        _Pragma("unroll")                                                     \
        for (int j = 0; j < 4; j++) {                                         \
            const int n  = bn0 + j;                                           \
            const int nt = n >> 4;                                            \
            bf16x8 s;                                                         \
            _Pragma("unroll")                                                 \
            for (int r = 0; r < 8; r++) s[r] = (bv)[r][j];                    \
            *(bf16x8*)&Bs[((nt*8 + bkg)*16 + (((n & 15) ^ bkg ^ nt) & 15))*8] = s; \
        }                                                                     \
    }

#define GEMM_LOAD_A16(av, kb)                                                 \
    {                                                                         \
        _Pragma("unroll")                                                     \
        for (int c = 0; c < 4; c++)                                           \
            (av)[c] = *(const bf16x8*)(Ap + (kb) + c*8);                      \
    }

#define GEMM_LOAD_B(bv, kb, strideN)                                          \
    {                                                                         \
        _Pragma("unroll")                                                     \
        for (int r = 0; r < 8; r++)                                           \
            *(float4*)&(bv)[r][0] = *(const float4*)(Wp + (long)((kb) + r) * (strideN)); \
    }

#define GEMM_LOAD_B16(bv, kb, strideN)                                        \
    {                                                                         \
        _Pragma("unroll")                                                     \
        for (int r = 0; r < 8; r++)                                           \
            *(bf16x4*)&(bv)[r][0] = *(const bf16x4*)(Wp + (long)((kb) + r) * (strideN)); \
    }

#define GEMM_COMPUTE()                                                        \
    {                                                                         \
        _Pragma("unroll")                                                     \
        for (int ks = 0; ks < 2; ks++) {                                      \
            const int kc = ks*4 + quad;                                       \
            bf16x8 af[4], bf[4];                                              \
            _Pragma("unroll")                                                 \
            for (int mt = 0; mt < 4; mt++) {                                  \
                const int MT = wr*4 + mt;                                     \
                af[mt] = *(const bf16x8*)&As[((MT*8 + kc)*16 + ((l15 ^ kc ^ MT) & 15))*8]; \
            }                                                                 \
            _Pragma("unroll")                                                 \
            for (int nt = 0; nt < 4; nt++) {                                  \
                const int NT = wc*4 + nt;                                     \
                bf[nt] = *(const bf16x8*)&Bs[((NT*8 + kc)*16 + ((l15 ^ kc ^ NT) & 15))*8]; \
            }                                                                 \
            _Pragma("unroll")                                                 \
            for (int mt = 0; mt < 4; mt++)                                    \
                _Pragma("unroll")                                             \
                for (int nt = 0; nt < 4; nt++)                                \
                    acc[mt][nt] = __builtin_amdgcn_mfma_f32_16x16x32_bf16(    \
                        af[mt], bf[nt], acc[mt][nt], 0, 0, 0);                \
        }                                                                     \
    }

#define GEMM_COMMON_IDS()                                                     \
    const int tid  = threadIdx.x;                                             \
    const int wave = tid >> 6;                                                \
    const int lane = tid & 63;                                                \
    const int l15  = lane & 15;                                               \
    const int quad = lane >> 4;                                               \
    const int wr   = wave >> 1;                                               \
    const int wc   = wave & 1;                                                \
    const int ar   = tid >> 1;                                                \
    const int akb  = (tid & 1) * 32;                                          \
    const int amt  = ar >> 4;                                                 \
    const int ar15 = ar & 15;                                                 \
    const int bn0  = (tid & 31) * 4;                                          \
    const int bkg  = tid >> 5;

// ---------------------------------------------------------------------------
// prepack: fp32 -> bf16 for x, W_kv, W_q, W_g1 (the multi-read operands).
// float4-granular; segments selected by flat index.
// ---------------------------------------------------------------------------
#define PPK_N0 393216   // x        1572864 f /4
#define PPK_N1 294912   // W_kv     1179648 f /4
#define PPK_N2 884736   // W_q      3538944 f /4
#define PPK_N3 221184   // W_g1      884736 f /4
__global__ __launch_bounds__(256) void prepack(
    const float* __restrict__ x, const float* __restrict__ Wkv,
    const float* __restrict__ Wq, const float* __restrict__ Wg1,
    short* __restrict__ xb, short* __restrict__ wkvb,
    short* __restrict__ wqb, short* __restrict__ wg1b)
{
    long idx = (long)blockIdx.x * 256 + threadIdx.x;
    const float* src; short* dst;
    if (idx < PPK_N0) { src = x; dst = xb; }
    else if ((idx -= PPK_N0) < PPK_N1) { src = Wkv; dst = wkvb; }
    else if ((idx -= PPK_N1) < PPK_N2) { src = Wq;  dst = wqb; }
    else { idx -= PPK_N2; src = Wg1; dst = wg1b; }
    float4 v = ((const float4*)src)[idx];
    bf16x4 o;
    o[0] = f2bf(v.x); o[1] = f2bf(v.y); o[2] = f2bf(v.z); o[3] = f2bf(v.w);
    ((bf16x4*)dst)[idx] = o;
}

// ---------------------------------------------------------------------------
// mfma_gemm: bf16 A, fp32 W/out.
// MODE 2: C = bf2f(addend) + (*scale_ptr)*v ; MODE 4: raw split-K partial
// ---------------------------------------------------------------------------
template<int MODE>
__global__ __launch_bounds__(256, 2) void mfma_gemm(
    const short* __restrict__ A, const float* __restrict__ W,
    const float* __restrict__ bias, float* __restrict__ C,
    int M, int N, int K, int kLen,
    long cStrideZ, long kStrideZ,
    const short* __restrict__ addend, const float* __restrict__ scale_ptr)
{
    if (blockIdx.z) C += (long)blockIdx.z * cStrideZ;
    const int kBeg = (int)(blockIdx.z * kStrideZ);
    const int kEnd = kBeg + kLen;

    __shared__ __align__(16) short As[8192];
    __shared__ __align__(16) short Bs[8192];

    GEMM_COMMON_IDS();

    const int m0 = blockIdx.y * 128;
    const int n0 = blockIdx.x * 128;

    const short* Ap = A + (long)(m0 + ar) * K + akb;
    const float* Wp = W + (long)(bkg * 8) * N + n0 + bn0;

    f32x4 acc[4][4];
    #pragma unroll
    for (int i = 0; i < 4; i++)
        #pragma unroll
        for (int j = 0; j < 4; j++)
            acc[i][j] = (f32x4){0.f, 0.f, 0.f, 0.f};

    bf16x8 a0[4], a1[4];
    float b0[8][4], b1[8][4];
    GEMM_LOAD_A16(a0, kBeg);
    GEMM_LOAD_B(b0, kBeg, N);

    for (int kb = kBeg; kb < kEnd; kb += 128) {
        GEMM_STAGE_A16(a0); GEMM_STAGE_B(b0);
        __syncthreads();
        GEMM_LOAD_A16(a1, kb + 64);
        GEMM_LOAD_B(b1, kb + 64, N);
        GEMM_COMPUTE();
        __syncthreads();
        GEMM_STAGE_A16(a1); GEMM_STAGE_B(b1);
        __syncthreads();
        if (kb + 128 < kEnd) {
            GEMM_LOAD_A16(a0, kb + 128);
            GEMM_LOAD_B(b0, kb + 128, N);
        }
        GEMM_COMPUTE();
        __syncthreads();
    }

    float scale = 0.0f;
    if (MODE == 2) scale = *scale_ptr;
    #pragma unroll
    for (int nt = 0; nt < 4; nt++) {
        const int col = n0 + wc*64 + nt*16 + l15;
        const float bcol = (MODE == 4) ? 0.0f : bias[col];
        #pragma unroll
        for (int mt = 0; mt < 4; mt++) {
            #pragma unroll
            for (int r = 0; r < 4; r++) {
                const long row = m0 + wr*64 + mt*16 + quad*4 + r;
                float v = acc[mt][nt][r] + bcol;
                if (MODE == 2) v = bf2f(addend[row*N + col]) + scale * v;
                C[row*N + col] = v;
            }
        }
    }
}

// ---------------------------------------------------------------------------
// xproj: fused projections of x — all-bf16 operands (prepacked).
//   tiles  0..11 -> kv fp32 [B*S,1536]
//   tiles 12..47 -> q bf16 pre-scaled*(0.125*log2e) -> qb [F][B][H][S][64]
//   tiles 48..56 -> g1 = gelu(..) fp32 [B*S,1152]
// ---------------------------------------------------------------------------
#define QSCALE 0.18033688011112042f   // 0.125 * log2(e)
__global__ __launch_bounds__(256, 2) void xproj_gemm(
    const short* __restrict__ xb,
    const short* __restrict__ W_kv, const float* __restrict__ b_kv, float* __restrict__ bufKV,
    const short* __restrict__ W_q,  const float* __restrict__ b_q,  short* __restrict__ qb,
    const short* __restrict__ W_g1, const float* __restrict__ b_g1, float* __restrict__ bufG1)
{
    __shared__ __align__(16) short As[8192];
    __shared__ __align__(16) short Bs[8192];

    GEMM_COMMON_IDS();

    const int ntile = blockIdx.x;
    const int m0 = blockIdx.y * 128;

    const short* Wseg; const float* bseg; float* Cseg = nullptr;
    int Nw, ncol, fidx = 0, mode;   // mode 0=kv,1=q,2=g1
    if (ntile < 12) {
        Wseg = W_kv; bseg = b_kv; Cseg = bufKV; Nw = 1536; ncol = ntile * 128; mode = 0;
    } else if (ntile < 48) {
        const int t = ntile - 12; fidx = t / 6;
        ncol = (t % 6) * 128;
        Wseg = W_q + (long)fidx * D_ * D_; bseg = b_q + fidx * D_;
        Nw = 768; mode = 1;
    } else {
        const int t = ntile - 48;
        Wseg = W_g1; bseg = b_g1; Cseg = bufG1; Nw = 1152; ncol = t * 128; mode = 2;
    }

    const short* Ap = xb + (long)(m0 + ar) * D_ + akb;
    const short* Wp = Wseg + (long)(bkg * 8) * Nw + ncol + bn0;

    f32x4 acc[4][4];
    #pragma unroll
    for (int i = 0; i < 4; i++)
        #pragma unroll
        for (int j = 0; j < 4; j++)
            acc[i][j] = (f32x4){0.f, 0.f, 0.f, 0.f};

    bf16x8 a0[4], a1[4];
    short b0[8][4], b1[8][4];
    GEMM_LOAD_A16(a0, 0);
    GEMM_LOAD_B16(b0, 0, Nw);

    for (int kb = 0; kb < D_; kb += 128) {
        GEMM_STAGE_A16(a0); GEMM_STAGE_B16(b0);
        __syncthreads();
        GEMM_LOAD_A16(a1, kb + 64);
        GEMM_LOAD_B16(b1, kb + 64, Nw);
        GEMM_COMPUTE();
        __syncthreads();
        GEMM_STAGE_A16(a1); GEMM_STAGE_B16(b1);
        __syncthreads();
        if (kb + 128 < D_) {
            GEMM_LOAD_A16(a0, kb + 128);
            GEMM_LOAD_B16(b0, kb + 128, Nw);
        }
        GEMM_COMPUTE();
        __syncthreads();
    }

    if (mode == 1) {
        const int bb = m0 >> 10;
        const int sBase = (m0 & 1023) + wr*64;
        #pragma unroll
        for (int nt = 0; nt < 4; nt++) {
            const int col = ncol + wc*64 + nt*16 + l15;   // 0..767
            const int hh = col >> 6, dd = col & 63;
            const float bcol = bseg[col];
            short* qBase = qb + ((((long)fidx*B_ + bb)*H_ + hh)*S_)*64 + dd;
            #pragma unroll
            for (int mt = 0; mt < 4; mt++) {
                #pragma unroll
                for (int r = 0; r < 4; r++) {
                    const int s = sBase + mt*16 + quad*4 + r;
                    qBase[(long)s*64] = f2bf((acc[mt][nt][r] + bcol) * QSCALE);
                }
            }
        }
    } else {
        #pragma unroll
        for (int nt = 0; nt < 4; nt++) {
            const int col = ncol + wc*64 + nt*16 + l15;
            const float bcol = bseg[col];
            #pragma unroll
            for (int mt = 0; mt < 4; mt++) {
                #pragma unroll
                for (int r = 0; r < 4; r++) {
                    const long row = m0 + wr*64 + mt*16 + quad*4 + r;
                    float v = acc[mt][nt][r] + bcol;
                    if (mode == 2) v = gelu_exact(v);
                    Cseg[row*Nw + col] = v;
                }
            }
        }
    }
}

// ---------------------------------------------------------------------------
// repack_kv: kv fp32 [B*S,1536] -> Kb bf16 [B][H][S][64], Vt bf16 [B][H][64][S]
// ---------------------------------------------------------------------------
__global__ __launch_bounds__(256) void repack_kv(
    const float* __restrict__ kvf, short* __restrict__ Kb, short* __restrict__ Vtb)
{
    __shared__ __align__(16) short T[64*64];
    const int bx = blockIdx.x;         // b*192 + h*16 + st
    const int st = bx & 15;
    const int h  = (bx >> 4) % 12;
    const int b  = bx / 192;
    const int tid = threadIdx.x;
    const int s_loc = tid & 63;
    const int dch  = (tid >> 6) * 16;
    const int s0 = st * 64;

    const float* kr = kvf + (long)(b*S_ + s0 + s_loc) * D2_ + h*64 + dch;
    float v[16];

    #pragma unroll
    for (int i = 0; i < 4; i++) *(float4*)&v[i*4] = *(const float4*)(kr + i*4);
    {
        short* kw = Kb + ((long)(b*H_ + h)*S_ + s0 + s_loc)*64 + dch;
        bf16x8 p0, p1;
        #pragma unroll
        for (int i = 0; i < 8; i++) { p0[i] = f2bf(v[i]); p1[i] = f2bf(v[8+i]); }
        *(bf16x8*)&kw[0] = p0;
        *(bf16x8*)&kw[8] = p1;
    }

    #pragma unroll
    for (int i = 0; i < 4; i++) *(float4*)&v[i*4] = *(const float4*)(kr + D_ + i*4);
    #pragma unroll
    for (int i = 0; i < 16; i++) {
        const int d = dch + i;
        T[d*64 + ((((s_loc >> 3) ^ d) & 7) << 3) + (s_loc & 7)] = f2bf(v[i]);
    }
    __syncthreads();
    const int d_loc = tid >> 2;
    const int sc = (tid & 3) * 16;
    const int c0 = sc >> 3;
    bf16x8 o0 = *(const bf16x8*)&T[d_loc*64 + (((c0 ^ d_loc) & 7) << 3)];
    bf16x8 o1 = *(const bf16x8*)&T[d_loc*64 + ((((c0+1) ^ d_loc) & 7) << 3)];
    short* vw = Vtb + ((long)(b*H_ + h)*64 + d_loc)*S_ + s0 + sc;
    *(bf16x8*)&vw[0] = o0;
    *(bf16x8*)&vw[8] = o1;
}

// ---------------------------------------------------------------------------
// MFMA flash attention v5: v4 + log2-domain softmax (q pre-scaled by log2e),
// exp2f (bare v_exp_f32), truncating P conversion (l self-consistent via
// ones-column MFMA on the same truncated P).
// ---------------------------------------------------------------------------
__global__ __launch_bounds__(256, 4) void attn_mfma5(
    const short* __restrict__ qb,
    const short* __restrict__ Kb,
    const short* __restrict__ Vt,
    short* __restrict__ stackedb)
{
    __shared__ __align__(16) short Ks[64*64];
    __shared__ __align__(16) short Vs[64*64];
    __shared__ __align__(16) short Ps[4][16*64];

    const int bx = blockIdx.x;
    const int qt = bx & 15;           // 16 q-tiles of 64 rows
    const int rest = bx >> 4;         // 0..143
    const int h = rest % 12;
    const int r2 = rest / 12;
    const int f = r2 % 6;
    const int b = r2 / 6;

    const int tid  = threadIdx.x;
    const int wave = tid >> 6;
    const int lane = tid & 63;
    const int l15  = lane & 15;
    const int quad = lane >> 4;

    const short* Kg = Kb + (long)(b*H_ + h) * S_ * 64;
    const short* Vg = Vt + (long)(b*H_ + h) * 64 * S_;

    bf16x8 aq[2];
    {
        const short* qp = qb + ((((long)f*B_ + b)*H_ + h)*S_ + qt*64 + wave*16)*64;
        #pragma unroll
        for (int ks = 0; ks < 2; ks++)
            aq[ks] = *(const bf16x8*)&qp[l15*64 + ks*32 + quad*8];
    }

    bf16x8 onesf;
    {
        const short ONE = (short)0x3F80;
        #pragma unroll
        for (int j = 0; j < 8; j++) onesf[j] = (l15 == 0) ? ONE : (short)0;
    }

    const int skey = tid >> 2;         // staging row 0..63
    const int sch  = (tid & 3) * 2;    // chunk pair

    short* Psw = Ps[wave];

    f32x4 st[4], o[4], lo;
    lo = (f32x4){0.f,0.f,0.f,0.f};
    #pragma unroll
    for (int nt = 0; nt < 4; nt++) o[nt] = (f32x4){0.f,0.f,0.f,0.f};
    float m_i[4] = {-INFINITY,-INFINITY,-INFINITY,-INFINITY};

    bf16x8 kc[2], vc[2], kn[2], vn[2];
    #pragma unroll
    for (int j = 0; j < 2; j++) {
        const int ch = sch + j;
        kc[j] = *(const bf16x8*)&Kg[(long)skey*64 + ch*8];
        vc[j] = *(const bf16x8*)&Vg[(long)skey*S_ + ch*8];
    }

    for (int kt = 0; kt < 16; kt++) {
        #pragma unroll
        for (int j = 0; j < 2; j++) {
            const int ch = sch + j;
            const int slot = ((ch ^ skey) & 7) << 3;
            *(bf16x8*)&Ks[skey*64 + slot] = kc[j];
            *(bf16x8*)&Vs[skey*64 + slot] = vc[j];
        }
        __syncthreads();

        if (kt + 1 < 16) {
            #pragma unroll
            for (int j = 0; j < 2; j++) {
                const int ch = sch + j;
                kn[j] = *(const bf16x8*)&Kg[(long)((kt+1)*64 + skey)*64 + ch*8];
                vn[j] = *(const bf16x8*)&Vg[(long)skey*S_ + (kt+1)*64 + ch*8];
            }
        }

        // ---- S = Q @ K^T  (scores already in log2 domain) ----
        #pragma unroll
        for (int nt = 0; nt < 4; nt++) st[nt] = (f32x4){0.f,0.f,0.f,0.f};
        #pragma unroll
        for (int nt = 0; nt < 4; nt++) {
            const int key = nt*16 + l15;
            #pragma unroll
            for (int ks = 0; ks < 2; ks++) {
                const bf16x8 kf = *(const bf16x8*)
                    &Ks[key*64 + ((((ks*4 + quad) ^ key) & 7) << 3)];
                st[nt] = __builtin_amdgcn_mfma_f32_16x16x32_bf16(aq[ks], kf, st[nt], 0, 0, 0);
            }
        }

        // ---- online softmax in log2 domain ----
        float alpha[4];
        #pragma unroll
        for (int r = 0; r < 4; r++) {
            float t = fmaxf(fmaxf(st[0][r], st[1][r]), fmaxf(st[2][r], st[3][r]));
            t = fmaxf(t, __shfl_xor(t, 1));
            t = fmaxf(t, __shfl_xor(t, 2));
            t = fmaxf(t, __shfl_xor(t, 4));
            t = fmaxf(t, __shfl_xor(t, 8));
            const float mn = fmaxf(m_i[r], t);
            alpha[r] = exp2f(m_i[r] - mn);
            m_i[r] = mn;
            const int row = quad*4 + r;
            #pragma unroll
            for (int nt = 0; nt < 4; nt++) {
                const float p = exp2f(st[nt][r] - mn);
                const int col = nt*16 + l15;
                Psw[row*64 + ((((col >> 3) ^ row) & 7) << 3) + (col & 7)] = f2bf_t(p);
            }
        }
        #pragma unroll
        for (int nt = 0; nt < 4; nt++) {
            o[nt][0] *= alpha[0]; o[nt][1] *= alpha[1];
            o[nt][2] *= alpha[2]; o[nt][3] *= alpha[3];
        }
        lo[0] *= alpha[0]; lo[1] *= alpha[1];
        lo[2] *= alpha[2]; lo[3] *= alpha[3];

        bf16x8 pa[2];
        #pragma unroll
        for (int ks = 0; ks < 2; ks++)
            pa[ks] = *(const bf16x8*)
                &Psw[l15*64 + ((((ks*4 + quad) ^ l15) & 7) << 3)];

        #pragma unroll
        for (int nt = 0; nt < 4; nt++) {
            const int dim = nt*16 + l15;
            #pragma unroll
            for (int ks = 0; ks < 2; ks++) {
                const bf16x8 vf = *(const bf16x8*)
                    &Vs[dim*64 + ((((ks*4 + quad) ^ dim) & 7) << 3)];
                o[nt] = __builtin_amdgcn_mfma_f32_16x16x32_bf16(pa[ks], vf, o[nt], 0, 0, 0);
            }
        }
        #pragma unroll
        for (int ks = 0; ks < 2; ks++)
            lo = __builtin_amdgcn_mfma_f32_16x16x32_bf16(pa[ks], onesf, lo, 0, 0, 0);

        __syncthreads();
        #pragma unroll
        for (int j = 0; j < 2; j++) { kc[j] = kn[j]; vc[j] = vn[j]; }
    }

    float inv[4];
    #pragma unroll
    for (int r = 0; r < 4; r++)
        inv[r] = 1.0f / __shfl(lo[r], quad << 4);
    const long rowBase = (long)(b*S_ + qt*64 + wave*16 + quad*4);
    #pragma unroll
    for (int nt = 0; nt < 4; nt++) {
        #pragma unroll
        for (int r = 0; r < 4; r++) {
            stackedb[(rowBase + r)*FD_ + f*D_ + h*64 + nt*16 + l15] =
                f2bf(o[nt][r] * inv[r]);
        }
    }
}

// ---------------------------------------------------------------------------
// gates[m,f] = softmax_f( g1[m,:] @ W_g2 + b_g2 ), one wave per row
// ---------------------------------------------------------------------------
__global__ __launch_bounds__(64) void gates_kernel(
    const float* __restrict__ g1, const float* __restrict__ W_g2,
    const float* __restrict__ b_g2, float* __restrict__ gates)
{
    const int m = blockIdx.x;
    const int lane = threadIdx.x;
    float p[6] = {0.f,0.f,0.f,0.f,0.f,0.f};
    for (int k = lane; k < FD4_; k += 64) {
        float g = g1[(long)m*FD4_ + k];
        #pragma unroll
        for (int f = 0; f < 6; f++) p[f] += g * W_g2[k*6 + f];
    }
    #pragma unroll
    for (int f = 0; f < 6; f++) {
        float v = p[f];
        #pragma unroll
        for (int off = 1; off < 64; off <<= 1) v += __shfl_xor(v, off);
        p[f] = v + b_g2[f];
    }
    float mx = p[0];
    #pragma unroll
    for (int f = 1; f < 6; f++) mx = fmaxf(mx, p[f]);
    float se = 0.f;
    #pragma unroll
    for (int f = 0; f < 6; f++) { p[f] = expf(p[f] - mx); se += p[f]; }
    const float inv = 1.0f / se;
    if (lane < 6) gates[m*6 + lane] = p[lane] * inv;
}

// ---------------------------------------------------------------------------
// reduce_m1: h1 = gelu(p0+p1+p2+bias) -> bf16 [2048,1536]
// ---------------------------------------------------------------------------
__global__ __launch_bounds__(256) void reduce_m1(
    const float* __restrict__ p, const float* __restrict__ bias,
    short* __restrict__ out)
{
    const int idx = blockIdx.x * 256 + threadIdx.x;
    const int col4 = idx % (D2_/4);
    const long MN4 = (long)BS_ * D2_ / 4;
    float4 a = ((const float4*)p)[idx];
    float4 b = ((const float4*)p)[idx + MN4];
    float4 c = ((const float4*)p)[idx + 2*MN4];
    float4 bb = ((const float4*)bias)[col4];
    bf16x4 o;
    o[0] = f2bf(gelu_exact(a.x + b.x + c.x + bb.x));
    o[1] = f2bf(gelu_exact(a.y + b.y + c.y + bb.y));
    o[2] = f2bf(gelu_exact(a.z + b.z + c.z + bb.z));
    o[3] = f2bf(gelu_exact(a.w + b.w + c.w + bb.w));
    ((bf16x4*)out)[idx] = o;
}

// ---------------------------------------------------------------------------
// comb[m,d] = sum_f mixed[m, f*768+d] * gates[m,f]  -> bf16
// ---------------------------------------------------------------------------
__global__ __launch_bounds__(256) void combine_kernel(
    const float* __restrict__ mixed, const float* __restrict__ gates,
    short* __restrict__ comb)
{
    const int idx = blockIdx.x * 256 + threadIdx.x;
    const int m = idx / 192;
    const int d4 = idx - m*192;
    const float4* mrow = (const float4*)(mixed + (long)m * FD_);
    float4 a = {0.f,0.f,0.f,0.f};
    #pragma unroll
    for (int f = 0; f < 6; f++) {
        float g = gates[m*6 + f];
        float4 v = mrow[f*192 + d4];
        a.x += g*v.x; a.y += g*v.y; a.z += g*v.z; a.w += g*v.w;
    }
    bf16x4 o;
    o[0] = f2bf(a.x); o[1] = f2bf(a.y); o[2] = f2bf(a.z); o[3] = f2bf(a.w);
    ((bf16x4*)comb)[idx] = o;
}

// ---------------------------------------------------------------------------
// reduce_ln: preY = x + p0 + p1 + b_out, then LayerNorm -> out. One block/row.
// ---------------------------------------------------------------------------
__global__ __launch_bounds__(256) void reduce_ln(
    const float* __restrict__ p, const float* __restrict__ bias,
    const float* __restrict__ x,
    const float* __restrict__ ln_g, const float* __restrict__ ln_b,
    float* __restrict__ out)
{
    __shared__ float red[8];
    const int m = blockIdx.x;
    const int tid = threadIdx.x;
    const long MN = (long)BS_ * D_;
    float vals[3];
    float s = 0.f, s2 = 0.f;
    #pragma unroll
    for (int i = 0; i < 3; i++) {
        const int d = tid + 256*i;
        const long o = (long)m*D_ + d;
        float v = x[o] + p[o] + p[MN + o] + bias[d];
        vals[i] = v;
        s += v; s2 += v*v;
    }
    #pragma unroll
    for (int off = 32; off >= 1; off >>= 1) {
        s  += __shfl_xor(s, off);
        s2 += __shfl_xor(s2, off);
    }
    const int wave = tid >> 6;
    if ((tid & 63) == 0) { red[wave*2] = s; red[wave*2+1] = s2; }
    __syncthreads();
    s  = red[0]+red[2]+red[4]+red[6];
    s2 = red[1]+red[3]+red[5]+red[7];
    const float mu  = s * (1.0f/D_);
    const float var = s2 * (1.0f/D_) - mu*mu;
    const float inv = rsqrtf(var + 1e-5f);
    #pragma unroll
    for (int i = 0; i < 3; i++) {
        const int d = tid + 256*i;
        out[(long)m*D_ + d] = (vals[i] - mu) * inv * ln_g[d] + ln_b[d];
    }
}

// ---------------------------------------------------------------------------
extern "C" void kernel_launch(void* const* d_in, const int* in_sizes, int n_in,
                              void* d_out, int out_size, void* d_ws, size_t ws_size,
                              hipStream_t stream)
{
    const float* x     = (const float*)d_in[0];
    const float* W_kv  = (const float*)d_in[1];
    const float* b_kv  = (const float*)d_in[2];
    const float* W_q   = (const float*)d_in[3];
    const float* b_q   = (const float*)d_in[4];
    const float* W_m1  = (const float*)d_in[5];
    const float* b_m1  = (const float*)d_in[6];
    const float* W_m2  = (const float*)d_in[7];
    const float* b_m2  = (const float*)d_in[8];
    const float* cross = (const float*)d_in[9];
    const float* W_g1  = (const float*)d_in[10];
    const float* b_g1  = (const float*)d_in[11];
    const float* W_g2  = (const float*)d_in[12];
    const float* b_g2  = (const float*)d_in[13];
    const float* W_out = (const float*)d_in[14];
    const float* b_out = (const float*)d_in[15];
    const float* ln_g  = (const float*)d_in[16];
    const float* ln_b  = (const float*)d_in[17];
    float* out = (float*)d_out;

    // workspace layout (float units):
    //  bufA    [9,437,184] : qb bf16 (first half) -> m1 partials fp32 -> mixed fp32
    //  bufB    [3,145,728] : kv fp32 -> h1 bf16
    //  stackedS[4,718,592] : stacked bf16 -> out partials fp32
    //  bufC    [2,359,296] : g1 fp32 -> Kb/Vt bf16 -> comb bf16
    //  gates   [12,288]
    //  wpack   [3,588,096] : bf16 prepack of x / W_kv / W_q / W_g1
    float* ws       = (float*)d_ws;
    float* bufA     = ws;
    float* bufB     = bufA + (size_t)9437184;
    short* stackedS = (short*)(bufB + (size_t)3145728);
    float* bufC     = (float*)(stackedS + (size_t)BS_*FD_);
    float* gates    = bufC + (size_t)BS_*FD4_;

    short* wpack = (short*)(gates + 12288);
    short* xb    = wpack;                                  // 1,572,864
    short* wkvb  = xb + (size_t)BS_*D_;                    // 1,179,648
    short* wqb   = wkvb + (size_t)D_*D2_;                  // 3,538,944
    short* wg1b  = wqb + (size_t)F_*D_*D_;                 //   884,736

    short* qb = (short*)bufA;
    short* Kb = (short*)bufC;
    short* Vt = Kb + (size_t)B_*H_*S_*DH_;
    short* h1b = (short*)bufB;
    short* combb = (short*)bufC;
    float* mixed = bufA;
    float* outPart = (float*)stackedS;

    dim3 blk(256);

    // 0. prepack x + xproj weights to bf16
    prepack<<<dim3((PPK_N0+PPK_N1+PPK_N2+PPK_N3)/256), blk, 0, stream>>>(
        x, W_kv, W_q, W_g1, xb, wkvb, wqb, wg1b);
    // 1. fused x-projections (all-bf16): kv fp32, q bf16 (log2e-scaled), g1 fp32
    xproj_gemm<<<dim3(57, 16, 1), blk, 0, stream>>>(
        xb, wkvb, b_kv, bufB, wqb, b_q, qb, wg1b, b_g1, bufC);
    // 2. gates = softmax(g1 @ W_g2 + b_g2)
    gates_kernel<<<dim3(BS_), dim3(64), 0, stream>>>(bufC, W_g2, b_g2, gates);
    // 3. repack kv fp32 -> Kb, Vt bf16
    repack_kv<<<dim3(B_*H_*16), blk, 0, stream>>>(bufB, Kb, Vt);
    // 4. MFMA flash attention v5 -> stacked bf16
    attn_mfma5<<<dim3(16 * 144), blk, 0, stream>>>(qb, Kb, Vt, stackedS);
    // 5. h1 partials: split-K x3 of stacked(bf16) @ W_m1 -> bufA fp32
    mfma_gemm<4><<<dim3(D2_/128, BS_/128, 3), blk, 0, stream>>>(
        stackedS, W_m1, b_m1, bufA, BS_, D2_, FD_, FD_/3,
        (long)BS_*D2_, FD_/3, nullptr, nullptr);
    // 6. h1 = gelu(sum partials + b_m1) -> bf16 bufB
    reduce_m1<<<dim3(BS_*D2_/4/256), blk, 0, stream>>>(bufA, b_m1, h1b);
    // 7. mixed = stacked + cross*(h1(bf16) @ W_m2 + b_m2) -> fp32 bufA
    mfma_gemm<2><<<dim3(FD_/128, BS_/128, 1), blk, 0, stream>>>(
        h1b, W_m2, b_m2, mixed, BS_, FD_, D2_, D2_,
        0, 0, stackedS, cross);
    // 8. comb = sum_f mixed*gates -> bf16 bufC (Kb/Vt dead)
    combine_kernel<<<dim3(BS_*(D_/4)/256), blk, 0, stream>>>(mixed, gates, combb);
    // 9. out partials: split-K x2 of comb(bf16) @ W_out -> fp32 (stacked region)
    mfma_gemm<4><<<dim3(D_/128, BS_/128, 2), blk, 0, stream>>>(
        combb, W_out, b_out, outPart, BS_, D_, D_, D_/2,
        (long)BS_*D_, D_/2, nullptr, nullptr);
    // 10. preY = x + partials + b_out, LayerNorm -> d_out (fused)
    reduce_ln<<<dim3(BS_), blk, 0, stream>>>(outPart, b_out, x, ln_g, ln_b, out);
}